// Round 1
// baseline (5263.844 us; speedup 1.0000x reference)
//
#include <hip/hip_runtime.h>
#include <math.h>

#define NB   8
#define CIN  512
#define COUT 256
#define DIN  512
#define LHW  4096
#define NCHK 32
#define CHL  128

__device__ __forceinline__ float siluf(float v)  { return v / (1.f + __expf(-v)); }
__device__ __forceinline__ float splusf(float v) { return v > 20.f ? v : log1pf(__expf(v)); }

// ---------------------------------------------------------------------------
// K1: xl[b][o][l] = sum_k lw[o][k] * x[b][k][l] + lb[o]
// ---------------------------------------------------------------------------
__global__ __launch_bounds__(256)
void k_lateral(const float* __restrict__ x, const float* __restrict__ lw,
               const float* __restrict__ lb, float* __restrict__ xl) {
  __shared__ float As[16][68];  // [k][m]
  __shared__ float Bs[16][68];  // [k][n]
  const int b  = blockIdx.z;
  const int m0 = blockIdx.y * 64;
  const int n0 = blockIdx.x * 64;
  const int tid = threadIdx.x;
  const int tx = tid & 15, ty = tid >> 4;
  const int ar = tid >> 2, ac = tid & 3;
  float acc[4][4] = {};
  const float* xb = x + (size_t)b * CIN * LHW;
  for (int k0 = 0; k0 < CIN; k0 += 16) {
    float4 av = *(const float4*)(lw + (size_t)(m0 + ar) * CIN + k0 + ac * 4);
    As[ac*4+0][ar] = av.x; As[ac*4+1][ar] = av.y;
    As[ac*4+2][ar] = av.z; As[ac*4+3][ar] = av.w;
    float4 bv = *(const float4*)(xb + (size_t)(k0 + ty) * LHW + n0 + tx * 4);
    *(float4*)(&Bs[ty][tx*4]) = bv;
    __syncthreads();
#pragma unroll
    for (int kk = 0; kk < 16; ++kk) {
      float4 a4 = *(const float4*)(&As[kk][ty*4]);
      float4 b4 = *(const float4*)(&Bs[kk][tx*4]);
      const float aa[4] = {a4.x, a4.y, a4.z, a4.w};
      const float bb[4] = {b4.x, b4.y, b4.z, b4.w};
#pragma unroll
      for (int i = 0; i < 4; ++i)
#pragma unroll
        for (int j = 0; j < 4; ++j)
          acc[i][j] = fmaf(aa[i], bb[j], acc[i][j]);
    }
    __syncthreads();
  }
#pragma unroll
  for (int i = 0; i < 4; ++i) {
    const int m = m0 + ty*4 + i;
    const float bias = lb[m];
    float4 o = make_float4(acc[i][0]+bias, acc[i][1]+bias, acc[i][2]+bias, acc[i][3]+bias);
    *(float4*)(xl + ((size_t)b*COUT + m)*LHW + n0 + tx*4) = o;
  }
}

// ---------------------------------------------------------------------------
// K2: xz[b][l][e] = sum_d ipw[e][d] * xl[b][d][l]; e<512 -> xm_t ; e>=512 -> silu -> zs
// ---------------------------------------------------------------------------
__global__ __launch_bounds__(256)
void k_inproj(const float* __restrict__ xl, const float* __restrict__ ipw,
              float* __restrict__ xm_t, float* __restrict__ zs) {
  __shared__ float As[16][68];  // [k=d][m=l]
  __shared__ float Bs[16][68];  // [k=d][n=e]
  const int b  = blockIdx.z;
  const int m0 = blockIdx.y * 64;  // l
  const int n0 = blockIdx.x * 64;  // e
  const int tid = threadIdx.x;
  const int tx = tid & 15, ty = tid >> 4;
  const int ar = tid >> 2, ac = tid & 3;
  float acc[4][4] = {};
  const float* xlb = xl + (size_t)b * COUT * LHW;
  for (int k0 = 0; k0 < COUT; k0 += 16) {
    float4 av = *(const float4*)(xlb + (size_t)(k0 + ty) * LHW + m0 + tx * 4);
    *(float4*)(&As[ty][tx*4]) = av;
    float4 bv = *(const float4*)(ipw + (size_t)(n0 + ar) * COUT + k0 + ac * 4);
    Bs[ac*4+0][ar] = bv.x; Bs[ac*4+1][ar] = bv.y;
    Bs[ac*4+2][ar] = bv.z; Bs[ac*4+3][ar] = bv.w;
    __syncthreads();
#pragma unroll
    for (int kk = 0; kk < 16; ++kk) {
      float4 a4 = *(const float4*)(&As[kk][ty*4]);
      float4 b4 = *(const float4*)(&Bs[kk][tx*4]);
      const float aa[4] = {a4.x, a4.y, a4.z, a4.w};
      const float bb[4] = {b4.x, b4.y, b4.z, b4.w};
#pragma unroll
      for (int i = 0; i < 4; ++i)
#pragma unroll
        for (int j = 0; j < 4; ++j)
          acc[i][j] = fmaf(aa[i], bb[j], acc[i][j]);
    }
    __syncthreads();
  }
  const bool isz = (n0 >= DIN);
  const int eb = isz ? (n0 - DIN) : n0;
  float* outb = isz ? zs : xm_t;
#pragma unroll
  for (int i = 0; i < 4; ++i) {
    const int l = m0 + ty*4 + i;
    float v0 = acc[i][0], v1 = acc[i][1], v2 = acc[i][2], v3 = acc[i][3];
    if (isz) { v0 = siluf(v0); v1 = siluf(v1); v2 = siluf(v2); v3 = siluf(v3); }
    *(float4*)(outb + ((size_t)b*LHW + l)*DIN + eb + tx*4) = make_float4(v0,v1,v2,v3);
  }
}

// ---------------------------------------------------------------------------
// K3: depthwise causal conv1d along l + bias + silu, (b,l,e) layout
// ---------------------------------------------------------------------------
__global__ __launch_bounds__(256)
void k_conv1d(const float* __restrict__ xm_t, const float* __restrict__ cw,
              const float* __restrict__ cb, float* __restrict__ xc_t) {
  const int tid = blockIdx.x * 256 + threadIdx.x;  // NB*LHW*128
  const int e4 = tid & 127;
  const int l  = (tid >> 7) & 4095;
  const int b  = tid >> 19;
  const int e0 = e4 * 4;
  float4 a4 = *(const float4*)(cb + e0);
  float acc[4] = {a4.x, a4.y, a4.z, a4.w};
  float wv[4][4];
#pragma unroll
  for (int q = 0; q < 4; ++q) {
    float4 w4 = *(const float4*)(cw + (e0+q)*4);
    wv[q][0] = w4.x; wv[q][1] = w4.y; wv[q][2] = w4.z; wv[q][3] = w4.w;
  }
  const float* base = xm_t + ((size_t)b*LHW) * DIN + e0;
#pragma unroll
  for (int k = 0; k < 4; ++k) {
    const int ll = l - 3 + k;
    if (ll >= 0) {
      float4 xv = *(const float4*)(base + (size_t)ll*DIN);
      acc[0] = fmaf(xv.x, wv[0][k], acc[0]);
      acc[1] = fmaf(xv.y, wv[1][k], acc[1]);
      acc[2] = fmaf(xv.z, wv[2][k], acc[2]);
      acc[3] = fmaf(xv.w, wv[3][k], acc[3]);
    }
  }
  float4 o = make_float4(siluf(acc[0]), siluf(acc[1]), siluf(acc[2]), siluf(acc[3]));
  *(float4*)(xc_t + ((size_t)b*LHW + l)*DIN + e0) = o;
}

// ---------------------------------------------------------------------------
// K4: proj[b][l][j] = sum_e xpw[j][e] * xc_t[b][l][e], j<48
// ---------------------------------------------------------------------------
__global__ __launch_bounds__(256)
void k_xproj(const float* __restrict__ xc_t, const float* __restrict__ xpw,
             float* __restrict__ proj) {
  __shared__ float xs[16][516];
  const int lg = blockIdx.x * 16;
  const int b  = lg >> 12;
  const int l0 = lg & 4095;
  const int t  = threadIdx.x;
  const float* src = xc_t + ((size_t)(b*LHW + l0)) * DIN;
#pragma unroll
  for (int q = 0; q < 8; ++q) {
    const int f = t + q * 256;
    const int row = f >> 7, col4 = f & 127;
    float4 v = *(const float4*)(src + (size_t)row*DIN + col4*4);
    *(float4*)(&xs[row][col4*4]) = v;
  }
  __syncthreads();
  const int jl = t & 15, li = t >> 4;
  float acc[3] = {0.f, 0.f, 0.f};
  for (int e4 = 0; e4 < 128; ++e4) {
    float4 xv = *(const float4*)(&xs[li][e4*4]);
#pragma unroll
    for (int s = 0; s < 3; ++s) {
      float4 w4 = *(const float4*)(xpw + (size_t)(jl + s*16)*DIN + e4*4);
      acc[s] = fmaf(xv.x, w4.x, acc[s]);
      acc[s] = fmaf(xv.y, w4.y, acc[s]);
      acc[s] = fmaf(xv.z, w4.z, acc[s]);
      acc[s] = fmaf(xv.w, w4.w, acc[s]);
    }
  }
  float* dst = proj + ((size_t)(b*LHW + l0 + li)) * 48;
#pragma unroll
  for (int s = 0; s < 3; ++s) dst[jl + s*16] = acc[s];
}

// ---------------------------------------------------------------------------
// K5: scan phase A — per (b,d,chunk): P = prod dA, S = local end state from h=0
// ---------------------------------------------------------------------------
__global__ __launch_bounds__(256)
void k_scanA(const float* __restrict__ proj, const float* __restrict__ xc_t,
             const float* __restrict__ dtpw, const float* __restrict__ dtpb,
             const float* __restrict__ A_log, float* __restrict__ PS) {
  const int tid = blockIdx.x * 256 + threadIdx.x;  // (b*32 + c)*512 + d
  const int d = tid & 511;
  const int c = (tid >> 9) & 31;
  const int b = tid >> 14;
  float w[16], An[16];
#pragma unroll
  for (int q = 0; q < 4; ++q)
    *(float4*)(&w[q*4]) = *(const float4*)(dtpw + d*16 + q*4);
#pragma unroll
  for (int q = 0; q < 4; ++q) {
    float4 a4 = *(const float4*)(A_log + d*16 + q*4);
    An[q*4+0] = -__expf(a4.x); An[q*4+1] = -__expf(a4.y);
    An[q*4+2] = -__expf(a4.z); An[q*4+3] = -__expf(a4.w);
  }
  const float bias = dtpb[d];
  float h[16], P[16];
#pragma unroll
  for (int n = 0; n < 16; ++n) { h[n] = 0.f; P[n] = 1.f; }
  const size_t rbase = (size_t)(b*LHW + c*CHL);
  const float* pr0 = proj + rbase * 48;
  const float* xc0 = xc_t + rbase * DIN + d;
  for (int i = 0; i < CHL; ++i) {
    const float* pr = pr0 + i * 48;
    float dtl = bias;
#pragma unroll
    for (int q = 0; q < 4; ++q) {
      float4 r4 = *(const float4*)(pr + q*4);
      dtl = fmaf(w[q*4+0], r4.x, dtl);
      dtl = fmaf(w[q*4+1], r4.y, dtl);
      dtl = fmaf(w[q*4+2], r4.z, dtl);
      dtl = fmaf(w[q*4+3], r4.w, dtl);
    }
    const float dt  = splusf(dtl);
    const float xt  = xc0[(size_t)i * DIN];
    const float dtx = dt * xt;
#pragma unroll
    for (int q = 0; q < 4; ++q) {
      float4 B4 = *(const float4*)(pr + 16 + q*4);
      const float bs[4] = {B4.x, B4.y, B4.z, B4.w};
#pragma unroll
      for (int u = 0; u < 4; ++u) {
        const int n = q*4 + u;
        const float dA = __expf(dt * An[n]);
        P[n] *= dA;
        h[n] = fmaf(dA, h[n], dtx * bs[u]);
      }
    }
  }
  float* o = PS + (size_t)tid * 32;
#pragma unroll
  for (int q = 0; q < 4; ++q)
    *(float4*)(o + q*4) = make_float4(P[q*4], P[q*4+1], P[q*4+2], P[q*4+3]);
#pragma unroll
  for (int q = 0; q < 4; ++q)
    *(float4*)(o + 16 + q*4) = make_float4(h[q*4], h[q*4+1], h[q*4+2], h[q*4+3]);
}

// ---------------------------------------------------------------------------
// K6: scan phase B — combine chunk summaries, store chunk-entry states
// ---------------------------------------------------------------------------
__global__ __launch_bounds__(256)
void k_scanB(const float* __restrict__ PS, float* __restrict__ hst) {
  const int tid = blockIdx.x * 256 + threadIdx.x;  // (b*512 + d)*16 + n
  const int n = tid & 15;
  const int d = (tid >> 4) & 511;
  const int b = tid >> 13;
  float h = 0.f;
  for (int c = 0; c < NCHK; ++c) {
    const size_t idx = (size_t)((b*NCHK + c)*512 + d);
    hst[idx*16 + n] = h;
    h = PS[idx*32 + n] * h + PS[idx*32 + 16 + n];
  }
}

// ---------------------------------------------------------------------------
// K7: scan phase C — rescan each chunk from entry state, produce gated y
// ---------------------------------------------------------------------------
__global__ __launch_bounds__(256)
void k_scanC(const float* __restrict__ proj, const float* __restrict__ xc_t,
             const float* __restrict__ zs, const float* __restrict__ hst,
             const float* __restrict__ dtpw, const float* __restrict__ dtpb,
             const float* __restrict__ A_log, const float* __restrict__ Dpar,
             float* __restrict__ ydata) {
  const int tid = blockIdx.x * 256 + threadIdx.x;
  const int d = tid & 511;
  const int c = (tid >> 9) & 31;
  const int b = tid >> 14;
  float w[16], An[16], h[16];
#pragma unroll
  for (int q = 0; q < 4; ++q)
    *(float4*)(&w[q*4]) = *(const float4*)(dtpw + d*16 + q*4);
#pragma unroll
  for (int q = 0; q < 4; ++q) {
    float4 a4 = *(const float4*)(A_log + d*16 + q*4);
    An[q*4+0] = -__expf(a4.x); An[q*4+1] = -__expf(a4.y);
    An[q*4+2] = -__expf(a4.z); An[q*4+3] = -__expf(a4.w);
  }
#pragma unroll
  for (int q = 0; q < 4; ++q) {
    float4 h4 = *(const float4*)(hst + (size_t)tid*16 + q*4);
    h[q*4+0] = h4.x; h[q*4+1] = h4.y; h[q*4+2] = h4.z; h[q*4+3] = h4.w;
  }
  const float bias = dtpb[d];
  const float dp = Dpar[d];
  const size_t rbase = (size_t)(b*LHW + c*CHL);
  const float* pr0 = proj + rbase * 48;
  const float* xc0 = xc_t + rbase * DIN + d;
  const float* zs0 = zs   + rbase * DIN + d;
  float* y0 = ydata + rbase * DIN + d;
  for (int i = 0; i < CHL; ++i) {
    const float* pr = pr0 + i * 48;
    float dtl = bias;
#pragma unroll
    for (int q = 0; q < 4; ++q) {
      float4 r4 = *(const float4*)(pr + q*4);
      dtl = fmaf(w[q*4+0], r4.x, dtl);
      dtl = fmaf(w[q*4+1], r4.y, dtl);
      dtl = fmaf(w[q*4+2], r4.z, dtl);
      dtl = fmaf(w[q*4+3], r4.w, dtl);
    }
    const float dt  = splusf(dtl);
    const float xt  = xc0[(size_t)i * DIN];
    const float dtx = dt * xt;
    float y = 0.f;
#pragma unroll
    for (int q = 0; q < 4; ++q) {
      float4 B4 = *(const float4*)(pr + 16 + q*4);
      float4 C4 = *(const float4*)(pr + 32 + q*4);
      const float bs[4] = {B4.x, B4.y, B4.z, B4.w};
      const float cs[4] = {C4.x, C4.y, C4.z, C4.w};
#pragma unroll
      for (int u = 0; u < 4; ++u) {
        const int n = q*4 + u;
        const float dA = __expf(dt * An[n]);
        h[n] = fmaf(dA, h[n], dtx * bs[u]);
        y = fmaf(h[n], cs[u], y);
      }
    }
    const float ov = (y + xt * dp) * zs0[(size_t)i * DIN];
    y0[(size_t)i * DIN] = ov;
  }
}

// ---------------------------------------------------------------------------
// K8: xr[b][o][l] = xl[b][o][l] + sum_e opw[o][e] * ydata[b][l][e]
// ---------------------------------------------------------------------------
__global__ __launch_bounds__(256)
void k_outproj(const float* __restrict__ ydata, const float* __restrict__ opw,
               const float* __restrict__ xl, float* __restrict__ xr) {
  __shared__ float As[16][68];  // [k=e][m=o]
  __shared__ float Bs[16][68];  // [k=e][n=l]
  const int b  = blockIdx.z;
  const int m0 = blockIdx.y * 64;  // o
  const int n0 = blockIdx.x * 64;  // l
  const int tid = threadIdx.x;
  const int tx = tid & 15, ty = tid >> 4;
  const int ar = tid >> 2, ac = tid & 3;
  float acc[4][4] = {};
  const float* yb = ydata + (size_t)b * LHW * DIN;
  for (int k0 = 0; k0 < DIN; k0 += 16) {
    float4 av = *(const float4*)(opw + (size_t)(m0 + ar) * DIN + k0 + ac * 4);
    As[ac*4+0][ar] = av.x; As[ac*4+1][ar] = av.y;
    As[ac*4+2][ar] = av.z; As[ac*4+3][ar] = av.w;
    float4 bv = *(const float4*)(yb + (size_t)(n0 + ar) * DIN + k0 + ac * 4);
    Bs[ac*4+0][ar] = bv.x; Bs[ac*4+1][ar] = bv.y;
    Bs[ac*4+2][ar] = bv.z; Bs[ac*4+3][ar] = bv.w;
    __syncthreads();
#pragma unroll
    for (int kk = 0; kk < 16; ++kk) {
      float4 a4 = *(const float4*)(&As[kk][ty*4]);
      float4 b4 = *(const float4*)(&Bs[kk][tx*4]);
      const float aa[4] = {a4.x, a4.y, a4.z, a4.w};
      const float bb[4] = {b4.x, b4.y, b4.z, b4.w};
#pragma unroll
      for (int i = 0; i < 4; ++i)
#pragma unroll
        for (int j = 0; j < 4; ++j)
          acc[i][j] = fmaf(aa[i], bb[j], acc[i][j]);
    }
    __syncthreads();
  }
#pragma unroll
  for (int i = 0; i < 4; ++i) {
    const int m = m0 + ty*4 + i;
    const size_t off = ((size_t)b*COUT + m)*LHW + n0 + tx*4;
    float4 r = *(const float4*)(xl + off);
    float4 o = make_float4(acc[i][0]+r.x, acc[i][1]+r.y, acc[i][2]+r.z, acc[i][3]+r.w);
    *(float4*)(xr + off) = o;
  }
}

// ---------------------------------------------------------------------------
// K9: refine 3x3 conv (pad 1) + BN + ReLU
// ---------------------------------------------------------------------------
__global__ __launch_bounds__(256)
void k_refine(const float* __restrict__ xr, const float* __restrict__ rw,
              const float* __restrict__ rb, const float* __restrict__ bng,
              const float* __restrict__ bnb, const float* __restrict__ bnm,
              const float* __restrict__ bnv, float* __restrict__ out) {
  __shared__ float wl[COUT * 9];
  const int o = blockIdx.y;
  const int b = blockIdx.z;
  const int ybase = blockIdx.x * 16;
  const int t = threadIdx.x;
  const float* wsrc = rw + (size_t)o * COUT * 9;
  for (int f = t; f < COUT * 9; f += 256) wl[f] = wsrc[f];
  __syncthreads();
  const int tx = t & 15, ty = t >> 4;
  const int y = ybase + ty, x0 = tx * 4;
  float acc0 = 0.f, acc1 = 0.f, acc2 = 0.f, acc3 = 0.f;
  const float* xb = xr + (size_t)b * COUT * LHW;
#pragma unroll 2
  for (int i = 0; i < COUT; ++i) {
    const float* wr = &wl[i * 9];
    const float* rowb = xb + (size_t)i * LHW;
#pragma unroll
    for (int ky = 0; ky < 3; ++ky) {
      const int yy = y + ky - 1;
      if (yy < 0 || yy > 63) continue;
      const float* row = rowb + yy * 64;
      float4 v = *(const float4*)(row + x0);
      const float lm = (x0 > 0)  ? row[x0 - 1] : 0.f;
      const float rp = (x0 < 60) ? row[x0 + 4] : 0.f;
      const float w0 = wr[ky*3+0], w1 = wr[ky*3+1], w2 = wr[ky*3+2];
      acc0 = fmaf(w0, lm,  fmaf(w1, v.x, fmaf(w2, v.y, acc0)));
      acc1 = fmaf(w0, v.x, fmaf(w1, v.y, fmaf(w2, v.z, acc1)));
      acc2 = fmaf(w0, v.y, fmaf(w1, v.z, fmaf(w2, v.w, acc2)));
      acc3 = fmaf(w0, v.z, fmaf(w1, v.w, fmaf(w2, rp,  acc3)));
    }
  }
  const float inv = bng[o] * rsqrtf(bnv[o] + 1e-5f);
  const float sh  = (rb[o] - bnm[o]) * inv + bnb[o];
  float4 res;
  res.x = fmaxf(fmaf(acc0, inv, sh), 0.f);
  res.y = fmaxf(fmaf(acc1, inv, sh), 0.f);
  res.z = fmaxf(fmaf(acc2, inv, sh), 0.f);
  res.w = fmaxf(fmaf(acc3, inv, sh), 0.f);
  *(float4*)(out + (((size_t)b*COUT + o)*64 + y)*64 + x0) = res;
}

// ---------------------------------------------------------------------------
extern "C" void kernel_launch(void* const* d_in, const int* in_sizes, int n_in,
                              void* d_out, int out_size, void* d_ws, size_t ws_size,
                              hipStream_t stream) {
  const float* x    = (const float*)d_in[0];
  const float* lw   = (const float*)d_in[1];
  const float* lb   = (const float*)d_in[2];
  const float* ipw  = (const float*)d_in[3];
  const float* cw   = (const float*)d_in[4];
  const float* cb   = (const float*)d_in[5];
  const float* xpw  = (const float*)d_in[6];
  const float* dtpw = (const float*)d_in[7];
  const float* dtpb = (const float*)d_in[8];
  const float* Alog = (const float*)d_in[9];
  const float* Dpar = (const float*)d_in[10];
  const float* opw  = (const float*)d_in[11];
  const float* rw   = (const float*)d_in[12];
  const float* rb   = (const float*)d_in[13];
  const float* bng  = (const float*)d_in[14];
  const float* bnb  = (const float*)d_in[15];
  const float* bnm  = (const float*)d_in[16];
  const float* bnv  = (const float*)d_in[17];
  float* out = (float*)d_out;

  float* ws   = (float*)d_ws;
  float* xl   = ws;                                   //  8,388,608 f
  float* xm_t = xl   + (size_t)NB*COUT*LHW;           // 16,777,216 f (reused as ydata)
  float* zs   = xm_t + (size_t)NB*LHW*DIN;            // 16,777,216 f (reused as xr)
  float* xc_t = zs   + (size_t)NB*LHW*DIN;            // 16,777,216 f
  float* proj = xc_t + (size_t)NB*LHW*DIN;            //  1,572,864 f
  float* PS   = proj + (size_t)NB*LHW*48;             //  4,194,304 f
  float* hst  = PS   + (size_t)NB*DIN*NCHK*32;        //  2,097,152 f
  float* ydata = xm_t;
  float* xr    = zs;

  k_lateral<<<dim3(64, 4, 8), 256, 0, stream>>>(x, lw, lb, xl);
  k_inproj <<<dim3(16, 64, 8), 256, 0, stream>>>(xl, ipw, xm_t, zs);
  k_conv1d <<<dim3(16384), 256, 0, stream>>>(xm_t, cw, cb, xc_t);
  k_xproj  <<<dim3(2048), 256, 0, stream>>>(xc_t, xpw, proj);
  k_scanA  <<<dim3(512), 256, 0, stream>>>(proj, xc_t, dtpw, dtpb, Alog, PS);
  k_scanB  <<<dim3(256), 256, 0, stream>>>(PS, hst);
  k_scanC  <<<dim3(512), 256, 0, stream>>>(proj, xc_t, zs, hst, dtpw, dtpb, Alog, Dpar, ydata);
  k_outproj<<<dim3(64, 4, 8), 256, 0, stream>>>(ydata, opw, xl, xr);
  k_refine <<<dim3(4, 256, 8), 256, 0, stream>>>(xr, rw, rb, bng, bnb, bnm, bnv, out);
}

// Round 2
// 1227.792 us; speedup vs baseline: 4.2872x; 4.2872x over previous
//
#include <hip/hip_runtime.h>
#include <math.h>

#define NB   8
#define CIN  512
#define COUT 256
#define DIN  512
#define LHW  4096
#define NCHK 32
#define CHL  128
#define PW   66          // padded spatial width/height
#define PPOS (PW*PW)     // 4356 padded positions

typedef __attribute__((ext_vector_type(8))) short bf16x8;
typedef __attribute__((ext_vector_type(4))) float f32x4;

__device__ __forceinline__ float siluf(float v)  { return v / (1.f + __expf(-v)); }
__device__ __forceinline__ float splusf(float v) { return v > 20.f ? v : log1pf(__expf(v)); }

__device__ __forceinline__ unsigned short f2b(float f) {
  union { float f; unsigned u; } v; v.f = f;
  unsigned r = v.u + 0x7fff + ((v.u >> 16) & 1);
  return (unsigned short)(r >> 16);
}

__device__ __forceinline__ void gload16(const unsigned short* g, unsigned short* l) {
  __builtin_amdgcn_global_load_lds(
      (const __attribute__((address_space(1))) unsigned int*)g,
      (__attribute__((address_space(3))) unsigned int*)l, 16, 0, 0);
}

// ---------------------------------------------------------------------------
// K1: xl[b][o][l] = sum_k lw[o][k] * x[b][k][l] + lb[o]
// ---------------------------------------------------------------------------
__global__ __launch_bounds__(256)
void k_lateral(const float* __restrict__ x, const float* __restrict__ lw,
               const float* __restrict__ lb, float* __restrict__ xl) {
  __shared__ float As[16][68];
  __shared__ float Bs[16][68];
  const int b  = blockIdx.z;
  const int m0 = blockIdx.y * 64;
  const int n0 = blockIdx.x * 64;
  const int tid = threadIdx.x;
  const int tx = tid & 15, ty = tid >> 4;
  const int ar = tid >> 2, ac = tid & 3;
  float acc[4][4] = {};
  const float* xb = x + (size_t)b * CIN * LHW;
  for (int k0 = 0; k0 < CIN; k0 += 16) {
    float4 av = *(const float4*)(lw + (size_t)(m0 + ar) * CIN + k0 + ac * 4);
    As[ac*4+0][ar] = av.x; As[ac*4+1][ar] = av.y;
    As[ac*4+2][ar] = av.z; As[ac*4+3][ar] = av.w;
    float4 bv = *(const float4*)(xb + (size_t)(k0 + ty) * LHW + n0 + tx * 4);
    *(float4*)(&Bs[ty][tx*4]) = bv;
    __syncthreads();
#pragma unroll
    for (int kk = 0; kk < 16; ++kk) {
      float4 a4 = *(const float4*)(&As[kk][ty*4]);
      float4 b4 = *(const float4*)(&Bs[kk][tx*4]);
      const float aa[4] = {a4.x, a4.y, a4.z, a4.w};
      const float bb[4] = {b4.x, b4.y, b4.z, b4.w};
#pragma unroll
      for (int i = 0; i < 4; ++i)
#pragma unroll
        for (int j = 0; j < 4; ++j)
          acc[i][j] = fmaf(aa[i], bb[j], acc[i][j]);
    }
    __syncthreads();
  }
#pragma unroll
  for (int i = 0; i < 4; ++i) {
    const int m = m0 + ty*4 + i;
    const float bias = lb[m];
    float4 o = make_float4(acc[i][0]+bias, acc[i][1]+bias, acc[i][2]+bias, acc[i][3]+bias);
    *(float4*)(xl + ((size_t)b*COUT + m)*LHW + n0 + tx*4) = o;
  }
}

// ---------------------------------------------------------------------------
// K2: xz[b][l][e] = sum_d ipw[e][d] * xl[b][d][l]; e<512 -> xm_t ; e>=512 -> silu -> zs
// ---------------------------------------------------------------------------
__global__ __launch_bounds__(256)
void k_inproj(const float* __restrict__ xl, const float* __restrict__ ipw,
              float* __restrict__ xm_t, float* __restrict__ zs) {
  __shared__ float As[16][68];
  __shared__ float Bs[16][68];
  const int b  = blockIdx.z;
  const int m0 = blockIdx.y * 64;  // l
  const int n0 = blockIdx.x * 64;  // e
  const int tid = threadIdx.x;
  const int tx = tid & 15, ty = tid >> 4;
  const int ar = tid >> 2, ac = tid & 3;
  float acc[4][4] = {};
  const float* xlb = xl + (size_t)b * COUT * LHW;
  for (int k0 = 0; k0 < COUT; k0 += 16) {
    float4 av = *(const float4*)(xlb + (size_t)(k0 + ty) * LHW + m0 + tx * 4);
    *(float4*)(&As[ty][tx*4]) = av;
    float4 bv = *(const float4*)(ipw + (size_t)(n0 + ar) * COUT + k0 + ac * 4);
    Bs[ac*4+0][ar] = bv.x; Bs[ac*4+1][ar] = bv.y;
    Bs[ac*4+2][ar] = bv.z; Bs[ac*4+3][ar] = bv.w;
    __syncthreads();
#pragma unroll
    for (int kk = 0; kk < 16; ++kk) {
      float4 a4 = *(const float4*)(&As[kk][ty*4]);
      float4 b4 = *(const float4*)(&Bs[kk][tx*4]);
      const float aa[4] = {a4.x, a4.y, a4.z, a4.w};
      const float bb[4] = {b4.x, b4.y, b4.z, b4.w};
#pragma unroll
      for (int i = 0; i < 4; ++i)
#pragma unroll
        for (int j = 0; j < 4; ++j)
          acc[i][j] = fmaf(aa[i], bb[j], acc[i][j]);
    }
    __syncthreads();
  }
  const bool isz = (n0 >= DIN);
  const int eb = isz ? (n0 - DIN) : n0;
  float* outb = isz ? zs : xm_t;
#pragma unroll
  for (int i = 0; i < 4; ++i) {
    const int l = m0 + ty*4 + i;
    float v0 = acc[i][0], v1 = acc[i][1], v2 = acc[i][2], v3 = acc[i][3];
    if (isz) { v0 = siluf(v0); v1 = siluf(v1); v2 = siluf(v2); v3 = siluf(v3); }
    *(float4*)(outb + ((size_t)b*LHW + l)*DIN + eb + tx*4) = make_float4(v0,v1,v2,v3);
  }
}

// ---------------------------------------------------------------------------
// K3: depthwise causal conv1d along l + bias + silu, (b,l,e) layout
// ---------------------------------------------------------------------------
__global__ __launch_bounds__(256)
void k_conv1d(const float* __restrict__ xm_t, const float* __restrict__ cw,
              const float* __restrict__ cb, float* __restrict__ xc_t) {
  const int tid = blockIdx.x * 256 + threadIdx.x;
  const int e4 = tid & 127;
  const int l  = (tid >> 7) & 4095;
  const int b  = tid >> 19;
  const int e0 = e4 * 4;
  float4 a4 = *(const float4*)(cb + e0);
  float acc[4] = {a4.x, a4.y, a4.z, a4.w};
  float wv[4][4];
#pragma unroll
  for (int q = 0; q < 4; ++q) {
    float4 w4 = *(const float4*)(cw + (e0+q)*4);
    wv[q][0] = w4.x; wv[q][1] = w4.y; wv[q][2] = w4.z; wv[q][3] = w4.w;
  }
  const float* base = xm_t + ((size_t)b*LHW) * DIN + e0;
#pragma unroll
  for (int k = 0; k < 4; ++k) {
    const int ll = l - 3 + k;
    if (ll >= 0) {
      float4 xv = *(const float4*)(base + (size_t)ll*DIN);
      acc[0] = fmaf(xv.x, wv[0][k], acc[0]);
      acc[1] = fmaf(xv.y, wv[1][k], acc[1]);
      acc[2] = fmaf(xv.z, wv[2][k], acc[2]);
      acc[3] = fmaf(xv.w, wv[3][k], acc[3]);
    }
  }
  float4 o = make_float4(siluf(acc[0]), siluf(acc[1]), siluf(acc[2]), siluf(acc[3]));
  *(float4*)(xc_t + ((size_t)b*LHW + l)*DIN + e0) = o;
}

// ---------------------------------------------------------------------------
// K4: proj[b][l][j] = sum_e xpw[j][e] * xc_t[b][l][e], j<48
// ---------------------------------------------------------------------------
__global__ __launch_bounds__(256)
void k_xproj(const float* __restrict__ xc_t, const float* __restrict__ xpw,
             float* __restrict__ proj) {
  __shared__ float xs[16][516];
  const int lg = blockIdx.x * 16;
  const int b  = lg >> 12;
  const int l0 = lg & 4095;
  const int t  = threadIdx.x;
  const float* src = xc_t + ((size_t)(b*LHW + l0)) * DIN;
#pragma unroll
  for (int q = 0; q < 8; ++q) {
    const int f = t + q * 256;
    const int row = f >> 7, col4 = f & 127;
    float4 v = *(const float4*)(src + (size_t)row*DIN + col4*4);
    *(float4*)(&xs[row][col4*4]) = v;
  }
  __syncthreads();
  const int jl = t & 15, li = t >> 4;
  float acc[3] = {0.f, 0.f, 0.f};
  for (int e4 = 0; e4 < 128; ++e4) {
    float4 xv = *(const float4*)(&xs[li][e4*4]);
#pragma unroll
    for (int s = 0; s < 3; ++s) {
      float4 w4 = *(const float4*)(xpw + (size_t)(jl + s*16)*DIN + e4*4);
      acc[s] = fmaf(xv.x, w4.x, acc[s]);
      acc[s] = fmaf(xv.y, w4.y, acc[s]);
      acc[s] = fmaf(xv.z, w4.z, acc[s]);
      acc[s] = fmaf(xv.w, w4.w, acc[s]);
    }
  }
  float* dst = proj + ((size_t)(b*LHW + l0 + li)) * 48;
#pragma unroll
  for (int s = 0; s < 3; ++s) dst[jl + s*16] = acc[s];
}

// ---------------------------------------------------------------------------
// K5: scan phase A
// ---------------------------------------------------------------------------
__global__ __launch_bounds__(256)
void k_scanA(const float* __restrict__ proj, const float* __restrict__ xc_t,
             const float* __restrict__ dtpw, const float* __restrict__ dtpb,
             const float* __restrict__ A_log, float* __restrict__ PS) {
  const int tid = blockIdx.x * 256 + threadIdx.x;
  const int d = tid & 511;
  const int c = (tid >> 9) & 31;
  const int b = tid >> 14;
  float w[16], An[16];
#pragma unroll
  for (int q = 0; q < 4; ++q)
    *(float4*)(&w[q*4]) = *(const float4*)(dtpw + d*16 + q*4);
#pragma unroll
  for (int q = 0; q < 4; ++q) {
    float4 a4 = *(const float4*)(A_log + d*16 + q*4);
    An[q*4+0] = -__expf(a4.x); An[q*4+1] = -__expf(a4.y);
    An[q*4+2] = -__expf(a4.z); An[q*4+3] = -__expf(a4.w);
  }
  const float bias = dtpb[d];
  float h[16], P[16];
#pragma unroll
  for (int n = 0; n < 16; ++n) { h[n] = 0.f; P[n] = 1.f; }
  const size_t rbase = (size_t)(b*LHW + c*CHL);
  const float* pr0 = proj + rbase * 48;
  const float* xc0 = xc_t + rbase * DIN + d;
  for (int i = 0; i < CHL; ++i) {
    const float* pr = pr0 + i * 48;
    float dtl = bias;
#pragma unroll
    for (int q = 0; q < 4; ++q) {
      float4 r4 = *(const float4*)(pr + q*4);
      dtl = fmaf(w[q*4+0], r4.x, dtl);
      dtl = fmaf(w[q*4+1], r4.y, dtl);
      dtl = fmaf(w[q*4+2], r4.z, dtl);
      dtl = fmaf(w[q*4+3], r4.w, dtl);
    }
    const float dt  = splusf(dtl);
    const float xt  = xc0[(size_t)i * DIN];
    const float dtx = dt * xt;
#pragma unroll
    for (int q = 0; q < 4; ++q) {
      float4 B4 = *(const float4*)(pr + 16 + q*4);
      const float bs[4] = {B4.x, B4.y, B4.z, B4.w};
#pragma unroll
      for (int u = 0; u < 4; ++u) {
        const int n = q*4 + u;
        const float dA = __expf(dt * An[n]);
        P[n] *= dA;
        h[n] = fmaf(dA, h[n], dtx * bs[u]);
      }
    }
  }
  float* o = PS + (size_t)tid * 32;
#pragma unroll
  for (int q = 0; q < 4; ++q)
    *(float4*)(o + q*4) = make_float4(P[q*4], P[q*4+1], P[q*4+2], P[q*4+3]);
#pragma unroll
  for (int q = 0; q < 4; ++q)
    *(float4*)(o + 16 + q*4) = make_float4(h[q*4], h[q*4+1], h[q*4+2], h[q*4+3]);
}

// ---------------------------------------------------------------------------
// K6: scan phase B
// ---------------------------------------------------------------------------
__global__ __launch_bounds__(256)
void k_scanB(const float* __restrict__ PS, float* __restrict__ hst) {
  const int tid = blockIdx.x * 256 + threadIdx.x;
  const int n = tid & 15;
  const int d = (tid >> 4) & 511;
  const int b = tid >> 13;
  float h = 0.f;
  for (int c = 0; c < NCHK; ++c) {
    const size_t idx = (size_t)((b*NCHK + c)*512 + d);
    hst[idx*16 + n] = h;
    h = PS[idx*32 + n] * h + PS[idx*32 + 16 + n];
  }
}

// ---------------------------------------------------------------------------
// K7: scan phase C
// ---------------------------------------------------------------------------
__global__ __launch_bounds__(256)
void k_scanC(const float* __restrict__ proj, const float* __restrict__ xc_t,
             const float* __restrict__ zs, const float* __restrict__ hst,
             const float* __restrict__ dtpw, const float* __restrict__ dtpb,
             const float* __restrict__ A_log, const float* __restrict__ Dpar,
             float* __restrict__ ydata) {
  const int tid = blockIdx.x * 256 + threadIdx.x;
  const int d = tid & 511;
  const int c = (tid >> 9) & 31;
  const int b = tid >> 14;
  float w[16], An[16], h[16];
#pragma unroll
  for (int q = 0; q < 4; ++q)
    *(float4*)(&w[q*4]) = *(const float4*)(dtpw + d*16 + q*4);
#pragma unroll
  for (int q = 0; q < 4; ++q) {
    float4 a4 = *(const float4*)(A_log + d*16 + q*4);
    An[q*4+0] = -__expf(a4.x); An[q*4+1] = -__expf(a4.y);
    An[q*4+2] = -__expf(a4.z); An[q*4+3] = -__expf(a4.w);
  }
#pragma unroll
  for (int q = 0; q < 4; ++q) {
    float4 h4 = *(const float4*)(hst + (size_t)tid*16 + q*4);
    h[q*4+0] = h4.x; h[q*4+1] = h4.y; h[q*4+2] = h4.z; h[q*4+3] = h4.w;
  }
  const float bias = dtpb[d];
  const float dp = Dpar[d];
  const size_t rbase = (size_t)(b*LHW + c*CHL);
  const float* pr0 = proj + rbase * 48;
  const float* xc0 = xc_t + rbase * DIN + d;
  const float* zs0 = zs   + rbase * DIN + d;
  float* y0 = ydata + rbase * DIN + d;
  for (int i = 0; i < CHL; ++i) {
    const float* pr = pr0 + i * 48;
    float dtl = bias;
#pragma unroll
    for (int q = 0; q < 4; ++q) {
      float4 r4 = *(const float4*)(pr + q*4);
      dtl = fmaf(w[q*4+0], r4.x, dtl);
      dtl = fmaf(w[q*4+1], r4.y, dtl);
      dtl = fmaf(w[q*4+2], r4.z, dtl);
      dtl = fmaf(w[q*4+3], r4.w, dtl);
    }
    const float dt  = splusf(dtl);
    const float xt  = xc0[(size_t)i * DIN];
    const float dtx = dt * xt;
    float y = 0.f;
#pragma unroll
    for (int q = 0; q < 4; ++q) {
      float4 B4 = *(const float4*)(pr + 16 + q*4);
      float4 C4 = *(const float4*)(pr + 32 + q*4);
      const float bs[4] = {B4.x, B4.y, B4.z, B4.w};
      const float cs[4] = {C4.x, C4.y, C4.z, C4.w};
#pragma unroll
      for (int u = 0; u < 4; ++u) {
        const int n = q*4 + u;
        const float dA = __expf(dt * An[n]);
        h[n] = fmaf(dA, h[n], dtx * bs[u]);
        y = fmaf(h[n], cs[u], y);
      }
    }
    const float ov = (y + xt * dp) * zs0[(size_t)i * DIN];
    y0[(size_t)i * DIN] = ov;
  }
}

// ---------------------------------------------------------------------------
// K8: outproj + residual, writes padded channel-last bf16 xrp[b][pos][i]
// ---------------------------------------------------------------------------
__global__ __launch_bounds__(256)
void k_outproj(const float* __restrict__ ydata, const float* __restrict__ opw,
               const float* __restrict__ xl, unsigned short* __restrict__ xrp) {
  __shared__ float As[16][68];  // [k=e][m=o]
  __shared__ float Bs[16][68];  // [k=e][n=l]
  __shared__ unsigned short T[64][72];
  const int b  = blockIdx.z;
  const int m0 = blockIdx.y * 64;  // o
  const int n0 = blockIdx.x * 64;  // l
  const int tid = threadIdx.x;
  const int tx = tid & 15, ty = tid >> 4;
  const int ar = tid >> 2, ac = tid & 3;
  float acc[4][4] = {};
  const float* yb = ydata + (size_t)b * LHW * DIN;
  for (int k0 = 0; k0 < DIN; k0 += 16) {
    float4 av = *(const float4*)(opw + (size_t)(m0 + ar) * DIN + k0 + ac * 4);
    As[ac*4+0][ar] = av.x; As[ac*4+1][ar] = av.y;
    As[ac*4+2][ar] = av.z; As[ac*4+3][ar] = av.w;
    float4 bv = *(const float4*)(yb + (size_t)(n0 + ar) * DIN + k0 + ac * 4);
    Bs[ac*4+0][ar] = bv.x; Bs[ac*4+1][ar] = bv.y;
    Bs[ac*4+2][ar] = bv.z; Bs[ac*4+3][ar] = bv.w;
    __syncthreads();
#pragma unroll
    for (int kk = 0; kk < 16; ++kk) {
      float4 a4 = *(const float4*)(&As[kk][ty*4]);
      float4 b4 = *(const float4*)(&Bs[kk][tx*4]);
      const float aa[4] = {a4.x, a4.y, a4.z, a4.w};
      const float bb[4] = {b4.x, b4.y, b4.z, b4.w};
#pragma unroll
      for (int i = 0; i < 4; ++i)
#pragma unroll
        for (int j = 0; j < 4; ++j)
          acc[i][j] = fmaf(aa[i], bb[j], acc[i][j]);
    }
    __syncthreads();
  }
  // add residual xl, convert to bf16, transpose via LDS
#pragma unroll
  for (int i = 0; i < 4; ++i) {
    const int m = ty*4 + i;
    const size_t off = ((size_t)b*COUT + m0 + m)*LHW + n0 + tx*4;
    float4 r = *(const float4*)(xl + off);
    T[tx*4+0][m] = f2b(acc[i][0] + r.x);
    T[tx*4+1][m] = f2b(acc[i][1] + r.y);
    T[tx*4+2][m] = f2b(acc[i][2] + r.z);
    T[tx*4+3][m] = f2b(acc[i][3] + r.w);
  }
  __syncthreads();
  // write channel-last: xrp[b][(y+1)*66 + x+1][m0 + 0..63]
  const int nl = tid >> 2;        // 0..63 (x)
  const int ic = tid & 3;         // 16-channel chunk
  const int y  = n0 >> 6;
  const int pos = (y + 1) * PW + nl + 1;
  uint4 v0 = *(const uint4*)&T[nl][ic*16];
  uint4 v1 = *(const uint4*)&T[nl][ic*16 + 8];
  unsigned short* dst = xrp + ((size_t)b*PPOS + pos)*COUT + m0 + ic*16;
  *(uint4*)dst = v0;
  *(uint4*)(dst + 8) = v1;
}

// ---------------------------------------------------------------------------
// K9a: reorder refine weights tap-major, bf16: Aw[o][tap*256+i] = rw[o][i][tap]
// ---------------------------------------------------------------------------
__global__ __launch_bounds__(256)
void k_wprep(const float* __restrict__ rw, unsigned short* __restrict__ Aw) {
  const int tid = blockIdx.x * 256 + threadIdx.x;   // 256*2304
  const int o = tid / 2304, kk = tid % 2304;
  const int tap = kk >> 8, i = kk & 255;
  Aw[tid] = f2b(rw[(o*256 + i)*9 + tap]);
}

// ---------------------------------------------------------------------------
// K9b: refine 3x3 conv as MFMA implicit GEMM + BN + ReLU
//   M=256 (o), N=4096/batch (yx), K=2304 (tap-major: tap*256+i)
//   128x128 tile, BK=32, 4 waves (2x2), 16x16x32 bf16 MFMA
// ---------------------------------------------------------------------------
__global__ __launch_bounds__(256)
void k_refine_mfma(const unsigned short* __restrict__ Aw,
                   const unsigned short* __restrict__ xrp,
                   const float* __restrict__ rb, const float* __restrict__ bng,
                   const float* __restrict__ bnb, const float* __restrict__ bnm,
                   const float* __restrict__ bnv, float* __restrict__ out) {
  __shared__ unsigned short As[128*32];   // [m][k] 8 KB
  __shared__ unsigned short Bs[128*32];   // [n][k] 8 KB
  const int t = threadIdx.x;
  const int lane = t & 63;
  const int w = t >> 6;
  const int wm = w >> 1, wn = w & 1;
  const int b  = blockIdx.z;
  const int m0 = blockIdx.y * 128;
  const int n0 = blockIdx.x * 128;
  const int y0 = n0 >> 6;                 // tile covers output rows y0, y0+1

  const unsigned short* xb = xrp + (size_t)b * PPOS * COUT;

  const int arow = t >> 2;                // 0..63
  const int acol = (t & 3) * 8;           // k-slice within 32
  unsigned short* aL0 = &As[w * 512];
  unsigned short* aL1 = &As[2048 + w * 512];
  unsigned short* bL0 = &Bs[w * 512];
  unsigned short* bL1 = &Bs[2048 + w * 512];

  f32x4 acc[4][4] = {};

  for (int ks = 0; ks < 72; ++ks) {
    const int tap = ks >> 3;
    const int i0  = (ks & 7) * 32;
    const int ky  = tap / 3, kx = tap - ky * 3;
    const int k0  = tap * 256 + i0;
    const unsigned short* ga0 = Aw + (size_t)(m0 + arow) * 2304 + k0 + acol;
    const unsigned short* gb0 = xb + ((size_t)((y0 + ky) * PW + kx + arow)) * COUT + i0 + acol;
    __syncthreads();
    gload16(ga0,              aL0);
    gload16(ga0 + 64 * 2304,  aL1);
    gload16(gb0,              bL0);
    gload16(gb0 + PW * COUT,  bL1);
    __syncthreads();
    const int fr = lane & 15, g8 = (lane >> 4) * 8;
    bf16x8 af[4], bfr[4];
#pragma unroll
    for (int f = 0; f < 4; ++f) {
      af[f]  = *(const bf16x8*)&As[(wm*64 + f*16 + fr) * 32 + g8];
      bfr[f] = *(const bf16x8*)&Bs[(wn*64 + f*16 + fr) * 32 + g8];
    }
#pragma unroll
    for (int i = 0; i < 4; ++i)
#pragma unroll
      for (int j = 0; j < 4; ++j)
        acc[i][j] = __builtin_amdgcn_mfma_f32_16x16x32_bf16(af[i], bfr[j], acc[i][j], 0, 0, 0);
  }
  // epilogue: BN + ReLU, C/D layout: col=lane&15, row=(lane>>4)*4+reg
  const int fr = lane & 15, q4 = (lane >> 4) * 4;
#pragma unroll
  for (int i = 0; i < 4; ++i) {
    const int obase = m0 + wm*64 + i*16 + q4;
#pragma unroll
    for (int q = 0; q < 4; ++q) {
      const int o = obase + q;
      const float inv = bng[o] * rsqrtf(bnv[o] + 1e-5f);
      const float sh  = (rb[o] - bnm[o]) * inv + bnb[o];
      float* orow = out + ((size_t)b * COUT + o) * LHW + n0 + wn*64 + fr;
#pragma unroll
      for (int j = 0; j < 4; ++j)
        orow[j*16] = fmaxf(fmaf(acc[i][j][q], inv, sh), 0.f);
    }
  }
}

// ---------------------------------------------------------------------------
extern "C" void kernel_launch(void* const* d_in, const int* in_sizes, int n_in,
                              void* d_out, int out_size, void* d_ws, size_t ws_size,
                              hipStream_t stream) {
  const float* x    = (const float*)d_in[0];
  const float* lw   = (const float*)d_in[1];
  const float* lb   = (const float*)d_in[2];
  const float* ipw  = (const float*)d_in[3];
  const float* cw   = (const float*)d_in[4];
  const float* cb   = (const float*)d_in[5];
  const float* xpw  = (const float*)d_in[6];
  const float* dtpw = (const float*)d_in[7];
  const float* dtpb = (const float*)d_in[8];
  const float* Alog = (const float*)d_in[9];
  const float* Dpar = (const float*)d_in[10];
  const float* opw  = (const float*)d_in[11];
  const float* rw   = (const float*)d_in[12];
  const float* rb   = (const float*)d_in[13];
  const float* bng  = (const float*)d_in[14];
  const float* bnb  = (const float*)d_in[15];
  const float* bnm  = (const float*)d_in[16];
  const float* bnv  = (const float*)d_in[17];
  float* out = (float*)d_out;

  float* ws   = (float*)d_ws;
  float* xl   = ws;                                   //  8,388,608 f
  float* xm_t = xl   + (size_t)NB*COUT*LHW;           // 16,777,216 f (reused as ydata)
  float* zs   = xm_t + (size_t)NB*LHW*DIN;            // 16,777,216 f (reused as xrp bf16)
  float* xc_t = zs   + (size_t)NB*LHW*DIN;            // 16,777,216 f
  float* proj = xc_t + (size_t)NB*LHW*DIN;            //  1,572,864 f
  float* PS   = proj + (size_t)NB*LHW*48;             //  4,194,304 f
  float* hst  = PS   + (size_t)NB*DIN*NCHK*32;        //  2,097,152 f
  unsigned short* Aw = (unsigned short*)(hst + (size_t)NB*DIN*NCHK*16);  // 589,824 bf16
  float* ydata = xm_t;
  unsigned short* xrp = (unsigned short*)zs;          // [NB][PPOS][COUT] bf16

  k_wprep  <<<dim3(2304), 256, 0, stream>>>(rw, Aw);
  k_lateral<<<dim3(64, 4, 8), 256, 0, stream>>>(x, lw, lb, xl);
  k_inproj <<<dim3(16, 64, 8), 256, 0, stream>>>(xl, ipw, xm_t, zs);
  k_conv1d <<<dim3(16384), 256, 0, stream>>>(xm_t, cw, cb, xc_t);
  k_xproj  <<<dim3(2048), 256, 0, stream>>>(xc_t, xpw, proj);
  k_scanA  <<<dim3(512), 256, 0, stream>>>(proj, xc_t, dtpw, dtpb, Alog, PS);
  k_scanB  <<<dim3(256), 256, 0, stream>>>(PS, hst);
  k_scanC  <<<dim3(512), 256, 0, stream>>>(proj, xc_t, zs, hst, dtpw, dtpb, Alog, Dpar, ydata);
  hipMemsetAsync(xrp, 0, (size_t)NB * PPOS * COUT * sizeof(unsigned short), stream);
  k_outproj<<<dim3(64, 4, 8), 256, 0, stream>>>(ydata, opw, xl, xrp);
  k_refine_mfma<<<dim3(32, 2, 8), 256, 0, stream>>>(Aw, xrp, rb, bng, bnb, bnm, bnv, out);
}

// Round 3
// 540.370 us; speedup vs baseline: 9.7412x; 2.2721x over previous
//
#include <hip/hip_runtime.h>
#include <math.h>

#define NB   8
#define CIN  512
#define COUT 256
#define DIN  512
#define LHW  4096
#define NCHK 32
#define CHL  128
#define PW   66
#define PPOS (PW*PW)

typedef __attribute__((ext_vector_type(8))) short bf16x8;
typedef __attribute__((ext_vector_type(4))) float f32x4;
typedef unsigned short ushort_t;

__device__ __forceinline__ float siluf(float v)  { return v / (1.f + __expf(-v)); }
__device__ __forceinline__ float splusf(float v) { return v > 20.f ? v : log1pf(__expf(v)); }

__device__ __forceinline__ unsigned short f2b(float f) {
  union { float f; unsigned u; } v; v.f = f;
  unsigned r = v.u + 0x7fff + ((v.u >> 16) & 1);
  return (unsigned short)(r >> 16);
}
__device__ __forceinline__ float b2f(unsigned int u) {
  union { unsigned u; float f; } v; v.u = (u & 0xffffu) << 16; return v.f;
}

__device__ __forceinline__ void gload16(const unsigned short* g, unsigned short* l) {
  __builtin_amdgcn_global_load_lds(
      (const __attribute__((address_space(1))) unsigned int*)g,
      (__attribute__((address_space(3))) unsigned int*)l, 16, 0, 0);
}

// ---------------------------------------------------------------------------
// W: weight prep — convert all GEMM weights to bf16 (xpw padded 48->64)
// wb layout: [0) lwb 256x512 | ipwb 1024x256 | xpwb 64x512 | opwb 256x512 | Aw 256x2304
// ---------------------------------------------------------------------------
#define WO1 131072
#define WO2 393216
#define WO3 425984
#define WO4 557056
__global__ __launch_bounds__(256)
void k_wprep(const float* __restrict__ lw, const float* __restrict__ ipw,
             const float* __restrict__ xpw, const float* __restrict__ opw,
             const float* __restrict__ rw, unsigned short* __restrict__ wb) {
  const int i = blockIdx.x * 256 + threadIdx.x;
  if (i < WO1)      wb[i] = f2b(lw[i]);
  else if (i < WO2) wb[i] = f2b(ipw[i - WO1]);
  else if (i < WO3) {
    const int j = i - WO2, row = j >> 9, col = j & 511;
    wb[i] = (row < 48) ? f2b(xpw[row * 512 + col]) : (unsigned short)0;
  }
  else if (i < WO4) wb[i] = f2b(opw[i - WO3]);
  else {
    const int j = i - WO4, o = j / 2304, kk = j % 2304;
    const int tap = kk >> 8, ch = kk & 255;
    wb[i] = f2b(rw[(o * 256 + ch) * 9 + tap]);
  }
}

// ---------------------------------------------------------------------------
// T: transpose x (b,k,l) f32 -> xt (b,l,k) bf16
// ---------------------------------------------------------------------------
__global__ __launch_bounds__(256)
void k_xpose(const float* __restrict__ x, unsigned short* __restrict__ xt) {
  __shared__ unsigned short Ts[64][80];
  const int b  = blockIdx.z;
  const int k0 = blockIdx.y * 64;
  const int l0 = blockIdx.x * 64;
  const int t  = threadIdx.x;
  const int tx = t & 15, ty = t >> 4;
#pragma unroll
  for (int r = 0; r < 4; ++r) {
    const int k = ty + r * 16;
    float4 v = *(const float4*)(x + ((size_t)b * CIN + k0 + k) * LHW + l0 + tx * 4);
    Ts[tx*4+0][k] = f2b(v.x);
    Ts[tx*4+1][k] = f2b(v.y);
    Ts[tx*4+2][k] = f2b(v.z);
    Ts[tx*4+3][k] = f2b(v.w);
  }
  __syncthreads();
  const int lr = t >> 2, kc = (t & 3) * 16;
  unsigned short* dst = xt + ((size_t)b * LHW + l0 + lr) * CIN + k0 + kc;
  *(uint4*)dst       = *(const uint4*)&Ts[lr][kc];
  *(uint4*)(dst + 8) = *(const uint4*)&Ts[lr][kc + 8];
}

// ---------------------------------------------------------------------------
// shared MFMA main loop: 128x128 tile, BK=32
// ---------------------------------------------------------------------------
template<int RSA, int RSB, int KTOT>
__device__ __forceinline__ void gemm_loop_128(
    const unsigned short* __restrict__ Ab, const unsigned short* __restrict__ Bb,
    unsigned short* As, unsigned short* Bs, int t, f32x4 acc[4][4]) {
  const int w = t >> 6, lane = t & 63;
  const int wm = w >> 1, wn = w & 1;
  const int arow = t >> 2, acol = (t & 3) * 8;
  const int fr = lane & 15, g8 = (lane >> 4) * 8;
  for (int k0 = 0; k0 < KTOT; k0 += 32) {
    __syncthreads();
    gload16(Ab + (size_t)arow * RSA + k0 + acol,        &As[w * 512]);
    gload16(Ab + (size_t)(64 + arow) * RSA + k0 + acol, &As[2048 + w * 512]);
    gload16(Bb + (size_t)arow * RSB + k0 + acol,        &Bs[w * 512]);
    gload16(Bb + (size_t)(64 + arow) * RSB + k0 + acol, &Bs[2048 + w * 512]);
    __syncthreads();
    bf16x8 af[4], bf[4];
#pragma unroll
    for (int f = 0; f < 4; ++f) {
      af[f] = *(const bf16x8*)&As[(wm*64 + f*16 + fr) * 32 + g8];
      bf[f] = *(const bf16x8*)&Bs[(wn*64 + f*16 + fr) * 32 + g8];
    }
#pragma unroll
    for (int i = 0; i < 4; ++i)
#pragma unroll
      for (int j = 0; j < 4; ++j)
        acc[i][j] = __builtin_amdgcn_mfma_f32_16x16x32_bf16(af[i], bf[j], acc[i][j], 0, 0, 0);
  }
}

// ---------------------------------------------------------------------------
// G1: lateral — ub[b][l][o] = bf16( sum_k xt[b][l][k]*lwb[o][k] + lb[o] )
// ---------------------------------------------------------------------------
__global__ __launch_bounds__(256)
void k_lat_mfma(const unsigned short* __restrict__ xt, const unsigned short* __restrict__ lwb,
                const float* __restrict__ lb, unsigned short* __restrict__ ub) {
  __shared__ __align__(16) unsigned short As[4096], Bs[4096];
  const int t = threadIdx.x, lane = t & 63, w = t >> 6;
  const int wm = w >> 1, wn = w & 1;
  const int b = blockIdx.z, m0 = blockIdx.y * 128, n0 = blockIdx.x * 128;
  f32x4 acc[4][4] = {};
  gemm_loop_128<512, 512, 512>(xt + ((size_t)b * LHW + m0) * 512,
                               lwb + (size_t)n0 * 512, As, Bs, t, acc);
  const int fr = lane & 15, q4 = (lane >> 4) * 4;
#pragma unroll
  for (int i = 0; i < 4; ++i) {
    const int l = m0 + wm*64 + i*16 + q4;
#pragma unroll
    for (int j = 0; j < 4; ++j) {
      const int o = n0 + wn*64 + j*16 + fr;
      const float bias = lb[o];
      unsigned short* dst = ub + ((size_t)b * LHW + l) * COUT + o;
#pragma unroll
      for (int q = 0; q < 4; ++q)
        dst[(size_t)q * COUT] = f2b(acc[i][j][q] + bias);
    }
  }
}

// ---------------------------------------------------------------------------
// G2: inproj — e<512 -> xm_b bf16 ; e>=512 -> silu -> zs f32
// ---------------------------------------------------------------------------
__global__ __launch_bounds__(256)
void k_inproj_mfma(const unsigned short* __restrict__ ub, const unsigned short* __restrict__ ipwb,
                   unsigned short* __restrict__ xm_b, float* __restrict__ zs) {
  __shared__ __align__(16) unsigned short As[4096], Bs[4096];
  const int t = threadIdx.x, lane = t & 63, w = t >> 6;
  const int wm = w >> 1, wn = w & 1;
  const int b = blockIdx.z, m0 = blockIdx.y * 128, n0 = blockIdx.x * 128;
  f32x4 acc[4][4] = {};
  gemm_loop_128<256, 256, 256>(ub + ((size_t)b * LHW + m0) * 256,
                               ipwb + (size_t)n0 * 256, As, Bs, t, acc);
  const int fr = lane & 15, q4 = (lane >> 4) * 4;
  const bool isz = (n0 >= 512);
#pragma unroll
  for (int i = 0; i < 4; ++i) {
    const int l = m0 + wm*64 + i*16 + q4;
#pragma unroll
    for (int j = 0; j < 4; ++j) {
      const int e = n0 + wn*64 + j*16 + fr;
      if (isz) {
        float* dst = zs + ((size_t)b * LHW + l) * DIN + (e - 512);
#pragma unroll
        for (int q = 0; q < 4; ++q)
          dst[(size_t)q * DIN] = siluf(acc[i][j][q]);
      } else {
        unsigned short* dst = xm_b + ((size_t)b * LHW + l) * DIN + e;
#pragma unroll
        for (int q = 0; q < 4; ++q)
          dst[(size_t)q * DIN] = f2b(acc[i][j][q]);
      }
    }
  }
}

// ---------------------------------------------------------------------------
// K3: depthwise causal conv1d + bias + silu, bf16 in/out, (b,l,e)
// ---------------------------------------------------------------------------
__global__ __launch_bounds__(256)
void k_conv1d(const unsigned short* __restrict__ xm_b, const float* __restrict__ cw,
              const float* __restrict__ cb, unsigned short* __restrict__ xc_b) {
  const int tid = blockIdx.x * 256 + threadIdx.x;  // NB*LHW*64
  const int e8 = tid & 63;
  const int l  = (tid >> 6) & 4095;
  const int b  = tid >> 18;
  const int e0 = e8 * 8;
  float acc[8];
  *(float4*)&acc[0] = *(const float4*)(cb + e0);
  *(float4*)&acc[4] = *(const float4*)(cb + e0 + 4);
  float wv[8][4];
#pragma unroll
  for (int q = 0; q < 8; ++q) {
    float4 w4 = *(const float4*)(cw + (e0 + q) * 4);
    wv[q][0] = w4.x; wv[q][1] = w4.y; wv[q][2] = w4.z; wv[q][3] = w4.w;
  }
  const unsigned short* base = xm_b + (size_t)b * LHW * DIN + e0;
#pragma unroll
  for (int k = 0; k < 4; ++k) {
    const int ll = l - 3 + k;
    if (ll >= 0) {
      uint4 raw = *(const uint4*)(base + (size_t)ll * DIN);
      acc[0] = fmaf(b2f(raw.x),       wv[0][k], acc[0]);
      acc[1] = fmaf(b2f(raw.x >> 16), wv[1][k], acc[1]);
      acc[2] = fmaf(b2f(raw.y),       wv[2][k], acc[2]);
      acc[3] = fmaf(b2f(raw.y >> 16), wv[3][k], acc[3]);
      acc[4] = fmaf(b2f(raw.z),       wv[4][k], acc[4]);
      acc[5] = fmaf(b2f(raw.z >> 16), wv[5][k], acc[5]);
      acc[6] = fmaf(b2f(raw.w),       wv[6][k], acc[6]);
      acc[7] = fmaf(b2f(raw.w >> 16), wv[7][k], acc[7]);
    }
  }
  uint4 o;
  o.x = (unsigned)f2b(siluf(acc[0])) | ((unsigned)f2b(siluf(acc[1])) << 16);
  o.y = (unsigned)f2b(siluf(acc[2])) | ((unsigned)f2b(siluf(acc[3])) << 16);
  o.z = (unsigned)f2b(siluf(acc[4])) | ((unsigned)f2b(siluf(acc[5])) << 16);
  o.w = (unsigned)f2b(siluf(acc[6])) | ((unsigned)f2b(siluf(acc[7])) << 16);
  *(uint4*)(xc_b + ((size_t)b * LHW + l) * DIN + e0) = o;
}

// ---------------------------------------------------------------------------
// G3: xproj — proj[b][l][j] (j<48), 128x64 tile
// ---------------------------------------------------------------------------
__global__ __launch_bounds__(256)
void k_xproj_mfma(const unsigned short* __restrict__ xc_b, const unsigned short* __restrict__ xpwb,
                  float* __restrict__ proj) {
  __shared__ __align__(16) unsigned short As[4096], Bs[2048];
  const int t = threadIdx.x, lane = t & 63, w = t >> 6;
  const int wm = w >> 1, wn = w & 1;
  const int b = blockIdx.y, m0 = blockIdx.x * 128;
  const int arow = t >> 2, acol = (t & 3) * 8;
  const int fr = lane & 15, g8 = (lane >> 4) * 8;
  const unsigned short* Ab = xc_b + ((size_t)b * LHW + m0) * 512;
  f32x4 acc[4][2] = {};
  for (int k0 = 0; k0 < 512; k0 += 32) {
    __syncthreads();
    gload16(Ab + (size_t)arow * 512 + k0 + acol,        &As[w * 512]);
    gload16(Ab + (size_t)(64 + arow) * 512 + k0 + acol, &As[2048 + w * 512]);
    gload16(xpwb + (size_t)arow * 512 + k0 + acol,      &Bs[w * 512]);
    __syncthreads();
    bf16x8 af[4], bf[2];
#pragma unroll
    for (int f = 0; f < 4; ++f)
      af[f] = *(const bf16x8*)&As[(wm*64 + f*16 + fr) * 32 + g8];
#pragma unroll
    for (int f = 0; f < 2; ++f)
      bf[f] = *(const bf16x8*)&Bs[(wn*32 + f*16 + fr) * 32 + g8];
#pragma unroll
    for (int i = 0; i < 4; ++i)
#pragma unroll
      for (int j = 0; j < 2; ++j)
        acc[i][j] = __builtin_amdgcn_mfma_f32_16x16x32_bf16(af[i], bf[j], acc[i][j], 0, 0, 0);
  }
  const int q4 = (lane >> 4) * 4;
#pragma unroll
  for (int i = 0; i < 4; ++i) {
    const int l = m0 + wm*64 + i*16 + q4;
#pragma unroll
    for (int j = 0; j < 2; ++j) {
      const int col = wn*32 + j*16 + fr;
      if (col < 48) {
        float* dst = proj + ((size_t)b * LHW + l) * 48 + col;
#pragma unroll
        for (int q = 0; q < 4; ++q)
          dst[(size_t)q * 48] = acc[i][j][q];
      }
    }
  }
}

// ---------------------------------------------------------------------------
// K5: scan phase A
// ---------------------------------------------------------------------------
__global__ __launch_bounds__(256)
void k_scanA(const float* __restrict__ proj, const unsigned short* __restrict__ xc_b,
             const float* __restrict__ dtpw, const float* __restrict__ dtpb,
             const float* __restrict__ A_log, float* __restrict__ PS) {
  const int tid = blockIdx.x * 256 + threadIdx.x;
  const int d = tid & 511;
  const int c = (tid >> 9) & 31;
  const int b = tid >> 14;
  float w[16], An[16];
#pragma unroll
  for (int q = 0; q < 4; ++q)
    *(float4*)(&w[q*4]) = *(const float4*)(dtpw + d*16 + q*4);
#pragma unroll
  for (int q = 0; q < 4; ++q) {
    float4 a4 = *(const float4*)(A_log + d*16 + q*4);
    An[q*4+0] = -__expf(a4.x); An[q*4+1] = -__expf(a4.y);
    An[q*4+2] = -__expf(a4.z); An[q*4+3] = -__expf(a4.w);
  }
  const float bias = dtpb[d];
  float h[16], P[16];
#pragma unroll
  for (int n = 0; n < 16; ++n) { h[n] = 0.f; P[n] = 1.f; }
  const size_t rbase = (size_t)(b*LHW + c*CHL);
  const float* pr0 = proj + rbase * 48;
  const unsigned short* xc0 = xc_b + rbase * DIN + d;
  for (int i = 0; i < CHL; ++i) {
    const float* pr = pr0 + i * 48;
    float dtl = bias;
#pragma unroll
    for (int q = 0; q < 4; ++q) {
      float4 r4 = *(const float4*)(pr + q*4);
      dtl = fmaf(w[q*4+0], r4.x, dtl);
      dtl = fmaf(w[q*4+1], r4.y, dtl);
      dtl = fmaf(w[q*4+2], r4.z, dtl);
      dtl = fmaf(w[q*4+3], r4.w, dtl);
    }
    const float dt  = splusf(dtl);
    const float xt  = b2f(xc0[(size_t)i * DIN]);
    const float dtx = dt * xt;
#pragma unroll
    for (int q = 0; q < 4; ++q) {
      float4 B4 = *(const float4*)(pr + 16 + q*4);
      const float bs[4] = {B4.x, B4.y, B4.z, B4.w};
#pragma unroll
      for (int u = 0; u < 4; ++u) {
        const int n = q*4 + u;
        const float dA = __expf(dt * An[n]);
        P[n] *= dA;
        h[n] = fmaf(dA, h[n], dtx * bs[u]);
      }
    }
  }
  float* o = PS + (size_t)tid * 32;
#pragma unroll
  for (int q = 0; q < 4; ++q)
    *(float4*)(o + q*4) = make_float4(P[q*4], P[q*4+1], P[q*4+2], P[q*4+3]);
#pragma unroll
  for (int q = 0; q < 4; ++q)
    *(float4*)(o + 16 + q*4) = make_float4(h[q*4], h[q*4+1], h[q*4+2], h[q*4+3]);
}

// ---------------------------------------------------------------------------
// K6: scan phase B
// ---------------------------------------------------------------------------
__global__ __launch_bounds__(256)
void k_scanB(const float* __restrict__ PS, float* __restrict__ hst) {
  const int tid = blockIdx.x * 256 + threadIdx.x;
  const int n = tid & 15;
  const int d = (tid >> 4) & 511;
  const int b = tid >> 13;
  float h = 0.f;
  for (int c = 0; c < NCHK; ++c) {
    const size_t idx = (size_t)((b*NCHK + c)*512 + d);
    hst[idx*16 + n] = h;
    h = PS[idx*32 + n] * h + PS[idx*32 + 16 + n];
  }
}

// ---------------------------------------------------------------------------
// K7: scan phase C — writes gated y as bf16 channel-last
// ---------------------------------------------------------------------------
__global__ __launch_bounds__(256)
void k_scanC(const float* __restrict__ proj, const unsigned short* __restrict__ xc_b,
             const float* __restrict__ zs, const float* __restrict__ hst,
             const float* __restrict__ dtpw, const float* __restrict__ dtpb,
             const float* __restrict__ A_log, const float* __restrict__ Dpar,
             unsigned short* __restrict__ ydata) {
  const int tid = blockIdx.x * 256 + threadIdx.x;
  const int d = tid & 511;
  const int c = (tid >> 9) & 31;
  const int b = tid >> 14;
  float w[16], An[16], h[16];
#pragma unroll
  for (int q = 0; q < 4; ++q)
    *(float4*)(&w[q*4]) = *(const float4*)(dtpw + d*16 + q*4);
#pragma unroll
  for (int q = 0; q < 4; ++q) {
    float4 a4 = *(const float4*)(A_log + d*16 + q*4);
    An[q*4+0] = -__expf(a4.x); An[q*4+1] = -__expf(a4.y);
    An[q*4+2] = -__expf(a4.z); An[q*4+3] = -__expf(a4.w);
  }
#pragma unroll
  for (int q = 0; q < 4; ++q) {
    float4 h4 = *(const float4*)(hst + (size_t)tid*16 + q*4);
    h[q*4+0] = h4.x; h[q*4+1] = h4.y; h[q*4+2] = h4.z; h[q*4+3] = h4.w;
  }
  const float bias = dtpb[d];
  const float dp = Dpar[d];
  const size_t rbase = (size_t)(b*LHW + c*CHL);
  const float* pr0 = proj + rbase * 48;
  const unsigned short* xc0 = xc_b + rbase * DIN + d;
  const float* zs0 = zs   + rbase * DIN + d;
  unsigned short* y0 = ydata + rbase * DIN + d;
  for (int i = 0; i < CHL; ++i) {
    const float* pr = pr0 + i * 48;
    float dtl = bias;
#pragma unroll
    for (int q = 0; q < 4; ++q) {
      float4 r4 = *(const float4*)(pr + q*4);
      dtl = fmaf(w[q*4+0], r4.x, dtl);
      dtl = fmaf(w[q*4+1], r4.y, dtl);
      dtl = fmaf(w[q*4+2], r4.z, dtl);
      dtl = fmaf(w[q*4+3], r4.w, dtl);
    }
    const float dt  = splusf(dtl);
    const float xt  = b2f(xc0[(size_t)i * DIN]);
    const float dtx = dt * xt;
    float y = 0.f;
#pragma unroll
    for (int q = 0; q < 4; ++q) {
      float4 B4 = *(const float4*)(pr + 16 + q*4);
      float4 C4 = *(const float4*)(pr + 32 + q*4);
      const float bs[4] = {B4.x, B4.y, B4.z, B4.w};
      const float cs[4] = {C4.x, C4.y, C4.z, C4.w};
#pragma unroll
      for (int u = 0; u < 4; ++u) {
        const int n = q*4 + u;
        const float dA = __expf(dt * An[n]);
        h[n] = fmaf(dA, h[n], dtx * bs[u]);
        y = fmaf(h[n], cs[u], y);
      }
    }
    const float ov = (y + xt * dp) * zs0[(size_t)i * DIN];
    y0[(size_t)i * DIN] = f2b(ov);
  }
}

// ---------------------------------------------------------------------------
// G4: outproj + residual(ub) -> padded channel-last bf16 xrp
// ---------------------------------------------------------------------------
__global__ __launch_bounds__(256)
void k_outproj_mfma(const unsigned short* __restrict__ ydata, const unsigned short* __restrict__ opwb,
                    const unsigned short* __restrict__ ub, unsigned short* __restrict__ xrp) {
  __shared__ __align__(16) unsigned short As[4096], Bs[4096];
  const int t = threadIdx.x, lane = t & 63, w = t >> 6;
  const int wm = w >> 1, wn = w & 1;
  const int b = blockIdx.z, m0 = blockIdx.y * 128, n0 = blockIdx.x * 128;
  f32x4 acc[4][4] = {};
  gemm_loop_128<512, 512, 512>(ydata + ((size_t)b * LHW + m0) * 512,
                               opwb + (size_t)n0 * 512, As, Bs, t, acc);
  const int fr = lane & 15, q4 = (lane >> 4) * 4;
#pragma unroll
  for (int i = 0; i < 4; ++i) {
    const int lbase = m0 + wm*64 + i*16 + q4;
#pragma unroll
    for (int q = 0; q < 4; ++q) {
      const int l = lbase + q;
      const int pos = ((l >> 6) + 1) * PW + (l & 63) + 1;
#pragma unroll
      for (int j = 0; j < 4; ++j) {
        const int o = n0 + wn*64 + j*16 + fr;
        const float r = b2f(ub[((size_t)b * LHW + l) * COUT + o]);
        xrp[((size_t)b * PPOS + pos) * COUT + o] = f2b(acc[i][j][q] + r);
      }
    }
  }
}

// ---------------------------------------------------------------------------
// G5: refine 3x3 conv as MFMA implicit GEMM + BN + ReLU (unchanged from R2)
// ---------------------------------------------------------------------------
__global__ __launch_bounds__(256)
void k_refine_mfma(const unsigned short* __restrict__ Aw,
                   const unsigned short* __restrict__ xrp,
                   const float* __restrict__ rb, const float* __restrict__ bng,
                   const float* __restrict__ bnb, const float* __restrict__ bnm,
                   const float* __restrict__ bnv, float* __restrict__ out) {
  __shared__ __align__(16) unsigned short As[4096], Bs[4096];
  const int t = threadIdx.x;
  const int lane = t & 63;
  const int w = t >> 6;
  const int wm = w >> 1, wn = w & 1;
  const int b  = blockIdx.z;
  const int m0 = blockIdx.y * 128;
  const int n0 = blockIdx.x * 128;
  const int y0 = n0 >> 6;
  const unsigned short* xb = xrp + (size_t)b * PPOS * COUT;
  const int arow = t >> 2;
  const int acol = (t & 3) * 8;
  f32x4 acc[4][4] = {};
  for (int ks = 0; ks < 72; ++ks) {
    const int tap = ks >> 3;
    const int i0  = (ks & 7) * 32;
    const int ky  = tap / 3, kx = tap - ky * 3;
    const int k0  = tap * 256 + i0;
    const unsigned short* ga0 = Aw + (size_t)(m0 + arow) * 2304 + k0 + acol;
    const unsigned short* gb0 = xb + ((size_t)((y0 + ky) * PW + kx + arow)) * COUT + i0 + acol;
    __syncthreads();
    gload16(ga0,              &As[w * 512]);
    gload16(ga0 + 64 * 2304,  &As[2048 + w * 512]);
    gload16(gb0,              &Bs[w * 512]);
    gload16(gb0 + PW * COUT,  &Bs[2048 + w * 512]);
    __syncthreads();
    const int fr = lane & 15, g8 = (lane >> 4) * 8;
    bf16x8 af[4], bfr[4];
#pragma unroll
    for (int f = 0; f < 4; ++f) {
      af[f]  = *(const bf16x8*)&As[(wm*64 + f*16 + fr) * 32 + g8];
      bfr[f] = *(const bf16x8*)&Bs[(wn*64 + f*16 + fr) * 32 + g8];
    }
#pragma unroll
    for (int i = 0; i < 4; ++i)
#pragma unroll
      for (int j = 0; j < 4; ++j)
        acc[i][j] = __builtin_amdgcn_mfma_f32_16x16x32_bf16(af[i], bfr[j], acc[i][j], 0, 0, 0);
  }
  const int fr = lane & 15, q4 = (lane >> 4) * 4;
#pragma unroll
  for (int i = 0; i < 4; ++i) {
    const int obase = m0 + wm*64 + i*16 + q4;
#pragma unroll
    for (int q = 0; q < 4; ++q) {
      const int o = obase + q;
      const float inv = bng[o] * rsqrtf(bnv[o] + 1e-5f);
      const float sh  = (rb[o] - bnm[o]) * inv + bnb[o];
      float* orow = out + ((size_t)b * COUT + o) * LHW + n0 + wn*64 + fr;
#pragma unroll
      for (int j = 0; j < 4; ++j)
        orow[j*16] = fmaxf(fmaf(acc[i][j][q], inv, sh), 0.f);
    }
  }
}

// ---------------------------------------------------------------------------
extern "C" void kernel_launch(void* const* d_in, const int* in_sizes, int n_in,
                              void* d_out, int out_size, void* d_ws, size_t ws_size,
                              hipStream_t stream) {
  const float* x    = (const float*)d_in[0];
  const float* lw   = (const float*)d_in[1];
  const float* lb   = (const float*)d_in[2];
  const float* ipw  = (const float*)d_in[3];
  const float* cw   = (const float*)d_in[4];
  const float* cb   = (const float*)d_in[5];
  const float* xpw  = (const float*)d_in[6];
  const float* dtpw = (const float*)d_in[7];
  const float* dtpb = (const float*)d_in[8];
  const float* Alog = (const float*)d_in[9];
  const float* Dpar = (const float*)d_in[10];
  const float* opw  = (const float*)d_in[11];
  const float* rw   = (const float*)d_in[12];
  const float* rb   = (const float*)d_in[13];
  const float* bng  = (const float*)d_in[14];
  const float* bnb  = (const float*)d_in[15];
  const float* bnm  = (const float*)d_in[16];
  const float* bnv  = (const float*)d_in[17];
  float* out = (float*)d_out;

  float* ws = (float*)d_ws;
  unsigned short* ub   = (unsigned short*)ws;                      // 8,388,608 us
  unsigned short* xt   = (unsigned short*)(ws + 4194304);          // 16,777,216 us (reused as xrp)
  unsigned short* xm_b = (unsigned short*)(ws + 12582912);         // 16,777,216 us (reused as ydata)
  unsigned short* xc_b = (unsigned short*)(ws + 20971520);         // 16,777,216 us
  float* zs   = ws + 29360128;                                     // 16,777,216 f
  float* proj = ws + 46137344;                                     //  1,572,864 f
  float* PS   = ws + 47710208;                                     //  4,194,304 f
  float* hst  = ws + 51904512;                                     //  2,097,152 f
  unsigned short* wb = (unsigned short*)(ws + 54001664);           //  1,146,880 us
  unsigned short* lwb  = wb;
  unsigned short* ipwb = wb + WO1;
  unsigned short* xpwb = wb + WO2;
  unsigned short* opwb = wb + WO3;
  unsigned short* Aw   = wb + WO4;
  unsigned short* ydata = xm_b;
  unsigned short* xrp   = xt;

  k_wprep<<<dim3(4480), 256, 0, stream>>>(lw, ipw, xpw, opw, rw, wb);
  k_xpose<<<dim3(64, 8, 8), 256, 0, stream>>>(x, xt);
  k_lat_mfma<<<dim3(2, 32, 8), 256, 0, stream>>>(xt, lwb, lb, ub);
  hipMemsetAsync(xrp, 0, (size_t)NB * PPOS * COUT * sizeof(unsigned short), stream);
  k_inproj_mfma<<<dim3(8, 32, 8), 256, 0, stream>>>(ub, ipwb, xm_b, zs);
  k_conv1d<<<dim3(8192), 256, 0, stream>>>(xm_b, cw, cb, xc_b);
  k_xproj_mfma<<<dim3(32, 8), 256, 0, stream>>>(xc_b, xpwb, proj);
  k_scanA<<<dim3(512), 256, 0, stream>>>(proj, xc_b, dtpw, dtpb, Alog, PS);
  k_scanB<<<dim3(256), 256, 0, stream>>>(PS, hst);
  k_scanC<<<dim3(512), 256, 0, stream>>>(proj, xc_b, zs, hst, dtpw, dtpb, Alog, Dpar, ydata);
  k_outproj_mfma<<<dim3(2, 32, 8), 256, 0, stream>>>(ydata, opwb, ub, xrp);
  k_refine_mfma<<<dim3(32, 2, 8), 256, 0, stream>>>(Aw, xrp, rb, bng, bnb, bnm, bnv, out);
}

// Round 4
// 463.724 us; speedup vs baseline: 11.3512x; 1.1653x over previous
//
#include <hip/hip_runtime.h>
#include <math.h>

#define NB   8
#define CIN  512
#define COUT 256
#define DIN  512
#define LHW  4096
#define NCHK 64
#define CHL  64
#define PW   66
#define PPOS (PW*PW)

typedef __attribute__((ext_vector_type(8))) short bf16x8;
typedef __attribute__((ext_vector_type(4))) float f32x4;

__device__ __forceinline__ float siluf(float v)  { return v / (1.f + __expf(-v)); }
__device__ __forceinline__ float splusf(float v) { return v > 20.f ? v : log1pf(__expf(v)); }

__device__ __forceinline__ unsigned short f2b(float f) {
  union { float f; unsigned u; } v; v.f = f;
  unsigned r = v.u + 0x7fff + ((v.u >> 16) & 1);
  return (unsigned short)(r >> 16);
}
__device__ __forceinline__ float b2f(unsigned int u) {
  union { unsigned u; float f; } v; v.u = (u & 0xffffu) << 16; return v.f;
}

__device__ __forceinline__ void gload16(const unsigned short* g, unsigned short* l) {
  __builtin_amdgcn_global_load_lds(
      (const __attribute__((address_space(1))) unsigned int*)g,
      (__attribute__((address_space(3))) unsigned int*)l, 16, 0, 0);
}

// ---------------------------------------------------------------------------
// W: weight prep — convert all GEMM weights to bf16 (xpw padded 48->64)
// ---------------------------------------------------------------------------
#define WO1 131072
#define WO2 393216
#define WO3 425984
#define WO4 557056
__global__ __launch_bounds__(256)
void k_wprep(const float* __restrict__ lw, const float* __restrict__ ipw,
             const float* __restrict__ xpw, const float* __restrict__ opw,
             const float* __restrict__ rw, unsigned short* __restrict__ wb) {
  const int i = blockIdx.x * 256 + threadIdx.x;
  if (i < WO1)      wb[i] = f2b(lw[i]);
  else if (i < WO2) wb[i] = f2b(ipw[i - WO1]);
  else if (i < WO3) {
    const int j = i - WO2, row = j >> 9, col = j & 511;
    wb[i] = (row < 48) ? f2b(xpw[row * 512 + col]) : (unsigned short)0;
  }
  else if (i < WO4) wb[i] = f2b(opw[i - WO3]);
  else {
    const int j = i - WO4, o = j / 2304, kk = j % 2304;
    const int tap = kk >> 8, ch = kk & 255;
    wb[i] = f2b(rw[(o * 256 + ch) * 9 + tap]);
  }
}

// ---------------------------------------------------------------------------
// T: transpose x (b,k,l) f32 -> xt (b,l,k) bf16
// ---------------------------------------------------------------------------
__global__ __launch_bounds__(256)
void k_xpose(const float* __restrict__ x, unsigned short* __restrict__ xt) {
  __shared__ unsigned short Ts[64][80];
  const int b  = blockIdx.z;
  const int k0 = blockIdx.y * 64;
  const int l0 = blockIdx.x * 64;
  const int t  = threadIdx.x;
  const int tx = t & 15, ty = t >> 4;
#pragma unroll
  for (int r = 0; r < 4; ++r) {
    const int k = ty + r * 16;
    float4 v = *(const float4*)(x + ((size_t)b * CIN + k0 + k) * LHW + l0 + tx * 4);
    Ts[tx*4+0][k] = f2b(v.x);
    Ts[tx*4+1][k] = f2b(v.y);
    Ts[tx*4+2][k] = f2b(v.z);
    Ts[tx*4+3][k] = f2b(v.w);
  }
  __syncthreads();
  const int lr = t >> 2, kc = (t & 3) * 16;
  unsigned short* dst = xt + ((size_t)b * LHW + l0 + lr) * CIN + k0 + kc;
  *(uint4*)dst       = *(const uint4*)&Ts[lr][kc];
  *(uint4*)(dst + 8) = *(const uint4*)&Ts[lr][kc + 8];
}

// ---------------------------------------------------------------------------
// shared MFMA main loop: 128x128 tile, BK=32
// ---------------------------------------------------------------------------
template<int RSA, int RSB, int KTOT>
__device__ __forceinline__ void gemm_loop_128(
    const unsigned short* __restrict__ Ab, const unsigned short* __restrict__ Bb,
    unsigned short* As, unsigned short* Bs, int t, f32x4 acc[4][4]) {
  const int w = t >> 6, lane = t & 63;
  const int wm = w >> 1, wn = w & 1;
  const int arow = t >> 2, acol = (t & 3) * 8;
  const int fr = lane & 15, g8 = (lane >> 4) * 8;
  for (int k0 = 0; k0 < KTOT; k0 += 32) {
    __syncthreads();
    gload16(Ab + (size_t)arow * RSA + k0 + acol,        &As[w * 512]);
    gload16(Ab + (size_t)(64 + arow) * RSA + k0 + acol, &As[2048 + w * 512]);
    gload16(Bb + (size_t)arow * RSB + k0 + acol,        &Bs[w * 512]);
    gload16(Bb + (size_t)(64 + arow) * RSB + k0 + acol, &Bs[2048 + w * 512]);
    __syncthreads();
    bf16x8 af[4], bf[4];
#pragma unroll
    for (int f = 0; f < 4; ++f) {
      af[f] = *(const bf16x8*)&As[(wm*64 + f*16 + fr) * 32 + g8];
      bf[f] = *(const bf16x8*)&Bs[(wn*64 + f*16 + fr) * 32 + g8];
    }
#pragma unroll
    for (int i = 0; i < 4; ++i)
#pragma unroll
      for (int j = 0; j < 4; ++j)
        acc[i][j] = __builtin_amdgcn_mfma_f32_16x16x32_bf16(af[i], bf[j], acc[i][j], 0, 0, 0);
  }
}

// ---------------------------------------------------------------------------
// G1: lateral — ub[b][l][o] = bf16( sum_k xt[b][l][k]*lwb[o][k] + lb[o] )
// ---------------------------------------------------------------------------
__global__ __launch_bounds__(256)
void k_lat_mfma(const unsigned short* __restrict__ xt, const unsigned short* __restrict__ lwb,
                const float* __restrict__ lb, unsigned short* __restrict__ ub) {
  __shared__ __align__(16) unsigned short As[4096], Bs[4096];
  const int t = threadIdx.x, lane = t & 63, w = t >> 6;
  const int wm = w >> 1, wn = w & 1;
  const int b = blockIdx.z, m0 = blockIdx.y * 128, n0 = blockIdx.x * 128;
  f32x4 acc[4][4] = {};
  gemm_loop_128<512, 512, 512>(xt + ((size_t)b * LHW + m0) * 512,
                               lwb + (size_t)n0 * 512, As, Bs, t, acc);
  const int fr = lane & 15, q4 = (lane >> 4) * 4;
#pragma unroll
  for (int i = 0; i < 4; ++i) {
    const int l = m0 + wm*64 + i*16 + q4;
#pragma unroll
    for (int j = 0; j < 4; ++j) {
      const int o = n0 + wn*64 + j*16 + fr;
      const float bias = lb[o];
      unsigned short* dst = ub + ((size_t)b * LHW + l) * COUT + o;
#pragma unroll
      for (int q = 0; q < 4; ++q)
        dst[(size_t)q * COUT] = f2b(acc[i][j][q] + bias);
    }
  }
}

// ---------------------------------------------------------------------------
// G2: inproj — e<512 -> xm_b bf16 ; e>=512 -> silu -> zs f32
// ---------------------------------------------------------------------------
__global__ __launch_bounds__(256)
void k_inproj_mfma(const unsigned short* __restrict__ ub, const unsigned short* __restrict__ ipwb,
                   unsigned short* __restrict__ xm_b, float* __restrict__ zs) {
  __shared__ __align__(16) unsigned short As[4096], Bs[4096];
  const int t = threadIdx.x, lane = t & 63, w = t >> 6;
  const int wm = w >> 1, wn = w & 1;
  const int b = blockIdx.z, m0 = blockIdx.y * 128, n0 = blockIdx.x * 128;
  f32x4 acc[4][4] = {};
  gemm_loop_128<256, 256, 256>(ub + ((size_t)b * LHW + m0) * 256,
                               ipwb + (size_t)n0 * 256, As, Bs, t, acc);
  const int fr = lane & 15, q4 = (lane >> 4) * 4;
  const bool isz = (n0 >= 512);
#pragma unroll
  for (int i = 0; i < 4; ++i) {
    const int l = m0 + wm*64 + i*16 + q4;
#pragma unroll
    for (int j = 0; j < 4; ++j) {
      const int e = n0 + wn*64 + j*16 + fr;
      if (isz) {
        float* dst = zs + ((size_t)b * LHW + l) * DIN + (e - 512);
#pragma unroll
        for (int q = 0; q < 4; ++q)
          dst[(size_t)q * DIN] = siluf(acc[i][j][q]);
      } else {
        unsigned short* dst = xm_b + ((size_t)b * LHW + l) * DIN + e;
#pragma unroll
        for (int q = 0; q < 4; ++q)
          dst[(size_t)q * DIN] = f2b(acc[i][j][q]);
      }
    }
  }
}

// ---------------------------------------------------------------------------
// K3: depthwise causal conv1d + bias + silu, bf16 in/out, (b,l,e)
// ---------------------------------------------------------------------------
__global__ __launch_bounds__(256)
void k_conv1d(const unsigned short* __restrict__ xm_b, const float* __restrict__ cw,
              const float* __restrict__ cb, unsigned short* __restrict__ xc_b) {
  const int tid = blockIdx.x * 256 + threadIdx.x;
  const int e8 = tid & 63;
  const int l  = (tid >> 6) & 4095;
  const int b  = tid >> 18;
  const int e0 = e8 * 8;
  float acc[8];
  *(float4*)&acc[0] = *(const float4*)(cb + e0);
  *(float4*)&acc[4] = *(const float4*)(cb + e0 + 4);
  float wv[8][4];
#pragma unroll
  for (int q = 0; q < 8; ++q) {
    float4 w4 = *(const float4*)(cw + (e0 + q) * 4);
    wv[q][0] = w4.x; wv[q][1] = w4.y; wv[q][2] = w4.z; wv[q][3] = w4.w;
  }
  const unsigned short* base = xm_b + (size_t)b * LHW * DIN + e0;
#pragma unroll
  for (int k = 0; k < 4; ++k) {
    const int ll = l - 3 + k;
    if (ll >= 0) {
      uint4 raw = *(const uint4*)(base + (size_t)ll * DIN);
      acc[0] = fmaf(b2f(raw.x),       wv[0][k], acc[0]);
      acc[1] = fmaf(b2f(raw.x >> 16), wv[1][k], acc[1]);
      acc[2] = fmaf(b2f(raw.y),       wv[2][k], acc[2]);
      acc[3] = fmaf(b2f(raw.y >> 16), wv[3][k], acc[3]);
      acc[4] = fmaf(b2f(raw.z),       wv[4][k], acc[4]);
      acc[5] = fmaf(b2f(raw.z >> 16), wv[5][k], acc[5]);
      acc[6] = fmaf(b2f(raw.w),       wv[6][k], acc[6]);
      acc[7] = fmaf(b2f(raw.w >> 16), wv[7][k], acc[7]);
    }
  }
  uint4 o;
  o.x = (unsigned)f2b(siluf(acc[0])) | ((unsigned)f2b(siluf(acc[1])) << 16);
  o.y = (unsigned)f2b(siluf(acc[2])) | ((unsigned)f2b(siluf(acc[3])) << 16);
  o.z = (unsigned)f2b(siluf(acc[4])) | ((unsigned)f2b(siluf(acc[5])) << 16);
  o.w = (unsigned)f2b(siluf(acc[6])) | ((unsigned)f2b(siluf(acc[7])) << 16);
  *(uint4*)(xc_b + ((size_t)b * LHW + l) * DIN + e0) = o;
}

// ---------------------------------------------------------------------------
// G3: xproj — proj[b][l][j] (j<48), 128x64 tile
// ---------------------------------------------------------------------------
__global__ __launch_bounds__(256)
void k_xproj_mfma(const unsigned short* __restrict__ xc_b, const unsigned short* __restrict__ xpwb,
                  float* __restrict__ proj) {
  __shared__ __align__(16) unsigned short As[4096], Bs[2048];
  const int t = threadIdx.x, lane = t & 63, w = t >> 6;
  const int wm = w >> 1, wn = w & 1;
  const int b = blockIdx.y, m0 = blockIdx.x * 128;
  const int arow = t >> 2, acol = (t & 3) * 8;
  const int fr = lane & 15, g8 = (lane >> 4) * 8;
  const unsigned short* Ab = xc_b + ((size_t)b * LHW + m0) * 512;
  f32x4 acc[4][2] = {};
  for (int k0 = 0; k0 < 512; k0 += 32) {
    __syncthreads();
    gload16(Ab + (size_t)arow * 512 + k0 + acol,        &As[w * 512]);
    gload16(Ab + (size_t)(64 + arow) * 512 + k0 + acol, &As[2048 + w * 512]);
    gload16(xpwb + (size_t)arow * 512 + k0 + acol,      &Bs[w * 512]);
    __syncthreads();
    bf16x8 af[4], bf[2];
#pragma unroll
    for (int f = 0; f < 4; ++f)
      af[f] = *(const bf16x8*)&As[(wm*64 + f*16 + fr) * 32 + g8];
#pragma unroll
    for (int f = 0; f < 2; ++f)
      bf[f] = *(const bf16x8*)&Bs[(wn*32 + f*16 + fr) * 32 + g8];
#pragma unroll
    for (int i = 0; i < 4; ++i)
#pragma unroll
      for (int j = 0; j < 2; ++j)
        acc[i][j] = __builtin_amdgcn_mfma_f32_16x16x32_bf16(af[i], bf[j], acc[i][j], 0, 0, 0);
  }
  const int q4 = (lane >> 4) * 4;
#pragma unroll
  for (int i = 0; i < 4; ++i) {
    const int l = m0 + wm*64 + i*16 + q4;
#pragma unroll
    for (int j = 0; j < 2; ++j) {
      const int col = wn*32 + j*16 + fr;
      if (col < 48) {
        float* dst = proj + ((size_t)b * LHW + l) * 48 + col;
#pragma unroll
        for (int q = 0; q < 4; ++q)
          dst[(size_t)q * 48] = acc[i][j][q];
      }
    }
  }
}

// ---------------------------------------------------------------------------
// K5: scan phase A — block = (b, chunk), 512 threads = d; proj staged in LDS.
// P[n] = exp(An * sum(dt))  (one exp batch per chunk); dA via power-tree when
// An[n] == (n+1)*An[0] (runtime-checked, uniform), else exp fallback.
// ---------------------------------------------------------------------------
__global__ __launch_bounds__(512, 4)
void k_scanA(const float* __restrict__ proj, const unsigned short* __restrict__ xc_b,
             const float* __restrict__ dtpw, const float* __restrict__ dtpb,
             const float* __restrict__ A_log, float* __restrict__ PS) {
  __shared__ float prs[CHL * 48];
  const int bx = blockIdx.x;
  const int b = bx >> 6, c = bx & 63;
  const int d = threadIdx.x;
  const size_t rbase = (size_t)b * LHW + c * CHL;
  {
    const float4* src = (const float4*)(proj + rbase * 48);
    float4* dst = (float4*)prs;
    for (int i = d; i < CHL * 12; i += 512) dst[i] = src[i];
  }
  float w[16], An[16], h[16];
#pragma unroll
  for (int q = 0; q < 4; ++q)
    *(float4*)(&w[q*4]) = *(const float4*)(dtpw + d*16 + q*4);
#pragma unroll
  for (int q = 0; q < 4; ++q) {
    float4 a4 = *(const float4*)(A_log + d*16 + q*4);
    An[q*4+0] = -__expf(a4.x); An[q*4+1] = -__expf(a4.y);
    An[q*4+2] = -__expf(a4.z); An[q*4+3] = -__expf(a4.w);
  }
#pragma unroll
  for (int n = 0; n < 16; ++n) h[n] = 0.f;
  const float An0 = An[0];
  bool lin = true;
#pragma unroll
  for (int n = 1; n < 16; ++n)
    lin = lin && (fabsf(An[n] - (n + 1) * An0) <= 1e-4f * fabsf(An[n]));
  const float bias = dtpb[d];
  float sdt = 0.f;
  const unsigned short* xc0 = xc_b + rbase * DIN + d;
  __syncthreads();
  for (int i = 0; i < CHL; ++i) {
    const float* pr = &prs[i * 48];
    float4 r0 = *(const float4*)pr;
    float4 r1 = *(const float4*)(pr + 4);
    float4 r2 = *(const float4*)(pr + 8);
    float4 r3 = *(const float4*)(pr + 12);
    float a0 = fmaf(w[0], r0.x, fmaf(w[1],  r0.y, fmaf(w[2],  r0.z, w[3]  * r0.w)));
    float a1 = fmaf(w[4], r1.x, fmaf(w[5],  r1.y, fmaf(w[6],  r1.z, w[7]  * r1.w)));
    float a2 = fmaf(w[8], r2.x, fmaf(w[9],  r2.y, fmaf(w[10], r2.z, w[11] * r2.w)));
    float a3 = fmaf(w[12],r3.x, fmaf(w[13], r3.y, fmaf(w[14], r3.z, w[15] * r3.w)));
    const float dt = splusf(bias + ((a0 + a1) + (a2 + a3)));
    sdt += dt;
    const float dtx = dt * b2f(xc0[(size_t)i * DIN]);
    float dA[16];
    if (lin) {
      const float e1 = __expf(dt * An0);
      const float e2 = e1 * e1, e3 = e2 * e1, e4 = e2 * e2;
      dA[0] = e1; dA[1] = e2; dA[2] = e3; dA[3] = e4;
#pragma unroll
      for (int n = 4; n < 16; ++n) dA[n] = dA[n-4] * e4;
    } else {
#pragma unroll
      for (int n = 0; n < 16; ++n) dA[n] = __expf(dt * An[n]);
    }
#pragma unroll
    for (int q = 0; q < 4; ++q) {
      float4 B4 = *(const float4*)(pr + 16 + q*4);
      h[q*4+0] = fmaf(dA[q*4+0], h[q*4+0], dtx * B4.x);
      h[q*4+1] = fmaf(dA[q*4+1], h[q*4+1], dtx * B4.y);
      h[q*4+2] = fmaf(dA[q*4+2], h[q*4+2], dtx * B4.z);
      h[q*4+3] = fmaf(dA[q*4+3], h[q*4+3], dtx * B4.w);
    }
  }
  float* o = PS + ((size_t)bx * 512 + d) * 32;
#pragma unroll
  for (int q = 0; q < 4; ++q) {
    float4 p4 = make_float4(__expf(sdt*An[q*4+0]), __expf(sdt*An[q*4+1]),
                            __expf(sdt*An[q*4+2]), __expf(sdt*An[q*4+3]));
    *(float4*)(o + q*4) = p4;
  }
#pragma unroll
  for (int q = 0; q < 4; ++q)
    *(float4*)(o + 16 + q*4) = make_float4(h[q*4], h[q*4+1], h[q*4+2], h[q*4+3]);
}

// ---------------------------------------------------------------------------
// K6: scan phase B — combine chunk summaries, store chunk-entry states
// ---------------------------------------------------------------------------
__global__ __launch_bounds__(256)
void k_scanB(const float* __restrict__ PS, float* __restrict__ hst) {
  const int tid = blockIdx.x * 256 + threadIdx.x;  // (b*512 + d)*16 + n
  const int n = tid & 15;
  const int d = (tid >> 4) & 511;
  const int b = tid >> 13;
  float h = 0.f;
  for (int c = 0; c < NCHK; ++c) {
    const size_t idx = (size_t)((b*NCHK + c)*512 + d);
    hst[idx*16 + n] = h;
    h = PS[idx*32 + n] * h + PS[idx*32 + 16 + n];
  }
}

// ---------------------------------------------------------------------------
// K7: scan phase C — rescan from entry state, gated y -> bf16 channel-last
// ---------------------------------------------------------------------------
__global__ __launch_bounds__(512, 4)
void k_scanC(const float* __restrict__ proj, const unsigned short* __restrict__ xc_b,
             const float* __restrict__ zs, const float* __restrict__ hst,
             const float* __restrict__ dtpw, const float* __restrict__ dtpb,
             const float* __restrict__ A_log, const float* __restrict__ Dpar,
             unsigned short* __restrict__ ydata) {
  __shared__ float prs[CHL * 48];
  const int bx = blockIdx.x;
  const int b = bx >> 6, c = bx & 63;
  const int d = threadIdx.x;
  const size_t rbase = (size_t)b * LHW + c * CHL;
  {
    const float4* src = (const float4*)(proj + rbase * 48);
    float4* dst = (float4*)prs;
    for (int i = d; i < CHL * 12; i += 512) dst[i] = src[i];
  }
  float w[16], An[16], h[16];
#pragma unroll
  for (int q = 0; q < 4; ++q)
    *(float4*)(&w[q*4]) = *(const float4*)(dtpw + d*16 + q*4);
#pragma unroll
  for (int q = 0; q < 4; ++q) {
    float4 a4 = *(const float4*)(A_log + d*16 + q*4);
    An[q*4+0] = -__expf(a4.x); An[q*4+1] = -__expf(a4.y);
    An[q*4+2] = -__expf(a4.z); An[q*4+3] = -__expf(a4.w);
  }
#pragma unroll
  for (int q = 0; q < 4; ++q) {
    float4 h4 = *(const float4*)(hst + ((size_t)bx * 512 + d) * 16 + q*4);
    h[q*4+0] = h4.x; h[q*4+1] = h4.y; h[q*4+2] = h4.z; h[q*4+3] = h4.w;
  }
  const float An0 = An[0];
  bool lin = true;
#pragma unroll
  for (int n = 1; n < 16; ++n)
    lin = lin && (fabsf(An[n] - (n + 1) * An0) <= 1e-4f * fabsf(An[n]));
  const float bias = dtpb[d];
  const float dp = Dpar[d];
  const unsigned short* xc0 = xc_b + rbase * DIN + d;
  const float* zs0 = zs + rbase * DIN + d;
  unsigned short* y0 = ydata + rbase * DIN + d;
  __syncthreads();
  for (int i = 0; i < CHL; ++i) {
    const float* pr = &prs[i * 48];
    float4 r0 = *(const float4*)pr;
    float4 r1 = *(const float4*)(pr + 4);
    float4 r2 = *(const float4*)(pr + 8);
    float4 r3 = *(const float4*)(pr + 12);
    float a0 = fmaf(w[0], r0.x, fmaf(w[1],  r0.y, fmaf(w[2],  r0.z, w[3]  * r0.w)));
    float a1 = fmaf(w[4], r1.x, fmaf(w[5],  r1.y, fmaf(w[6],  r1.z, w[7]  * r1.w)));
    float a2 = fmaf(w[8], r2.x, fmaf(w[9],  r2.y, fmaf(w[10], r2.z, w[11] * r2.w)));
    float a3 = fmaf(w[12],r3.x, fmaf(w[13], r3.y, fmaf(w[14], r3.z, w[15] * r3.w)));
    const float dt = splusf(bias + ((a0 + a1) + (a2 + a3)));
    const float xt = b2f(xc0[(size_t)i * DIN]);
    const float dtx = dt * xt;
    float dA[16];
    if (lin) {
      const float e1 = __expf(dt * An0);
      const float e2 = e1 * e1, e3 = e2 * e1, e4 = e2 * e2;
      dA[0] = e1; dA[1] = e2; dA[2] = e3; dA[3] = e4;
#pragma unroll
      for (int n = 4; n < 16; ++n) dA[n] = dA[n-4] * e4;
    } else {
#pragma unroll
      for (int n = 0; n < 16; ++n) dA[n] = __expf(dt * An[n]);
    }
    float y0a = 0.f, y1a = 0.f, y2a = 0.f, y3a = 0.f;
#pragma unroll
    for (int q = 0; q < 4; ++q) {
      float4 B4 = *(const float4*)(pr + 16 + q*4);
      float4 C4 = *(const float4*)(pr + 32 + q*4);
      h[q*4+0] = fmaf(dA[q*4+0], h[q*4+0], dtx * B4.x);
      h[q*4+1] = fmaf(dA[q*4+1], h[q*4+1], dtx * B4.y);
      h[q*4+2] = fmaf(dA[q*4+2], h[q*4+2], dtx * B4.z);
      h[q*4+3] = fmaf(dA[q*4+3], h[q*4+3], dtx * B4.w);
      y0a = fmaf(h[q*4+0], C4.x, y0a);
      y1a = fmaf(h[q*4+1], C4.y, y1a);
      y2a = fmaf(h[q*4+2], C4.z, y2a);
      y3a = fmaf(h[q*4+3], C4.w, y3a);
    }
    const float y = (y0a + y1a) + (y2a + y3a);
    const float ov = (y + xt * dp) * zs0[(size_t)i * DIN];
    y0[(size_t)i * DIN] = f2b(ov);
  }
}

// ---------------------------------------------------------------------------
// G4: outproj + residual(ub) -> padded channel-last bf16 xrp
// ---------------------------------------------------------------------------
__global__ __launch_bounds__(256)
void k_outproj_mfma(const unsigned short* __restrict__ ydata, const unsigned short* __restrict__ opwb,
                    const unsigned short* __restrict__ ub, unsigned short* __restrict__ xrp) {
  __shared__ __align__(16) unsigned short As[4096], Bs[4096];
  const int t = threadIdx.x, lane = t & 63, w = t >> 6;
  const int wm = w >> 1, wn = w & 1;
  const int b = blockIdx.z, m0 = blockIdx.y * 128, n0 = blockIdx.x * 128;
  f32x4 acc[4][4] = {};
  gemm_loop_128<512, 512, 512>(ydata + ((size_t)b * LHW + m0) * 512,
                               opwb + (size_t)n0 * 512, As, Bs, t, acc);
  const int fr = lane & 15, q4 = (lane >> 4) * 4;
#pragma unroll
  for (int i = 0; i < 4; ++i) {
    const int lbase = m0 + wm*64 + i*16 + q4;
#pragma unroll
    for (int q = 0; q < 4; ++q) {
      const int l = lbase + q;
      const int pos = ((l >> 6) + 1) * PW + (l & 63) + 1;
#pragma unroll
      for (int j = 0; j < 4; ++j) {
        const int o = n0 + wn*64 + j*16 + fr;
        const float r = b2f(ub[((size_t)b * LHW + l) * COUT + o]);
        xrp[((size_t)b * PPOS + pos) * COUT + o] = f2b(acc[i][j][q] + r);
      }
    }
  }
}

// ---------------------------------------------------------------------------
// G5: refine 3x3 conv as MFMA implicit GEMM + BN + ReLU
// ---------------------------------------------------------------------------
__global__ __launch_bounds__(256)
void k_refine_mfma(const unsigned short* __restrict__ Aw,
                   const unsigned short* __restrict__ xrp,
                   const float* __restrict__ rb, const float* __restrict__ bng,
                   const float* __restrict__ bnb, const float* __restrict__ bnm,
                   const float* __restrict__ bnv, float* __restrict__ out) {
  __shared__ __align__(16) unsigned short As[4096], Bs[4096];
  const int t = threadIdx.x;
  const int lane = t & 63;
  const int w = t >> 6;
  const int wm = w >> 1, wn = w & 1;
  const int b  = blockIdx.z;
  const int m0 = blockIdx.y * 128;
  const int n0 = blockIdx.x * 128;
  const int y0 = n0 >> 6;
  const unsigned short* xb = xrp + (size_t)b * PPOS * COUT;
  const int arow = t >> 2;
  const int acol = (t & 3) * 8;
  f32x4 acc[4][4] = {};
  for (int ks = 0; ks < 72; ++ks) {
    const int tap = ks >> 3;
    const int i0  = (ks & 7) * 32;
    const int ky  = tap / 3, kx = tap - ky * 3;
    const int k0  = tap * 256 + i0;
    const unsigned short* ga0 = Aw + (size_t)(m0 + arow) * 2304 + k0 + acol;
    const unsigned short* gb0 = xb + ((size_t)((y0 + ky) * PW + kx + arow)) * COUT + i0 + acol;
    __syncthreads();
    gload16(ga0,              &As[w * 512]);
    gload16(ga0 + 64 * 2304,  &As[2048 + w * 512]);
    gload16(gb0,              &Bs[w * 512]);
    gload16(gb0 + PW * COUT,  &Bs[2048 + w * 512]);
    __syncthreads();
    const int fr = lane & 15, g8 = (lane >> 4) * 8;
    bf16x8 af[4], bfr[4];
#pragma unroll
    for (int f = 0; f < 4; ++f) {
      af[f]  = *(const bf16x8*)&As[(wm*64 + f*16 + fr) * 32 + g8];
      bfr[f] = *(const bf16x8*)&Bs[(wn*64 + f*16 + fr) * 32 + g8];
    }
#pragma unroll
    for (int i = 0; i < 4; ++i)
#pragma unroll
      for (int j = 0; j < 4; ++j)
        acc[i][j] = __builtin_amdgcn_mfma_f32_16x16x32_bf16(af[i], bfr[j], acc[i][j], 0, 0, 0);
  }
  const int fr = lane & 15, q4 = (lane >> 4) * 4;
#pragma unroll
  for (int i = 0; i < 4; ++i) {
    const int obase = m0 + wm*64 + i*16 + q4;
#pragma unroll
    for (int q = 0; q < 4; ++q) {
      const int o = obase + q;
      const float inv = bng[o] * rsqrtf(bnv[o] + 1e-5f);
      const float sh  = (rb[o] - bnm[o]) * inv + bnb[o];
      float* orow = out + ((size_t)b * COUT + o) * LHW + n0 + wn*64 + fr;
#pragma unroll
      for (int j = 0; j < 4; ++j)
        orow[j*16] = fmaxf(fmaf(acc[i][j][q], inv, sh), 0.f);
    }
  }
}

// ---------------------------------------------------------------------------
extern "C" void kernel_launch(void* const* d_in, const int* in_sizes, int n_in,
                              void* d_out, int out_size, void* d_ws, size_t ws_size,
                              hipStream_t stream) {
  const float* x    = (const float*)d_in[0];
  const float* lw   = (const float*)d_in[1];
  const float* lb   = (const float*)d_in[2];
  const float* ipw  = (const float*)d_in[3];
  const float* cw   = (const float*)d_in[4];
  const float* cb   = (const float*)d_in[5];
  const float* xpw  = (const float*)d_in[6];
  const float* dtpw = (const float*)d_in[7];
  const float* dtpb = (const float*)d_in[8];
  const float* Alog = (const float*)d_in[9];
  const float* Dpar = (const float*)d_in[10];
  const float* opw  = (const float*)d_in[11];
  const float* rw   = (const float*)d_in[12];
  const float* rb   = (const float*)d_in[13];
  const float* bng  = (const float*)d_in[14];
  const float* bnb  = (const float*)d_in[15];
  const float* bnm  = (const float*)d_in[16];
  const float* bnv  = (const float*)d_in[17];
  float* out = (float*)d_out;

  float* ws = (float*)d_ws;
  unsigned short* ub   = (unsigned short*)ws;                      // 8.4M us
  unsigned short* xt   = (unsigned short*)(ws + 4194304);          // 16.8M us (reused as xrp)
  unsigned short* xm_b = (unsigned short*)(ws + 12582912);         // 16.8M us (reused as ydata)
  unsigned short* xc_b = (unsigned short*)(ws + 20971520);         // 16.8M us
  float* zs   = ws + 29360128;                                     // 16.8M f
  float* proj = ws + 46137344;                                     //  1.6M f
  float* PS   = ws + 47710208;                                     //  8.4M f  (NB*NCHK*512*32)
  float* hst  = ws + 56098816;                                     //  4.2M f  (NB*NCHK*512*16)
  unsigned short* wb = (unsigned short*)(ws + 60293120);           //  1.15M us
  unsigned short* lwb  = wb;
  unsigned short* ipwb = wb + WO1;
  unsigned short* xpwb = wb + WO2;
  unsigned short* opwb = wb + WO3;
  unsigned short* Aw   = wb + WO4;
  unsigned short* ydata = xm_b;
  unsigned short* xrp   = xt;

  k_wprep<<<dim3(4480), 256, 0, stream>>>(lw, ipw, xpw, opw, rw, wb);
  k_xpose<<<dim3(64, 8, 8), 256, 0, stream>>>(x, xt);
  k_lat_mfma<<<dim3(2, 32, 8), 256, 0, stream>>>(xt, lwb, lb, ub);
  hipMemsetAsync(xrp, 0, (size_t)NB * PPOS * COUT * sizeof(unsigned short), stream);
  k_inproj_mfma<<<dim3(8, 32, 8), 256, 0, stream>>>(ub, ipwb, xm_b, zs);
  k_conv1d<<<dim3(8192), 256, 0, stream>>>(xm_b, cw, cb, xc_b);
  k_xproj_mfma<<<dim3(32, 8), 256, 0, stream>>>(xc_b, xpwb, proj);
  k_scanA<<<dim3(NB * NCHK), 512, 0, stream>>>(proj, xc_b, dtpw, dtpb, Alog, PS);
  k_scanB<<<dim3(256), 256, 0, stream>>>(PS, hst);
  k_scanC<<<dim3(NB * NCHK), 512, 0, stream>>>(proj, xc_b, zs, hst, dtpw, dtpb, Alog, Dpar, ydata);
  k_outproj_mfma<<<dim3(2, 32, 8), 256, 0, stream>>>(ydata, opwb, ub, xrp);
  k_refine_mfma<<<dim3(32, 2, 8), 256, 0, stream>>>(Aw, xrp, rb, bng, bnb, bnm, bnv, out);
}

// Round 5
// 411.823 us; speedup vs baseline: 12.7818x; 1.1260x over previous
//
#include <hip/hip_runtime.h>
#include <math.h>

#define NB   8
#define CIN  512
#define COUT 256
#define DIN  512
#define LHW  4096
#define NCHK 64
#define CHL  64
#define PW   66
#define PPOS (PW*PW)

typedef __attribute__((ext_vector_type(8))) short bf16x8;
typedef __attribute__((ext_vector_type(4))) float f32x4;

__device__ __forceinline__ float siluf(float v)  { return v / (1.f + __expf(-v)); }
__device__ __forceinline__ float splusf(float v) { return v > 20.f ? v : log1pf(__expf(v)); }

__device__ __forceinline__ unsigned short f2b(float f) {
  union { float f; unsigned u; } v; v.f = f;
  unsigned r = v.u + 0x7fff + ((v.u >> 16) & 1);
  return (unsigned short)(r >> 16);
}
__device__ __forceinline__ float b2f(unsigned int u) {
  union { unsigned u; float f; } v; v.u = (u & 0xffffu) << 16; return v.f;
}

__device__ __forceinline__ void gload16(const unsigned short* g, unsigned short* l) {
  __builtin_amdgcn_global_load_lds(
      (const __attribute__((address_space(1))) unsigned int*)g,
      (__attribute__((address_space(3))) unsigned int*)l, 16, 0, 0);
}

// ---------------------------------------------------------------------------
// W: weight prep — convert all GEMM weights to bf16 (xpw padded 48->64)
// ---------------------------------------------------------------------------
#define WO1 131072
#define WO2 393216
#define WO3 425984
#define WO4 557056
__global__ __launch_bounds__(256)
void k_wprep(const float* __restrict__ lw, const float* __restrict__ ipw,
             const float* __restrict__ xpw, const float* __restrict__ opw,
             const float* __restrict__ rw, unsigned short* __restrict__ wb) {
  const int i = blockIdx.x * 256 + threadIdx.x;
  if (i < WO1)      wb[i] = f2b(lw[i]);
  else if (i < WO2) wb[i] = f2b(ipw[i - WO1]);
  else if (i < WO3) {
    const int j = i - WO2, row = j >> 9, col = j & 511;
    wb[i] = (row < 48) ? f2b(xpw[row * 512 + col]) : (unsigned short)0;
  }
  else if (i < WO4) wb[i] = f2b(opw[i - WO3]);
  else {
    const int j = i - WO4, o = j / 2304, kk = j % 2304;
    const int tap = kk >> 8, ch = kk & 255;
    wb[i] = f2b(rw[(o * 256 + ch) * 9 + tap]);
  }
}

// ---------------------------------------------------------------------------
// T: transpose x (b,k,l) f32 -> xt (b,l,k) bf16
// ---------------------------------------------------------------------------
__global__ __launch_bounds__(256)
void k_xpose(const float* __restrict__ x, unsigned short* __restrict__ xt) {
  __shared__ unsigned short Ts[64][80];
  const int b  = blockIdx.z;
  const int k0 = blockIdx.y * 64;
  const int l0 = blockIdx.x * 64;
  const int t  = threadIdx.x;
  const int tx = t & 15, ty = t >> 4;
#pragma unroll
  for (int r = 0; r < 4; ++r) {
    const int k = ty + r * 16;
    float4 v = *(const float4*)(x + ((size_t)b * CIN + k0 + k) * LHW + l0 + tx * 4);
    Ts[tx*4+0][k] = f2b(v.x);
    Ts[tx*4+1][k] = f2b(v.y);
    Ts[tx*4+2][k] = f2b(v.z);
    Ts[tx*4+3][k] = f2b(v.w);
  }
  __syncthreads();
  const int lr = t >> 2, kc = (t & 3) * 16;
  unsigned short* dst = xt + ((size_t)b * LHW + l0 + lr) * CIN + k0 + kc;
  *(uint4*)dst       = *(const uint4*)&Ts[lr][kc];
  *(uint4*)(dst + 8) = *(const uint4*)&Ts[lr][kc + 8];
}

// ---------------------------------------------------------------------------
// shared MFMA main loop: 128x128 tile, BK=32
// ---------------------------------------------------------------------------
template<int RSA, int RSB, int KTOT>
__device__ __forceinline__ void gemm_loop_128(
    const unsigned short* __restrict__ Ab, const unsigned short* __restrict__ Bb,
    unsigned short* As, unsigned short* Bs, int t, f32x4 acc[4][4]) {
  const int w = t >> 6, lane = t & 63;
  const int wm = w >> 1, wn = w & 1;
  const int arow = t >> 2, acol = (t & 3) * 8;
  const int fr = lane & 15, g8 = (lane >> 4) * 8;
  for (int k0 = 0; k0 < KTOT; k0 += 32) {
    __syncthreads();
    gload16(Ab + (size_t)arow * RSA + k0 + acol,        &As[w * 512]);
    gload16(Ab + (size_t)(64 + arow) * RSA + k0 + acol, &As[2048 + w * 512]);
    gload16(Bb + (size_t)arow * RSB + k0 + acol,        &Bs[w * 512]);
    gload16(Bb + (size_t)(64 + arow) * RSB + k0 + acol, &Bs[2048 + w * 512]);
    __syncthreads();
    bf16x8 af[4], bf[4];
#pragma unroll
    for (int f = 0; f < 4; ++f) {
      af[f] = *(const bf16x8*)&As[(wm*64 + f*16 + fr) * 32 + g8];
      bf[f] = *(const bf16x8*)&Bs[(wn*64 + f*16 + fr) * 32 + g8];
    }
#pragma unroll
    for (int i = 0; i < 4; ++i)
#pragma unroll
      for (int j = 0; j < 4; ++j)
        acc[i][j] = __builtin_amdgcn_mfma_f32_16x16x32_bf16(af[i], bf[j], acc[i][j], 0, 0, 0);
  }
}

// ---------------------------------------------------------------------------
// G1: lateral — ub[b][l][o] = bf16( sum_k xt[b][l][k]*lwb[o][k] + lb[o] )
// ---------------------------------------------------------------------------
__global__ __launch_bounds__(256)
void k_lat_mfma(const unsigned short* __restrict__ xt, const unsigned short* __restrict__ lwb,
                const float* __restrict__ lb, unsigned short* __restrict__ ub) {
  __shared__ __align__(16) unsigned short As[4096], Bs[4096];
  const int t = threadIdx.x, lane = t & 63, w = t >> 6;
  const int wm = w >> 1, wn = w & 1;
  const int b = blockIdx.z, m0 = blockIdx.y * 128, n0 = blockIdx.x * 128;
  f32x4 acc[4][4] = {};
  gemm_loop_128<512, 512, 512>(xt + ((size_t)b * LHW + m0) * 512,
                               lwb + (size_t)n0 * 512, As, Bs, t, acc);
  const int fr = lane & 15, q4 = (lane >> 4) * 4;
#pragma unroll
  for (int i = 0; i < 4; ++i) {
    const int l = m0 + wm*64 + i*16 + q4;
#pragma unroll
    for (int j = 0; j < 4; ++j) {
      const int o = n0 + wn*64 + j*16 + fr;
      const float bias = lb[o];
      unsigned short* dst = ub + ((size_t)b * LHW + l) * COUT + o;
#pragma unroll
      for (int q = 0; q < 4; ++q)
        dst[(size_t)q * COUT] = f2b(acc[i][j][q] + bias);
    }
  }
}

// ---------------------------------------------------------------------------
// G2: inproj — e<512 -> xm_b bf16 ; e>=512 -> silu -> zsb bf16
// ---------------------------------------------------------------------------
__global__ __launch_bounds__(256)
void k_inproj_mfma(const unsigned short* __restrict__ ub, const unsigned short* __restrict__ ipwb,
                   unsigned short* __restrict__ xm_b, unsigned short* __restrict__ zsb) {
  __shared__ __align__(16) unsigned short As[4096], Bs[4096];
  const int t = threadIdx.x, lane = t & 63, w = t >> 6;
  const int wm = w >> 1, wn = w & 1;
  const int b = blockIdx.z, m0 = blockIdx.y * 128, n0 = blockIdx.x * 128;
  f32x4 acc[4][4] = {};
  gemm_loop_128<256, 256, 256>(ub + ((size_t)b * LHW + m0) * 256,
                               ipwb + (size_t)n0 * 256, As, Bs, t, acc);
  const int fr = lane & 15, q4 = (lane >> 4) * 4;
  const bool isz = (n0 >= 512);
#pragma unroll
  for (int i = 0; i < 4; ++i) {
    const int l = m0 + wm*64 + i*16 + q4;
#pragma unroll
    for (int j = 0; j < 4; ++j) {
      const int e = n0 + wn*64 + j*16 + fr;
      if (isz) {
        unsigned short* dst = zsb + ((size_t)b * LHW + l) * DIN + (e - 512);
#pragma unroll
        for (int q = 0; q < 4; ++q)
          dst[(size_t)q * DIN] = f2b(siluf(acc[i][j][q]));
      } else {
        unsigned short* dst = xm_b + ((size_t)b * LHW + l) * DIN + e;
#pragma unroll
        for (int q = 0; q < 4; ++q)
          dst[(size_t)q * DIN] = f2b(acc[i][j][q]);
      }
    }
  }
}

// ---------------------------------------------------------------------------
// K3: depthwise causal conv1d + bias + silu, bf16 in/out, (b,l,e)
// ---------------------------------------------------------------------------
__global__ __launch_bounds__(256)
void k_conv1d(const unsigned short* __restrict__ xm_b, const float* __restrict__ cw,
              const float* __restrict__ cb, unsigned short* __restrict__ xc_b) {
  const int tid = blockIdx.x * 256 + threadIdx.x;
  const int e8 = tid & 63;
  const int l  = (tid >> 6) & 4095;
  const int b  = tid >> 18;
  const int e0 = e8 * 8;
  float acc[8];
  *(float4*)&acc[0] = *(const float4*)(cb + e0);
  *(float4*)&acc[4] = *(const float4*)(cb + e0 + 4);
  float wv[8][4];
#pragma unroll
  for (int q = 0; q < 8; ++q) {
    float4 w4 = *(const float4*)(cw + (e0 + q) * 4);
    wv[q][0] = w4.x; wv[q][1] = w4.y; wv[q][2] = w4.z; wv[q][3] = w4.w;
  }
  const unsigned short* base = xm_b + (size_t)b * LHW * DIN + e0;
#pragma unroll
  for (int k = 0; k < 4; ++k) {
    const int ll = l - 3 + k;
    if (ll >= 0) {
      uint4 raw = *(const uint4*)(base + (size_t)ll * DIN);
      acc[0] = fmaf(b2f(raw.x),       wv[0][k], acc[0]);
      acc[1] = fmaf(b2f(raw.x >> 16), wv[1][k], acc[1]);
      acc[2] = fmaf(b2f(raw.y),       wv[2][k], acc[2]);
      acc[3] = fmaf(b2f(raw.y >> 16), wv[3][k], acc[3]);
      acc[4] = fmaf(b2f(raw.z),       wv[4][k], acc[4]);
      acc[5] = fmaf(b2f(raw.z >> 16), wv[5][k], acc[5]);
      acc[6] = fmaf(b2f(raw.w),       wv[6][k], acc[6]);
      acc[7] = fmaf(b2f(raw.w >> 16), wv[7][k], acc[7]);
    }
  }
  uint4 o;
  o.x = (unsigned)f2b(siluf(acc[0])) | ((unsigned)f2b(siluf(acc[1])) << 16);
  o.y = (unsigned)f2b(siluf(acc[2])) | ((unsigned)f2b(siluf(acc[3])) << 16);
  o.z = (unsigned)f2b(siluf(acc[4])) | ((unsigned)f2b(siluf(acc[5])) << 16);
  o.w = (unsigned)f2b(siluf(acc[6])) | ((unsigned)f2b(siluf(acc[7])) << 16);
  *(uint4*)(xc_b + ((size_t)b * LHW + l) * DIN + e0) = o;
}

// ---------------------------------------------------------------------------
// G3: xproj — proj[b][l][j] (j<48), 128x64 tile
// ---------------------------------------------------------------------------
__global__ __launch_bounds__(256)
void k_xproj_mfma(const unsigned short* __restrict__ xc_b, const unsigned short* __restrict__ xpwb,
                  float* __restrict__ proj) {
  __shared__ __align__(16) unsigned short As[4096], Bs[2048];
  const int t = threadIdx.x, lane = t & 63, w = t >> 6;
  const int wm = w >> 1, wn = w & 1;
  const int b = blockIdx.y, m0 = blockIdx.x * 128;
  const int arow = t >> 2, acol = (t & 3) * 8;
  const int fr = lane & 15, g8 = (lane >> 4) * 8;
  const unsigned short* Ab = xc_b + ((size_t)b * LHW + m0) * 512;
  f32x4 acc[4][2] = {};
  for (int k0 = 0; k0 < 512; k0 += 32) {
    __syncthreads();
    gload16(Ab + (size_t)arow * 512 + k0 + acol,        &As[w * 512]);
    gload16(Ab + (size_t)(64 + arow) * 512 + k0 + acol, &As[2048 + w * 512]);
    gload16(xpwb + (size_t)arow * 512 + k0 + acol,      &Bs[w * 512]);
    __syncthreads();
    bf16x8 af[4], bf[2];
#pragma unroll
    for (int f = 0; f < 4; ++f)
      af[f] = *(const bf16x8*)&As[(wm*64 + f*16 + fr) * 32 + g8];
#pragma unroll
    for (int f = 0; f < 2; ++f)
      bf[f] = *(const bf16x8*)&Bs[(wn*32 + f*16 + fr) * 32 + g8];
#pragma unroll
    for (int i = 0; i < 4; ++i)
#pragma unroll
      for (int j = 0; j < 2; ++j)
        acc[i][j] = __builtin_amdgcn_mfma_f32_16x16x32_bf16(af[i], bf[j], acc[i][j], 0, 0, 0);
  }
  const int q4 = (lane >> 4) * 4;
#pragma unroll
  for (int i = 0; i < 4; ++i) {
    const int l = m0 + wm*64 + i*16 + q4;
#pragma unroll
    for (int j = 0; j < 2; ++j) {
      const int col = wn*32 + j*16 + fr;
      if (col < 48) {
        float* dst = proj + ((size_t)b * LHW + l) * 48 + col;
#pragma unroll
        for (int q = 0; q < 4; ++q)
          dst[(size_t)q * 48] = acc[i][j][q];
      }
    }
  }
}

// ---------------------------------------------------------------------------
// D: dt precompute — dt[b·l][d] = softplus(bias[d] + proj[b·l][0..15]·dtpw[d])
// block: 512 threads = d, 32 l's per block; output bf16
// ---------------------------------------------------------------------------
__global__ __launch_bounds__(512)
void k_dt(const float* __restrict__ proj, const float* __restrict__ dtpw,
          const float* __restrict__ dtpb, unsigned short* __restrict__ dtb) {
  __shared__ float prs[32 * 16];
  const int d = threadIdx.x;
  const size_t l0 = (size_t)blockIdx.x * 32;
  for (int i = d; i < 32 * 4; i += 512) {
    const int row = i >> 2, c4 = i & 3;
    *(float4*)&prs[row * 16 + c4 * 4] = *(const float4*)(proj + (l0 + row) * 48 + c4 * 4);
  }
  float w[16];
#pragma unroll
  for (int q = 0; q < 4; ++q)
    *(float4*)(&w[q*4]) = *(const float4*)(dtpw + d * 16 + q * 4);
  const float bias = dtpb[d];
  __syncthreads();
#pragma unroll 4
  for (int i = 0; i < 32; ++i) {
    const float* pr = &prs[i * 16];
    float4 r0 = *(const float4*)pr;
    float4 r1 = *(const float4*)(pr + 4);
    float4 r2 = *(const float4*)(pr + 8);
    float4 r3 = *(const float4*)(pr + 12);
    float a0 = fmaf(w[0], r0.x, fmaf(w[1],  r0.y, fmaf(w[2],  r0.z, w[3]  * r0.w)));
    float a1 = fmaf(w[4], r1.x, fmaf(w[5],  r1.y, fmaf(w[6],  r1.z, w[7]  * r1.w)));
    float a2 = fmaf(w[8], r2.x, fmaf(w[9],  r2.y, fmaf(w[10], r2.z, w[11] * r2.w)));
    float a3 = fmaf(w[12],r3.x, fmaf(w[13], r3.y, fmaf(w[14], r3.z, w[15] * r3.w)));
    dtb[(l0 + i) * 512 + d] = f2b(splusf(bias + ((a0 + a1) + (a2 + a3))));
  }
}

// ---------------------------------------------------------------------------
// K5: scan phase A — per (b,chunk): P = exp(An·Σdt), S = local end state.
// dt read from dtb; only B staged in LDS.
// ---------------------------------------------------------------------------
__global__ __launch_bounds__(512, 4)
void k_scanA(const float* __restrict__ proj, const unsigned short* __restrict__ dtb,
             const unsigned short* __restrict__ xc_b,
             const float* __restrict__ A_log, float* __restrict__ PS) {
  __shared__ float prs[CHL * 16];
  const int bx = blockIdx.x;
  const int b = bx >> 6, c = bx & 63;
  const int d = threadIdx.x;
  const size_t rbase = (size_t)b * LHW + c * CHL;
  for (int i = d; i < CHL * 4; i += 512) {
    const int row = i >> 2, c4 = i & 3;
    *(float4*)&prs[row * 16 + c4 * 4] = *(const float4*)(proj + (rbase + row) * 48 + 16 + c4 * 4);
  }
  float An[16], h[16];
#pragma unroll
  for (int q = 0; q < 4; ++q) {
    float4 a4 = *(const float4*)(A_log + d*16 + q*4);
    An[q*4+0] = -__expf(a4.x); An[q*4+1] = -__expf(a4.y);
    An[q*4+2] = -__expf(a4.z); An[q*4+3] = -__expf(a4.w);
  }
#pragma unroll
  for (int n = 0; n < 16; ++n) h[n] = 0.f;
  const float An0 = An[0];
  bool lin = true;
#pragma unroll
  for (int n = 1; n < 16; ++n)
    lin = lin && (fabsf(An[n] - (n + 1) * An0) <= 1e-4f * fabsf(An[n]));
  float sdt = 0.f;
  const unsigned short* dt0 = dtb + rbase * 512 + d;
  const unsigned short* xc0 = xc_b + rbase * DIN + d;
  __syncthreads();
  for (int i = 0; i < CHL; ++i) {
    const float dt = b2f(dt0[(size_t)i * 512]);
    sdt += dt;
    const float dtx = dt * b2f(xc0[(size_t)i * DIN]);
    float dA[16];
    if (lin) {
      const float e1 = __expf(dt * An0);
      const float e2 = e1 * e1, e3 = e2 * e1, e4 = e2 * e2;
      dA[0] = e1; dA[1] = e2; dA[2] = e3; dA[3] = e4;
#pragma unroll
      for (int n = 4; n < 16; ++n) dA[n] = dA[n-4] * e4;
    } else {
#pragma unroll
      for (int n = 0; n < 16; ++n) dA[n] = __expf(dt * An[n]);
    }
    const float* pr = &prs[i * 16];
#pragma unroll
    for (int q = 0; q < 4; ++q) {
      float4 B4 = *(const float4*)(pr + q*4);
      h[q*4+0] = fmaf(dA[q*4+0], h[q*4+0], dtx * B4.x);
      h[q*4+1] = fmaf(dA[q*4+1], h[q*4+1], dtx * B4.y);
      h[q*4+2] = fmaf(dA[q*4+2], h[q*4+2], dtx * B4.z);
      h[q*4+3] = fmaf(dA[q*4+3], h[q*4+3], dtx * B4.w);
    }
  }
  float* o = PS + ((size_t)bx * 512 + d) * 32;
#pragma unroll
  for (int q = 0; q < 4; ++q)
    *(float4*)(o + q*4) = make_float4(__expf(sdt*An[q*4+0]), __expf(sdt*An[q*4+1]),
                                      __expf(sdt*An[q*4+2]), __expf(sdt*An[q*4+3]));
#pragma unroll
  for (int q = 0; q < 4; ++q)
    *(float4*)(o + 16 + q*4) = make_float4(h[q*4], h[q*4+1], h[q*4+2], h[q*4+3]);
}

// ---------------------------------------------------------------------------
// K6: scan phase B — combine chunk summaries, store chunk-entry states
// ---------------------------------------------------------------------------
__global__ __launch_bounds__(256)
void k_scanB(const float* __restrict__ PS, float* __restrict__ hst) {
  const int tid = blockIdx.x * 256 + threadIdx.x;
  const int n = tid & 15;
  const int d = (tid >> 4) & 511;
  const int b = tid >> 13;
  float h = 0.f;
  for (int c = 0; c < NCHK; ++c) {
    const size_t idx = (size_t)((b*NCHK + c)*512 + d);
    hst[idx*16 + n] = h;
    h = PS[idx*32 + n] * h + PS[idx*32 + 16 + n];
  }
}

// ---------------------------------------------------------------------------
// K7: scan phase C — rescan from entry state; B,C staged in LDS; dt from dtb
// ---------------------------------------------------------------------------
__global__ __launch_bounds__(512, 4)
void k_scanC(const float* __restrict__ proj, const unsigned short* __restrict__ dtb,
             const unsigned short* __restrict__ xc_b,
             const unsigned short* __restrict__ zsb, const float* __restrict__ hst,
             const float* __restrict__ A_log, const float* __restrict__ Dpar,
             unsigned short* __restrict__ ydata) {
  __shared__ float prs[CHL * 32];
  const int bx = blockIdx.x;
  const int b = bx >> 6, c = bx & 63;
  const int d = threadIdx.x;
  const size_t rbase = (size_t)b * LHW + c * CHL;
  for (int i = d; i < CHL * 8; i += 512) {
    const int row = i >> 3, c4 = i & 7;
    *(float4*)&prs[row * 32 + c4 * 4] = *(const float4*)(proj + (rbase + row) * 48 + 16 + c4 * 4);
  }
  float An[16], h[16];
#pragma unroll
  for (int q = 0; q < 4; ++q) {
    float4 a4 = *(const float4*)(A_log + d*16 + q*4);
    An[q*4+0] = -__expf(a4.x); An[q*4+1] = -__expf(a4.y);
    An[q*4+2] = -__expf(a4.z); An[q*4+3] = -__expf(a4.w);
  }
#pragma unroll
  for (int q = 0; q < 4; ++q) {
    float4 h4 = *(const float4*)(hst + ((size_t)bx * 512 + d) * 16 + q*4);
    h[q*4+0] = h4.x; h[q*4+1] = h4.y; h[q*4+2] = h4.z; h[q*4+3] = h4.w;
  }
  const float An0 = An[0];
  bool lin = true;
#pragma unroll
  for (int n = 1; n < 16; ++n)
    lin = lin && (fabsf(An[n] - (n + 1) * An0) <= 1e-4f * fabsf(An[n]));
  const float dp = Dpar[d];
  const unsigned short* dt0 = dtb + rbase * 512 + d;
  const unsigned short* xc0 = xc_b + rbase * DIN + d;
  const unsigned short* zs0 = zsb + rbase * DIN + d;
  unsigned short* y0 = ydata + rbase * DIN + d;
  __syncthreads();
  for (int i = 0; i < CHL; ++i) {
    const float dt = b2f(dt0[(size_t)i * 512]);
    const float xt = b2f(xc0[(size_t)i * DIN]);
    const float zv = b2f(zs0[(size_t)i * DIN]);
    const float dtx = dt * xt;
    float dA[16];
    if (lin) {
      const float e1 = __expf(dt * An0);
      const float e2 = e1 * e1, e3 = e2 * e1, e4 = e2 * e2;
      dA[0] = e1; dA[1] = e2; dA[2] = e3; dA[3] = e4;
#pragma unroll
      for (int n = 4; n < 16; ++n) dA[n] = dA[n-4] * e4;
    } else {
#pragma unroll
      for (int n = 0; n < 16; ++n) dA[n] = __expf(dt * An[n]);
    }
    const float* pr = &prs[i * 32];
    float y0a = 0.f, y1a = 0.f, y2a = 0.f, y3a = 0.f;
#pragma unroll
    for (int q = 0; q < 4; ++q) {
      float4 B4 = *(const float4*)(pr + q*4);
      float4 C4 = *(const float4*)(pr + 16 + q*4);
      h[q*4+0] = fmaf(dA[q*4+0], h[q*4+0], dtx * B4.x);
      h[q*4+1] = fmaf(dA[q*4+1], h[q*4+1], dtx * B4.y);
      h[q*4+2] = fmaf(dA[q*4+2], h[q*4+2], dtx * B4.z);
      h[q*4+3] = fmaf(dA[q*4+3], h[q*4+3], dtx * B4.w);
      y0a = fmaf(h[q*4+0], C4.x, y0a);
      y1a = fmaf(h[q*4+1], C4.y, y1a);
      y2a = fmaf(h[q*4+2], C4.z, y2a);
      y3a = fmaf(h[q*4+3], C4.w, y3a);
    }
    const float y = (y0a + y1a) + (y2a + y3a);
    y0[(size_t)i * DIN] = f2b((y + xt * dp) * zv);
  }
}

// ---------------------------------------------------------------------------
// G4: outproj + residual(ub) -> padded channel-last bf16 xrp
// ---------------------------------------------------------------------------
__global__ __launch_bounds__(256)
void k_outproj_mfma(const unsigned short* __restrict__ ydata, const unsigned short* __restrict__ opwb,
                    const unsigned short* __restrict__ ub, unsigned short* __restrict__ xrp) {
  __shared__ __align__(16) unsigned short As[4096], Bs[4096];
  const int t = threadIdx.x, lane = t & 63, w = t >> 6;
  const int wm = w >> 1, wn = w & 1;
  const int b = blockIdx.z, m0 = blockIdx.y * 128, n0 = blockIdx.x * 128;
  f32x4 acc[4][4] = {};
  gemm_loop_128<512, 512, 512>(ydata + ((size_t)b * LHW + m0) * 512,
                               opwb + (size_t)n0 * 512, As, Bs, t, acc);
  const int fr = lane & 15, q4 = (lane >> 4) * 4;
#pragma unroll
  for (int i = 0; i < 4; ++i) {
    const int lbase = m0 + wm*64 + i*16 + q4;
#pragma unroll
    for (int q = 0; q < 4; ++q) {
      const int l = lbase + q;
      const int pos = ((l >> 6) + 1) * PW + (l & 63) + 1;
#pragma unroll
      for (int j = 0; j < 4; ++j) {
        const int o = n0 + wn*64 + j*16 + fr;
        const float r = b2f(ub[((size_t)b * LHW + l) * COUT + o]);
        xrp[((size_t)b * PPOS + pos) * COUT + o] = f2b(acc[i][j][q] + r);
      }
    }
  }
}

// ---------------------------------------------------------------------------
// G5: refine 3x3 conv as MFMA implicit GEMM + BN + ReLU
// ---------------------------------------------------------------------------
__global__ __launch_bounds__(256)
void k_refine_mfma(const unsigned short* __restrict__ Aw,
                   const unsigned short* __restrict__ xrp,
                   const float* __restrict__ rb, const float* __restrict__ bng,
                   const float* __restrict__ bnb, const float* __restrict__ bnm,
                   const float* __restrict__ bnv, float* __restrict__ out) {
  __shared__ __align__(16) unsigned short As[4096], Bs[4096];
  const int t = threadIdx.x;
  const int lane = t & 63;
  const int w = t >> 6;
  const int wm = w >> 1, wn = w & 1;
  const int b  = blockIdx.z;
  const int m0 = blockIdx.y * 128;
  const int n0 = blockIdx.x * 128;
  const int y0 = n0 >> 6;
  const unsigned short* xb = xrp + (size_t)b * PPOS * COUT;
  const int arow = t >> 2;
  const int acol = (t & 3) * 8;
  f32x4 acc[4][4] = {};
  for (int ks = 0; ks < 72; ++ks) {
    const int tap = ks >> 3;
    const int i0  = (ks & 7) * 32;
    const int ky  = tap / 3, kx = tap - ky * 3;
    const int k0  = tap * 256 + i0;
    const unsigned short* ga0 = Aw + (size_t)(m0 + arow) * 2304 + k0 + acol;
    const unsigned short* gb0 = xb + ((size_t)((y0 + ky) * PW + kx + arow)) * COUT + i0 + acol;
    __syncthreads();
    gload16(ga0,              &As[w * 512]);
    gload16(ga0 + 64 * 2304,  &As[2048 + w * 512]);
    gload16(gb0,              &Bs[w * 512]);
    gload16(gb0 + PW * COUT,  &Bs[2048 + w * 512]);
    __syncthreads();
    const int fr = lane & 15, g8 = (lane >> 4) * 8;
    bf16x8 af[4], bfr[4];
#pragma unroll
    for (int f = 0; f < 4; ++f) {
      af[f]  = *(const bf16x8*)&As[(wm*64 + f*16 + fr) * 32 + g8];
      bfr[f] = *(const bf16x8*)&Bs[(wn*64 + f*16 + fr) * 32 + g8];
    }
#pragma unroll
    for (int i = 0; i < 4; ++i)
#pragma unroll
      for (int j = 0; j < 4; ++j)
        acc[i][j] = __builtin_amdgcn_mfma_f32_16x16x32_bf16(af[i], bfr[j], acc[i][j], 0, 0, 0);
  }
  const int fr = lane & 15, q4 = (lane >> 4) * 4;
#pragma unroll
  for (int i = 0; i < 4; ++i) {
    const int obase = m0 + wm*64 + i*16 + q4;
#pragma unroll
    for (int q = 0; q < 4; ++q) {
      const int o = obase + q;
      const float inv = bng[o] * rsqrtf(bnv[o] + 1e-5f);
      const float sh  = (rb[o] - bnm[o]) * inv + bnb[o];
      float* orow = out + ((size_t)b * COUT + o) * LHW + n0 + wn*64 + fr;
#pragma unroll
      for (int j = 0; j < 4; ++j)
        orow[j*16] = fmaxf(fmaf(acc[i][j][q], inv, sh), 0.f);
    }
  }
}

// ---------------------------------------------------------------------------
extern "C" void kernel_launch(void* const* d_in, const int* in_sizes, int n_in,
                              void* d_out, int out_size, void* d_ws, size_t ws_size,
                              hipStream_t stream) {
  const float* x    = (const float*)d_in[0];
  const float* lw   = (const float*)d_in[1];
  const float* lb   = (const float*)d_in[2];
  const float* ipw  = (const float*)d_in[3];
  const float* cw   = (const float*)d_in[4];
  const float* cb   = (const float*)d_in[5];
  const float* xpw  = (const float*)d_in[6];
  const float* dtpw = (const float*)d_in[7];
  const float* dtpb = (const float*)d_in[8];
  const float* Alog = (const float*)d_in[9];
  const float* Dpar = (const float*)d_in[10];
  const float* opw  = (const float*)d_in[11];
  const float* rw   = (const float*)d_in[12];
  const float* rb   = (const float*)d_in[13];
  const float* bng  = (const float*)d_in[14];
  const float* bnb  = (const float*)d_in[15];
  const float* bnm  = (const float*)d_in[16];
  const float* bnv  = (const float*)d_in[17];
  float* out = (float*)d_out;

  float* ws = (float*)d_ws;
  unsigned short* ub   = (unsigned short*)ws;                      // 8.4M us
  unsigned short* xt   = (unsigned short*)(ws + 4194304);          // 16.8M us (reused: dtb, xrp)
  unsigned short* xm_b = (unsigned short*)(ws + 12582912);         // 16.8M us (reused as ydata)
  unsigned short* xc_b = (unsigned short*)(ws + 20971520);         // 16.8M us
  unsigned short* zsb  = (unsigned short*)(ws + 29360128);         // 16.8M us
  float* proj = ws + 46137344;                                     //  1.6M f
  float* PS   = ws + 47710208;                                     //  8.4M f
  float* hst  = ws + 56098816;                                     //  4.2M f
  unsigned short* wb = (unsigned short*)(ws + 60293120);           //  1.15M us
  unsigned short* lwb  = wb;
  unsigned short* ipwb = wb + WO1;
  unsigned short* xpwb = wb + WO2;
  unsigned short* opwb = wb + WO3;
  unsigned short* Aw   = wb + WO4;
  unsigned short* ydata = xm_b;
  unsigned short* dtb   = xt;   // xt dead after k_lat_mfma
  unsigned short* xrp   = xt;   // dtb dead after scanC; memset below is after scanC

  k_wprep<<<dim3(4480), 256, 0, stream>>>(lw, ipw, xpw, opw, rw, wb);
  k_xpose<<<dim3(64, 8, 8), 256, 0, stream>>>(x, xt);
  k_lat_mfma<<<dim3(2, 32, 8), 256, 0, stream>>>(xt, lwb, lb, ub);
  k_inproj_mfma<<<dim3(8, 32, 8), 256, 0, stream>>>(ub, ipwb, xm_b, zsb);
  k_conv1d<<<dim3(8192), 256, 0, stream>>>(xm_b, cw, cb, xc_b);
  k_xproj_mfma<<<dim3(32, 8), 256, 0, stream>>>(xc_b, xpwb, proj);
  k_dt<<<dim3(NB * LHW / 32), 512, 0, stream>>>(proj, dtpw, dtpb, dtb);
  k_scanA<<<dim3(NB * NCHK), 512, 0, stream>>>(proj, dtb, xc_b, Alog, PS);
  k_scanB<<<dim3(256), 256, 0, stream>>>(PS, hst);
  k_scanC<<<dim3(NB * NCHK), 512, 0, stream>>>(proj, dtb, xc_b, zsb, hst, Alog, Dpar, ydata);
  hipMemsetAsync(xrp, 0, (size_t)NB * PPOS * COUT * sizeof(unsigned short), stream);
  k_outproj_mfma<<<dim3(2, 32, 8), 256, 0, stream>>>(ydata, opwb, ub, xrp);
  k_refine_mfma<<<dim3(32, 2, 8), 256, 0, stream>>>(Aw, xrp, rb, bng, bnb, bnm, bnv, out);
}

// Round 6
// 409.686 us; speedup vs baseline: 12.8485x; 1.0052x over previous
//
#include <hip/hip_runtime.h>
#include <math.h>

#define NB   8
#define CIN  512
#define COUT 256
#define DIN  512
#define LHW  4096
#define NCHK 128
#define CHL  32
#define PW   66
#define PPOS (PW*PW)

typedef __attribute__((ext_vector_type(8))) short bf16x8;
typedef __attribute__((ext_vector_type(4))) float f32x4;

__device__ __forceinline__ float siluf(float v)  { return v / (1.f + __expf(-v)); }
// branch-free fast softplus: max(v,0) + log(1 + exp(-|v|))
__device__ __forceinline__ float splusf(float v) {
  return fmaxf(v, 0.f) + __logf(1.f + __expf(-fabsf(v)));
}

__device__ __forceinline__ unsigned short f2b(float f) {
  union { float f; unsigned u; } v; v.f = f;
  unsigned r = v.u + 0x7fff + ((v.u >> 16) & 1);
  return (unsigned short)(r >> 16);
}
__device__ __forceinline__ float b2f(unsigned int u) {
  union { unsigned u; float f; } v; v.u = (u & 0xffffu) << 16; return v.f;
}

__device__ __forceinline__ void gload16(const unsigned short* g, unsigned short* l) {
  __builtin_amdgcn_global_load_lds(
      (const __attribute__((address_space(1))) unsigned int*)g,
      (__attribute__((address_space(3))) unsigned int*)l, 16, 0, 0);
}

// ---------------------------------------------------------------------------
// W: weight prep — convert GEMM weights to bf16
// ---------------------------------------------------------------------------
#define WO1 131072
#define WO2 393216
#define WO3 425984
#define WO4 557056
__global__ __launch_bounds__(256)
void k_wprep(const float* __restrict__ lw, const float* __restrict__ ipw,
             const float* __restrict__ xpw, const float* __restrict__ opw,
             const float* __restrict__ rw, unsigned short* __restrict__ wb) {
  const int i = blockIdx.x * 256 + threadIdx.x;
  if (i < WO1)      wb[i] = f2b(lw[i]);
  else if (i < WO2) wb[i] = f2b(ipw[i - WO1]);
  else if (i < WO3) {
    const int j = i - WO2, row = j >> 9, col = j & 511;
    wb[i] = (row < 48) ? f2b(xpw[row * 512 + col]) : (unsigned short)0;
  }
  else if (i < WO4) wb[i] = f2b(opw[i - WO3]);
  else {
    const int j = i - WO4, o = j / 2304, kk = j % 2304;
    const int tap = kk >> 8, ch = kk & 255;
    wb[i] = f2b(rw[(o * 256 + ch) * 9 + tap]);
  }
}

// ---------------------------------------------------------------------------
// WF: fused dt/proj B-matrix, 640 rows x 512 (bf16):
//   rows 0..511  : W_fused[d][e] = sum_r dtpw[d][r] * xpw[r][e]
//   rows 512..559: xpw[row-512][e]   (proj cols)
//   rows 560..639: 0
// ---------------------------------------------------------------------------
__global__ __launch_bounds__(256)
void k_wfuse(const float* __restrict__ dtpw, const float* __restrict__ xpw,
             unsigned short* __restrict__ wfb) {
  const int tid = blockIdx.x * 256 + threadIdx.x;   // 640*512
  const int row = tid >> 9, e = tid & 511;
  float v = 0.f;
  if (row < 512) {
#pragma unroll
    for (int r = 0; r < 16; ++r)
      v = fmaf(dtpw[row * 16 + r], xpw[r * 512 + e], v);
  } else if (row < 560) {
    v = xpw[(row - 512) * 512 + e];
  }
  wfb[tid] = f2b(v);
}

// ---------------------------------------------------------------------------
// T: transpose x (b,k,l) f32 -> xt (b,l,k) bf16
// ---------------------------------------------------------------------------
__global__ __launch_bounds__(256)
void k_xpose(const float* __restrict__ x, unsigned short* __restrict__ xt) {
  __shared__ unsigned short Ts[64][80];
  const int b  = blockIdx.z;
  const int k0 = blockIdx.y * 64;
  const int l0 = blockIdx.x * 64;
  const int t  = threadIdx.x;
  const int tx = t & 15, ty = t >> 4;
#pragma unroll
  for (int r = 0; r < 4; ++r) {
    const int k = ty + r * 16;
    float4 v = *(const float4*)(x + ((size_t)b * CIN + k0 + k) * LHW + l0 + tx * 4);
    Ts[tx*4+0][k] = f2b(v.x);
    Ts[tx*4+1][k] = f2b(v.y);
    Ts[tx*4+2][k] = f2b(v.z);
    Ts[tx*4+3][k] = f2b(v.w);
  }
  __syncthreads();
  const int lr = t >> 2, kc = (t & 3) * 16;
  unsigned short* dst = xt + ((size_t)b * LHW + l0 + lr) * CIN + k0 + kc;
  *(uint4*)dst       = *(const uint4*)&Ts[lr][kc];
  *(uint4*)(dst + 8) = *(const uint4*)&Ts[lr][kc + 8];
}

// ---------------------------------------------------------------------------
// shared MFMA main loop: 128x128 tile, BK=32
// ---------------------------------------------------------------------------
template<int RSA, int RSB, int KTOT>
__device__ __forceinline__ void gemm_loop_128(
    const unsigned short* __restrict__ Ab, const unsigned short* __restrict__ Bb,
    unsigned short* As, unsigned short* Bs, int t, f32x4 acc[4][4]) {
  const int w = t >> 6, lane = t & 63;
  const int wm = w >> 1, wn = w & 1;
  const int arow = t >> 2, acol = (t & 3) * 8;
  const int fr = lane & 15, g8 = (lane >> 4) * 8;
  for (int k0 = 0; k0 < KTOT; k0 += 32) {
    __syncthreads();
    gload16(Ab + (size_t)arow * RSA + k0 + acol,        &As[w * 512]);
    gload16(Ab + (size_t)(64 + arow) * RSA + k0 + acol, &As[2048 + w * 512]);
    gload16(Bb + (size_t)arow * RSB + k0 + acol,        &Bs[w * 512]);
    gload16(Bb + (size_t)(64 + arow) * RSB + k0 + acol, &Bs[2048 + w * 512]);
    __syncthreads();
    bf16x8 af[4], bf[4];
#pragma unroll
    for (int f = 0; f < 4; ++f) {
      af[f] = *(const bf16x8*)&As[(wm*64 + f*16 + fr) * 32 + g8];
      bf[f] = *(const bf16x8*)&Bs[(wn*64 + f*16 + fr) * 32 + g8];
    }
#pragma unroll
    for (int i = 0; i < 4; ++i)
#pragma unroll
      for (int j = 0; j < 4; ++j)
        acc[i][j] = __builtin_amdgcn_mfma_f32_16x16x32_bf16(af[i], bf[j], acc[i][j], 0, 0, 0);
  }
}

// ---------------------------------------------------------------------------
// G1: lateral — ub[b][l][o] = bf16( sum_k xt[b][l][k]*lwb[o][k] + lb[o] )
// ---------------------------------------------------------------------------
__global__ __launch_bounds__(256)
void k_lat_mfma(const unsigned short* __restrict__ xt, const unsigned short* __restrict__ lwb,
                const float* __restrict__ lb, unsigned short* __restrict__ ub) {
  __shared__ __align__(16) unsigned short As[4096], Bs[4096];
  const int t = threadIdx.x, lane = t & 63, w = t >> 6;
  const int wm = w >> 1, wn = w & 1;
  const int b = blockIdx.z, m0 = blockIdx.y * 128, n0 = blockIdx.x * 128;
  f32x4 acc[4][4] = {};
  gemm_loop_128<512, 512, 512>(xt + ((size_t)b * LHW + m0) * 512,
                               lwb + (size_t)n0 * 512, As, Bs, t, acc);
  const int fr = lane & 15, q4 = (lane >> 4) * 4;
#pragma unroll
  for (int i = 0; i < 4; ++i) {
    const int l = m0 + wm*64 + i*16 + q4;
#pragma unroll
    for (int j = 0; j < 4; ++j) {
      const int o = n0 + wn*64 + j*16 + fr;
      const float bias = lb[o];
      unsigned short* dst = ub + ((size_t)b * LHW + l) * COUT + o;
#pragma unroll
      for (int q = 0; q < 4; ++q)
        dst[(size_t)q * COUT] = f2b(acc[i][j][q] + bias);
    }
  }
}

// ---------------------------------------------------------------------------
// G2: inproj — e<512 -> xm_b bf16 ; e>=512 -> silu -> zsb bf16
// ---------------------------------------------------------------------------
__global__ __launch_bounds__(256)
void k_inproj_mfma(const unsigned short* __restrict__ ub, const unsigned short* __restrict__ ipwb,
                   unsigned short* __restrict__ xm_b, unsigned short* __restrict__ zsb) {
  __shared__ __align__(16) unsigned short As[4096], Bs[4096];
  const int t = threadIdx.x, lane = t & 63, w = t >> 6;
  const int wm = w >> 1, wn = w & 1;
  const int b = blockIdx.z, m0 = blockIdx.y * 128, n0 = blockIdx.x * 128;
  f32x4 acc[4][4] = {};
  gemm_loop_128<256, 256, 256>(ub + ((size_t)b * LHW + m0) * 256,
                               ipwb + (size_t)n0 * 256, As, Bs, t, acc);
  const int fr = lane & 15, q4 = (lane >> 4) * 4;
  const bool isz = (n0 >= 512);
#pragma unroll
  for (int i = 0; i < 4; ++i) {
    const int l = m0 + wm*64 + i*16 + q4;
#pragma unroll
    for (int j = 0; j < 4; ++j) {
      const int e = n0 + wn*64 + j*16 + fr;
      if (isz) {
        unsigned short* dst = zsb + ((size_t)b * LHW + l) * DIN + (e - 512);
#pragma unroll
        for (int q = 0; q < 4; ++q)
          dst[(size_t)q * DIN] = f2b(siluf(acc[i][j][q]));
      } else {
        unsigned short* dst = xm_b + ((size_t)b * LHW + l) * DIN + e;
#pragma unroll
        for (int q = 0; q < 4; ++q)
          dst[(size_t)q * DIN] = f2b(acc[i][j][q]);
      }
    }
  }
}

// ---------------------------------------------------------------------------
// K3: depthwise causal conv1d + bias + silu, bf16 in/out, (b,l,e)
// ---------------------------------------------------------------------------
__global__ __launch_bounds__(256)
void k_conv1d(const unsigned short* __restrict__ xm_b, const float* __restrict__ cw,
              const float* __restrict__ cb, unsigned short* __restrict__ xc_b) {
  const int tid = blockIdx.x * 256 + threadIdx.x;
  const int e8 = tid & 63;
  const int l  = (tid >> 6) & 4095;
  const int b  = tid >> 18;
  const int e0 = e8 * 8;
  float acc[8];
  *(float4*)&acc[0] = *(const float4*)(cb + e0);
  *(float4*)&acc[4] = *(const float4*)(cb + e0 + 4);
  float wv[8][4];
#pragma unroll
  for (int q = 0; q < 8; ++q) {
    float4 w4 = *(const float4*)(cw + (e0 + q) * 4);
    wv[q][0] = w4.x; wv[q][1] = w4.y; wv[q][2] = w4.z; wv[q][3] = w4.w;
  }
  const unsigned short* base = xm_b + (size_t)b * LHW * DIN + e0;
#pragma unroll
  for (int k = 0; k < 4; ++k) {
    const int ll = l - 3 + k;
    if (ll >= 0) {
      uint4 raw = *(const uint4*)(base + (size_t)ll * DIN);
      acc[0] = fmaf(b2f(raw.x),       wv[0][k], acc[0]);
      acc[1] = fmaf(b2f(raw.x >> 16), wv[1][k], acc[1]);
      acc[2] = fmaf(b2f(raw.y),       wv[2][k], acc[2]);
      acc[3] = fmaf(b2f(raw.y >> 16), wv[3][k], acc[3]);
      acc[4] = fmaf(b2f(raw.z),       wv[4][k], acc[4]);
      acc[5] = fmaf(b2f(raw.z >> 16), wv[5][k], acc[5]);
      acc[6] = fmaf(b2f(raw.w),       wv[6][k], acc[6]);
      acc[7] = fmaf(b2f(raw.w >> 16), wv[7][k], acc[7]);
    }
  }
  uint4 o;
  o.x = (unsigned)f2b(siluf(acc[0])) | ((unsigned)f2b(siluf(acc[1])) << 16);
  o.y = (unsigned)f2b(siluf(acc[2])) | ((unsigned)f2b(siluf(acc[3])) << 16);
  o.z = (unsigned)f2b(siluf(acc[4])) | ((unsigned)f2b(siluf(acc[5])) << 16);
  o.w = (unsigned)f2b(siluf(acc[6])) | ((unsigned)f2b(siluf(acc[7])) << 16);
  *(uint4*)(xc_b + ((size_t)b * LHW + l) * DIN + e0) = o;
}

// ---------------------------------------------------------------------------
// G3: fused xproj+dt GEMM — cols 0..511 -> dt (softplus, bf16); 512..559 -> proj f32
// ---------------------------------------------------------------------------
__global__ __launch_bounds__(256)
void k_xdt_mfma(const unsigned short* __restrict__ xc_b, const unsigned short* __restrict__ wfb,
                const float* __restrict__ dtpb,
                unsigned short* __restrict__ dtb, float* __restrict__ proj) {
  __shared__ __align__(16) unsigned short As[4096], Bs[4096];
  const int t = threadIdx.x, lane = t & 63, w = t >> 6;
  const int wm = w >> 1, wn = w & 1;
  const int b = blockIdx.z, m0 = blockIdx.x * 128, n0 = blockIdx.y * 128;
  f32x4 acc[4][4] = {};
  gemm_loop_128<512, 512, 512>(xc_b + ((size_t)b * LHW + m0) * 512,
                               wfb + (size_t)n0 * 512, As, Bs, t, acc);
  const int fr = lane & 15, q4 = (lane >> 4) * 4;
#pragma unroll
  for (int i = 0; i < 4; ++i) {
    const int l = m0 + wm*64 + i*16 + q4;
#pragma unroll
    for (int j = 0; j < 4; ++j) {
      const int c = n0 + wn*64 + j*16 + fr;
      if (c < 512) {
        const float bias = dtpb[c];
        unsigned short* dst = dtb + ((size_t)b * LHW + l) * 512 + c;
#pragma unroll
        for (int q = 0; q < 4; ++q)
          dst[(size_t)q * 512] = f2b(splusf(acc[i][j][q] + bias));
      } else if (c < 560) {
        float* dst = proj + ((size_t)b * LHW + l) * 48 + (c - 512);
#pragma unroll
        for (int q = 0; q < 4; ++q)
          dst[(size_t)q * 48] = acc[i][j][q];
      }
    }
  }
}

// ---------------------------------------------------------------------------
// K5: scan phase A — per (b,chunk): P = exp(An·Σdt), S = local end state.
// ---------------------------------------------------------------------------
__global__ __launch_bounds__(512, 4)
void k_scanA(const float* __restrict__ proj, const unsigned short* __restrict__ dtb,
             const unsigned short* __restrict__ xc_b,
             const float* __restrict__ A_log, float* __restrict__ PS) {
  __shared__ float prs[CHL * 16];
  const int bx = blockIdx.x;
  const int b = bx >> 7, c = bx & 127;
  const int d = threadIdx.x;
  const size_t rbase = (size_t)b * LHW + c * CHL;
  for (int i = d; i < CHL * 4; i += 512) {
    const int row = i >> 2, c4 = i & 3;
    *(float4*)&prs[row * 16 + c4 * 4] = *(const float4*)(proj + (rbase + row) * 48 + 16 + c4 * 4);
  }
  float An[16], h[16];
#pragma unroll
  for (int q = 0; q < 4; ++q) {
    float4 a4 = *(const float4*)(A_log + d*16 + q*4);
    An[q*4+0] = -__expf(a4.x); An[q*4+1] = -__expf(a4.y);
    An[q*4+2] = -__expf(a4.z); An[q*4+3] = -__expf(a4.w);
  }
#pragma unroll
  for (int n = 0; n < 16; ++n) h[n] = 0.f;
  const float An0 = An[0];
  bool lin = true;
#pragma unroll
  for (int n = 1; n < 16; ++n)
    lin = lin && (fabsf(An[n] - (n + 1) * An0) <= 1e-4f * fabsf(An[n]));
  float sdt = 0.f;
  const unsigned short* dt0 = dtb + rbase * 512 + d;
  const unsigned short* xc0 = xc_b + rbase * DIN + d;
  __syncthreads();
  for (int i = 0; i < CHL; ++i) {
    const float dt = b2f(dt0[(size_t)i * 512]);
    sdt += dt;
    const float dtx = dt * b2f(xc0[(size_t)i * DIN]);
    float dA[16];
    if (lin) {
      const float e1 = __expf(dt * An0);
      const float e2 = e1 * e1, e3 = e2 * e1, e4 = e2 * e2;
      dA[0] = e1; dA[1] = e2; dA[2] = e3; dA[3] = e4;
#pragma unroll
      for (int n = 4; n < 16; ++n) dA[n] = dA[n-4] * e4;
    } else {
#pragma unroll
      for (int n = 0; n < 16; ++n) dA[n] = __expf(dt * An[n]);
    }
    const float* pr = &prs[i * 16];
#pragma unroll
    for (int q = 0; q < 4; ++q) {
      float4 B4 = *(const float4*)(pr + q*4);
      h[q*4+0] = fmaf(dA[q*4+0], h[q*4+0], dtx * B4.x);
      h[q*4+1] = fmaf(dA[q*4+1], h[q*4+1], dtx * B4.y);
      h[q*4+2] = fmaf(dA[q*4+2], h[q*4+2], dtx * B4.z);
      h[q*4+3] = fmaf(dA[q*4+3], h[q*4+3], dtx * B4.w);
    }
  }
  float* o = PS + ((size_t)bx * 512 + d) * 32;
#pragma unroll
  for (int q = 0; q < 4; ++q)
    *(float4*)(o + q*4) = make_float4(__expf(sdt*An[q*4+0]), __expf(sdt*An[q*4+1]),
                                      __expf(sdt*An[q*4+2]), __expf(sdt*An[q*4+3]));
#pragma unroll
  for (int q = 0; q < 4; ++q)
    *(float4*)(o + 16 + q*4) = make_float4(h[q*4], h[q*4+1], h[q*4+2], h[q*4+3]);
}

// ---------------------------------------------------------------------------
// K6: scan phase B — combine chunk summaries, store chunk-entry states
// ---------------------------------------------------------------------------
__global__ __launch_bounds__(256)
void k_scanB(const float* __restrict__ PS, float* __restrict__ hst) {
  const int tid = blockIdx.x * 256 + threadIdx.x;
  const int n = tid & 15;
  const int d = (tid >> 4) & 511;
  const int b = tid >> 13;
  float h = 0.f;
  for (int c = 0; c < NCHK; ++c) {
    const size_t idx = (size_t)((b*NCHK + c)*512 + d);
    hst[idx*16 + n] = h;
    h = PS[idx*32 + n] * h + PS[idx*32 + 16 + n];
  }
}

// ---------------------------------------------------------------------------
// K7: scan phase C — rescan from entry state; B,C staged in LDS; dt from dtb
// ---------------------------------------------------------------------------
__global__ __launch_bounds__(512, 4)
void k_scanC(const float* __restrict__ proj, const unsigned short* __restrict__ dtb,
             const unsigned short* __restrict__ xc_b,
             const unsigned short* __restrict__ zsb, const float* __restrict__ hst,
             const float* __restrict__ A_log, const float* __restrict__ Dpar,
             unsigned short* __restrict__ ydata) {
  __shared__ float prs[CHL * 32];
  const int bx = blockIdx.x;
  const int b = bx >> 7, c = bx & 127;
  const int d = threadIdx.x;
  const size_t rbase = (size_t)b * LHW + c * CHL;
  for (int i = d; i < CHL * 8; i += 512) {
    const int row = i >> 3, c4 = i & 7;
    *(float4*)&prs[row * 32 + c4 * 4] = *(const float4*)(proj + (rbase + row) * 48 + 16 + c4 * 4);
  }
  float An[16], h[16];
#pragma unroll
  for (int q = 0; q < 4; ++q) {
    float4 a4 = *(const float4*)(A_log + d*16 + q*4);
    An[q*4+0] = -__expf(a4.x); An[q*4+1] = -__expf(a4.y);
    An[q*4+2] = -__expf(a4.z); An[q*4+3] = -__expf(a4.w);
  }
#pragma unroll
  for (int q = 0; q < 4; ++q) {
    float4 h4 = *(const float4*)(hst + ((size_t)bx * 512 + d) * 16 + q*4);
    h[q*4+0] = h4.x; h[q*4+1] = h4.y; h[q*4+2] = h4.z; h[q*4+3] = h4.w;
  }
  const float An0 = An[0];
  bool lin = true;
#pragma unroll
  for (int n = 1; n < 16; ++n)
    lin = lin && (fabsf(An[n] - (n + 1) * An0) <= 1e-4f * fabsf(An[n]));
  const float dp = Dpar[d];
  const unsigned short* dt0 = dtb + rbase * 512 + d;
  const unsigned short* xc0 = xc_b + rbase * DIN + d;
  const unsigned short* zs0 = zsb + rbase * DIN + d;
  unsigned short* y0 = ydata + rbase * DIN + d;
  __syncthreads();
  for (int i = 0; i < CHL; ++i) {
    const float dt = b2f(dt0[(size_t)i * 512]);
    const float xt = b2f(xc0[(size_t)i * DIN]);
    const float zv = b2f(zs0[(size_t)i * DIN]);
    const float dtx = dt * xt;
    float dA[16];
    if (lin) {
      const float e1 = __expf(dt * An0);
      const float e2 = e1 * e1, e3 = e2 * e1, e4 = e2 * e2;
      dA[0] = e1; dA[1] = e2; dA[2] = e3; dA[3] = e4;
#pragma unroll
      for (int n = 4; n < 16; ++n) dA[n] = dA[n-4] * e4;
    } else {
#pragma unroll
      for (int n = 0; n < 16; ++n) dA[n] = __expf(dt * An[n]);
    }
    const float* pr = &prs[i * 32];
    float y0a = 0.f, y1a = 0.f, y2a = 0.f, y3a = 0.f;
#pragma unroll
    for (int q = 0; q < 4; ++q) {
      float4 B4 = *(const float4*)(pr + q*4);
      float4 C4 = *(const float4*)(pr + 16 + q*4);
      h[q*4+0] = fmaf(dA[q*4+0], h[q*4+0], dtx * B4.x);
      h[q*4+1] = fmaf(dA[q*4+1], h[q*4+1], dtx * B4.y);
      h[q*4+2] = fmaf(dA[q*4+2], h[q*4+2], dtx * B4.z);
      h[q*4+3] = fmaf(dA[q*4+3], h[q*4+3], dtx * B4.w);
      y0a = fmaf(h[q*4+0], C4.x, y0a);
      y1a = fmaf(h[q*4+1], C4.y, y1a);
      y2a = fmaf(h[q*4+2], C4.z, y2a);
      y3a = fmaf(h[q*4+3], C4.w, y3a);
    }
    const float y = (y0a + y1a) + (y2a + y3a);
    y0[(size_t)i * DIN] = f2b((y + xt * dp) * zv);
  }
}

// ---------------------------------------------------------------------------
// G4: outproj + residual(ub) -> padded channel-last bf16 xrp
// ---------------------------------------------------------------------------
__global__ __launch_bounds__(256)
void k_outproj_mfma(const unsigned short* __restrict__ ydata, const unsigned short* __restrict__ opwb,
                    const unsigned short* __restrict__ ub, unsigned short* __restrict__ xrp) {
  __shared__ __align__(16) unsigned short As[4096], Bs[4096];
  const int t = threadIdx.x, lane = t & 63, w = t >> 6;
  const int wm = w >> 1, wn = w & 1;
  const int b = blockIdx.z, m0 = blockIdx.y * 128, n0 = blockIdx.x * 128;
  f32x4 acc[4][4] = {};
  gemm_loop_128<512, 512, 512>(ydata + ((size_t)b * LHW + m0) * 512,
                               opwb + (size_t)n0 * 512, As, Bs, t, acc);
  const int fr = lane & 15, q4 = (lane >> 4) * 4;
#pragma unroll
  for (int i = 0; i < 4; ++i) {
    const int lbase = m0 + wm*64 + i*16 + q4;
#pragma unroll
    for (int q = 0; q < 4; ++q) {
      const int l = lbase + q;
      const int pos = ((l >> 6) + 1) * PW + (l & 63) + 1;
#pragma unroll
      for (int j = 0; j < 4; ++j) {
        const int o = n0 + wn*64 + j*16 + fr;
        const float r = b2f(ub[((size_t)b * LHW + l) * COUT + o]);
        xrp[((size_t)b * PPOS + pos) * COUT + o] = f2b(acc[i][j][q] + r);
      }
    }
  }
}

// ---------------------------------------------------------------------------
// G5: refine 3x3 conv as MFMA implicit GEMM + BN + ReLU
// ---------------------------------------------------------------------------
__global__ __launch_bounds__(256)
void k_refine_mfma(const unsigned short* __restrict__ Aw,
                   const unsigned short* __restrict__ xrp,
                   const float* __restrict__ rb, const float* __restrict__ bng,
                   const float* __restrict__ bnb, const float* __restrict__ bnm,
                   const float* __restrict__ bnv, float* __restrict__ out) {
  __shared__ __align__(16) unsigned short As[4096], Bs[4096];
  const int t = threadIdx.x;
  const int lane = t & 63;
  const int w = t >> 6;
  const int wm = w >> 1, wn = w & 1;
  const int b  = blockIdx.z;
  const int m0 = blockIdx.y * 128;
  const int n0 = blockIdx.x * 128;
  const int y0 = n0 >> 6;
  const unsigned short* xb = xrp + (size_t)b * PPOS * COUT;
  const int arow = t >> 2;
  const int acol = (t & 3) * 8;
  f32x4 acc[4][4] = {};
  for (int ks = 0; ks < 72; ++ks) {
    const int tap = ks >> 3;
    const int i0  = (ks & 7) * 32;
    const int ky  = tap / 3, kx = tap - ky * 3;
    const int k0  = tap * 256 + i0;
    const unsigned short* ga0 = Aw + (size_t)(m0 + arow) * 2304 + k0 + acol;
    const unsigned short* gb0 = xb + ((size_t)((y0 + ky) * PW + kx + arow)) * COUT + i0 + acol;
    __syncthreads();
    gload16(ga0,              &As[w * 512]);
    gload16(ga0 + 64 * 2304,  &As[2048 + w * 512]);
    gload16(gb0,              &Bs[w * 512]);
    gload16(gb0 + PW * COUT,  &Bs[2048 + w * 512]);
    __syncthreads();
    const int fr = lane & 15, g8 = (lane >> 4) * 8;
    bf16x8 af[4], bfr[4];
#pragma unroll
    for (int f = 0; f < 4; ++f) {
      af[f]  = *(const bf16x8*)&As[(wm*64 + f*16 + fr) * 32 + g8];
      bfr[f] = *(const bf16x8*)&Bs[(wn*64 + f*16 + fr) * 32 + g8];
    }
#pragma unroll
    for (int i = 0; i < 4; ++i)
#pragma unroll
      for (int j = 0; j < 4; ++j)
        acc[i][j] = __builtin_amdgcn_mfma_f32_16x16x32_bf16(af[i], bfr[j], acc[i][j], 0, 0, 0);
  }
  const int fr = lane & 15, q4 = (lane >> 4) * 4;
#pragma unroll
  for (int i = 0; i < 4; ++i) {
    const int obase = m0 + wm*64 + i*16 + q4;
#pragma unroll
    for (int q = 0; q < 4; ++q) {
      const int o = obase + q;
      const float inv = bng[o] * rsqrtf(bnv[o] + 1e-5f);
      const float sh  = (rb[o] - bnm[o]) * inv + bnb[o];
      float* orow = out + ((size_t)b * COUT + o) * LHW + n0 + wn*64 + fr;
#pragma unroll
      for (int j = 0; j < 4; ++j)
        orow[j*16] = fmaxf(fmaf(acc[i][j][q], inv, sh), 0.f);
    }
  }
}

// ---------------------------------------------------------------------------
extern "C" void kernel_launch(void* const* d_in, const int* in_sizes, int n_in,
                              void* d_out, int out_size, void* d_ws, size_t ws_size,
                              hipStream_t stream) {
  const float* x    = (const float*)d_in[0];
  const float* lw   = (const float*)d_in[1];
  const float* lb   = (const float*)d_in[2];
  const float* ipw  = (const float*)d_in[3];
  const float* cw   = (const float*)d_in[4];
  const float* cb   = (const float*)d_in[5];
  const float* xpw  = (const float*)d_in[6];
  const float* dtpw = (const float*)d_in[7];
  const float* dtpb = (const float*)d_in[8];
  const float* Alog = (const float*)d_in[9];
  const float* Dpar = (const float*)d_in[10];
  const float* opw  = (const float*)d_in[11];
  const float* rw   = (const float*)d_in[12];
  const float* rb   = (const float*)d_in[13];
  const float* bng  = (const float*)d_in[14];
  const float* bnb  = (const float*)d_in[15];
  const float* bnm  = (const float*)d_in[16];
  const float* bnv  = (const float*)d_in[17];
  float* out = (float*)d_out;

  float* ws = (float*)d_ws;
  unsigned short* ub   = (unsigned short*)ws;                      // 8.4M us
  unsigned short* xt   = (unsigned short*)(ws + 4194304);          // 16.8M us (reused: dtb, xrp)
  unsigned short* xm_b = (unsigned short*)(ws + 12582912);         // 16.8M us (reused as ydata)
  unsigned short* xc_b = (unsigned short*)(ws + 20971520);         // 16.8M us
  unsigned short* zsb  = (unsigned short*)(ws + 29360128);         // 16.8M us
  float* proj = ws + 37748736;                                     //  1.57M f
  float* PS   = ws + 39321600;                                     // 16.8M f (NB*NCHK*512*32)
  float* hst  = ws + 56098816;                                     //  8.4M f (NB*NCHK*512*16)
  unsigned short* wb  = (unsigned short*)(ws + 64487424);          //  1.15M us
  unsigned short* wfb = (unsigned short*)(ws + 65060864);          //  0.33M us (640x512)
  unsigned short* lwb  = wb;
  unsigned short* ipwb = wb + WO1;
  unsigned short* opwb = wb + WO3;
  unsigned short* Aw   = wb + WO4;
  unsigned short* ydata = xm_b;
  unsigned short* dtb   = xt;   // xt dead after k_lat_mfma
  unsigned short* xrp   = xt;   // dtb dead after scanC; memset is after scanC

  k_wprep<<<dim3(4480), 256, 0, stream>>>(lw, ipw, xpw, opw, rw, wb);
  k_wfuse<<<dim3(1280), 256, 0, stream>>>(dtpw, xpw, wfb);
  k_xpose<<<dim3(64, 8, 8), 256, 0, stream>>>(x, xt);
  k_lat_mfma<<<dim3(2, 32, 8), 256, 0, stream>>>(xt, lwb, lb, ub);
  k_inproj_mfma<<<dim3(8, 32, 8), 256, 0, stream>>>(ub, ipwb, xm_b, zsb);
  k_conv1d<<<dim3(8192), 256, 0, stream>>>(xm_b, cw, cb, xc_b);
  k_xdt_mfma<<<dim3(32, 5, 8), 256, 0, stream>>>(xc_b, wfb, dtpb, dtb, proj);
  k_scanA<<<dim3(NB * NCHK), 512, 0, stream>>>(proj, dtb, xc_b, Alog, PS);
  k_scanB<<<dim3(256), 256, 0, stream>>>(PS, hst);
  k_scanC<<<dim3(NB * NCHK), 512, 0, stream>>>(proj, dtb, xc_b, zsb, hst, Alog, Dpar, ydata);
  hipMemsetAsync(xrp, 0, (size_t)NB * PPOS * COUT * sizeof(unsigned short), stream);
  k_outproj_mfma<<<dim3(2, 32, 8), 256, 0, stream>>>(ydata, opwb, ub, xrp);
  k_refine_mfma<<<dim3(32, 2, 8), 256, 0, stream>>>(Aw, xrp, rb, bng, bnb, bnm, bnv, out);
}

// Round 7
// 372.268 us; speedup vs baseline: 14.1399x; 1.1005x over previous
//
#include <hip/hip_runtime.h>
#include <math.h>

#define NB   8
#define CIN  512
#define COUT 256
#define DIN  512
#define LHW  4096
#define NCHK 128
#define CHL  32
#define PW   66
#define PPOS (PW*PW)

typedef __attribute__((ext_vector_type(8))) short bf16x8;
typedef __attribute__((ext_vector_type(4))) float f32x4;

__device__ __forceinline__ float siluf(float v)  { return v / (1.f + __expf(-v)); }
// branch-free fast softplus: max(v,0) + log(1 + exp(-|v|))
__device__ __forceinline__ float splusf(float v) {
  return fmaxf(v, 0.f) + __logf(1.f + __expf(-fabsf(v)));
}

__device__ __forceinline__ unsigned short f2b(float f) {
  union { float f; unsigned u; } v; v.f = f;
  unsigned r = v.u + 0x7fff + ((v.u >> 16) & 1);
  return (unsigned short)(r >> 16);
}
__device__ __forceinline__ float b2f(unsigned int u) {
  union { unsigned u; float f; } v; v.u = (u & 0xffffu) << 16; return v.f;
}

__device__ __forceinline__ void gload16(const unsigned short* g, unsigned short* l) {
  __builtin_amdgcn_global_load_lds(
      (const __attribute__((address_space(1))) unsigned int*)g,
      (__attribute__((address_space(3))) unsigned int*)l, 16, 0, 0);
}

// ---------------------------------------------------------------------------
// W: weight prep — convert GEMM weights to bf16
// ---------------------------------------------------------------------------
#define WO1 131072
#define WO2 393216
#define WO3 425984
#define WO4 557056
__global__ __launch_bounds__(256)
void k_wprep(const float* __restrict__ lw, const float* __restrict__ ipw,
             const float* __restrict__ xpw, const float* __restrict__ opw,
             const float* __restrict__ rw, unsigned short* __restrict__ wb) {
  const int i = blockIdx.x * 256 + threadIdx.x;
  if (i < WO1)      wb[i] = f2b(lw[i]);
  else if (i < WO2) wb[i] = f2b(ipw[i - WO1]);
  else if (i < WO3) {
    const int j = i - WO2, row = j >> 9, col = j & 511;
    wb[i] = (row < 48) ? f2b(xpw[row * 512 + col]) : (unsigned short)0;
  }
  else if (i < WO4) wb[i] = f2b(opw[i - WO3]);
  else {
    const int j = i - WO4, o = j / 2304, kk = j % 2304;
    const int tap = kk >> 8, ch = kk & 255;
    wb[i] = f2b(rw[(o * 256 + ch) * 9 + tap]);
  }
}

// ---------------------------------------------------------------------------
// WF: fused dt/proj B-matrix, 640 rows x 512 (bf16)
// ---------------------------------------------------------------------------
__global__ __launch_bounds__(256)
void k_wfuse(const float* __restrict__ dtpw, const float* __restrict__ xpw,
             unsigned short* __restrict__ wfb) {
  const int tid = blockIdx.x * 256 + threadIdx.x;   // 640*512
  const int row = tid >> 9, e = tid & 511;
  float v = 0.f;
  if (row < 512) {
#pragma unroll
    for (int r = 0; r < 16; ++r)
      v = fmaf(dtpw[row * 16 + r], xpw[r * 512 + e], v);
  } else if (row < 560) {
    v = xpw[(row - 512) * 512 + e];
  }
  wfb[tid] = f2b(v);
}

// ---------------------------------------------------------------------------
// T: transpose x (b,k,l) f32 -> xt (b,l,k) bf16
// ---------------------------------------------------------------------------
__global__ __launch_bounds__(256)
void k_xpose(const float* __restrict__ x, unsigned short* __restrict__ xt) {
  __shared__ unsigned short Ts[64][80];
  const int b  = blockIdx.z;
  const int k0 = blockIdx.y * 64;
  const int l0 = blockIdx.x * 64;
  const int t  = threadIdx.x;
  const int tx = t & 15, ty = t >> 4;
#pragma unroll
  for (int r = 0; r < 4; ++r) {
    const int k = ty + r * 16;
    float4 v = *(const float4*)(x + ((size_t)b * CIN + k0 + k) * LHW + l0 + tx * 4);
    Ts[tx*4+0][k] = f2b(v.x);
    Ts[tx*4+1][k] = f2b(v.y);
    Ts[tx*4+2][k] = f2b(v.z);
    Ts[tx*4+3][k] = f2b(v.w);
  }
  __syncthreads();
  const int lr = t >> 2, kc = (t & 3) * 16;
  unsigned short* dst = xt + ((size_t)b * LHW + l0 + lr) * CIN + k0 + kc;
  *(uint4*)dst       = *(const uint4*)&Ts[lr][kc];
  *(uint4*)(dst + 8) = *(const uint4*)&Ts[lr][kc + 8];
}

// ---------------------------------------------------------------------------
// shared MFMA main loop: 128x128 tile, BK=32
// ---------------------------------------------------------------------------
template<int RSA, int RSB, int KTOT>
__device__ __forceinline__ void gemm_loop_128(
    const unsigned short* __restrict__ Ab, const unsigned short* __restrict__ Bb,
    unsigned short* As, unsigned short* Bs, int t, f32x4 acc[4][4]) {
  const int w = t >> 6, lane = t & 63;
  const int wm = w >> 1, wn = w & 1;
  const int arow = t >> 2, acol = (t & 3) * 8;
  const int fr = lane & 15, g8 = (lane >> 4) * 8;
  for (int k0 = 0; k0 < KTOT; k0 += 32) {
    __syncthreads();
    gload16(Ab + (size_t)arow * RSA + k0 + acol,        &As[w * 512]);
    gload16(Ab + (size_t)(64 + arow) * RSA + k0 + acol, &As[2048 + w * 512]);
    gload16(Bb + (size_t)arow * RSB + k0 + acol,        &Bs[w * 512]);
    gload16(Bb + (size_t)(64 + arow) * RSB + k0 + acol, &Bs[2048 + w * 512]);
    __syncthreads();
    bf16x8 af[4], bf[4];
#pragma unroll
    for (int f = 0; f < 4; ++f) {
      af[f] = *(const bf16x8*)&As[(wm*64 + f*16 + fr) * 32 + g8];
      bf[f] = *(const bf16x8*)&Bs[(wn*64 + f*16 + fr) * 32 + g8];
    }
#pragma unroll
    for (int i = 0; i < 4; ++i)
#pragma unroll
      for (int j = 0; j < 4; ++j)
        acc[i][j] = __builtin_amdgcn_mfma_f32_16x16x32_bf16(af[i], bf[j], acc[i][j], 0, 0, 0);
  }
}

// ---------------------------------------------------------------------------
// G1: lateral — ub[b][l][o] = bf16( sum_k xt[b][l][k]*lwb[o][k] + lb[o] )
// ---------------------------------------------------------------------------
__global__ __launch_bounds__(256)
void k_lat_mfma(const unsigned short* __restrict__ xt, const unsigned short* __restrict__ lwb,
                const float* __restrict__ lb, unsigned short* __restrict__ ub) {
  __shared__ __align__(16) unsigned short As[4096], Bs[4096];
  const int t = threadIdx.x, lane = t & 63, w = t >> 6;
  const int wm = w >> 1, wn = w & 1;
  const int b = blockIdx.z, m0 = blockIdx.y * 128, n0 = blockIdx.x * 128;
  f32x4 acc[4][4] = {};
  gemm_loop_128<512, 512, 512>(xt + ((size_t)b * LHW + m0) * 512,
                               lwb + (size_t)n0 * 512, As, Bs, t, acc);
  const int fr = lane & 15, q4 = (lane >> 4) * 4;
#pragma unroll
  for (int i = 0; i < 4; ++i) {
    const int l = m0 + wm*64 + i*16 + q4;
#pragma unroll
    for (int j = 0; j < 4; ++j) {
      const int o = n0 + wn*64 + j*16 + fr;
      const float bias = lb[o];
      unsigned short* dst = ub + ((size_t)b * LHW + l) * COUT + o;
#pragma unroll
      for (int q = 0; q < 4; ++q)
        dst[(size_t)q * COUT] = f2b(acc[i][j][q] + bias);
    }
  }
}

// ---------------------------------------------------------------------------
// G2: inproj — e<512 -> xm_b bf16 ; e>=512 -> silu -> zsb bf16
// ---------------------------------------------------------------------------
__global__ __launch_bounds__(256)
void k_inproj_mfma(const unsigned short* __restrict__ ub, const unsigned short* __restrict__ ipwb,
                   unsigned short* __restrict__ xm_b, unsigned short* __restrict__ zsb) {
  __shared__ __align__(16) unsigned short As[4096], Bs[4096];
  const int t = threadIdx.x, lane = t & 63, w = t >> 6;
  const int wm = w >> 1, wn = w & 1;
  const int b = blockIdx.z, m0 = blockIdx.y * 128, n0 = blockIdx.x * 128;
  f32x4 acc[4][4] = {};
  gemm_loop_128<256, 256, 256>(ub + ((size_t)b * LHW + m0) * 256,
                               ipwb + (size_t)n0 * 256, As, Bs, t, acc);
  const int fr = lane & 15, q4 = (lane >> 4) * 4;
  const bool isz = (n0 >= 512);
#pragma unroll
  for (int i = 0; i < 4; ++i) {
    const int l = m0 + wm*64 + i*16 + q4;
#pragma unroll
    for (int j = 0; j < 4; ++j) {
      const int e = n0 + wn*64 + j*16 + fr;
      if (isz) {
        unsigned short* dst = zsb + ((size_t)b * LHW + l) * DIN + (e - 512);
#pragma unroll
        for (int q = 0; q < 4; ++q)
          dst[(size_t)q * DIN] = f2b(siluf(acc[i][j][q]));
      } else {
        unsigned short* dst = xm_b + ((size_t)b * LHW + l) * DIN + e;
#pragma unroll
        for (int q = 0; q < 4; ++q)
          dst[(size_t)q * DIN] = f2b(acc[i][j][q]);
      }
    }
  }
}

// ---------------------------------------------------------------------------
// K3: depthwise causal conv1d + bias + silu, bf16 in/out, (b,l,e)
// 4 consecutive l per thread: 7 row-loads -> 4 outputs (register rolling window)
// ---------------------------------------------------------------------------
__global__ __launch_bounds__(256)
void k_conv1d(const unsigned short* __restrict__ xm_b, const float* __restrict__ cw,
              const float* __restrict__ cb, unsigned short* __restrict__ xc_b) {
  const int tid = blockIdx.x * 256 + threadIdx.x;   // NB*(LHW/4)*64
  const int e8 = tid & 63;
  const int lg = tid >> 6;                           // 0..8191
  const int l0 = (lg & 1023) * 4;
  const int b  = lg >> 10;
  const int e0 = e8 * 8;
  float bias[8];
  *(float4*)&bias[0] = *(const float4*)(cb + e0);
  *(float4*)&bias[4] = *(const float4*)(cb + e0 + 4);
  float wv[8][4];
#pragma unroll
  for (int q = 0; q < 8; ++q) {
    float4 w4 = *(const float4*)(cw + (e0 + q) * 4);
    wv[q][0] = w4.x; wv[q][1] = w4.y; wv[q][2] = w4.z; wv[q][3] = w4.w;
  }
  const unsigned short* base = xm_b + ((size_t)b * LHW + l0) * DIN + e0;
  uint4 rows[7];
  const uint4 z4 = make_uint4(0u, 0u, 0u, 0u);
#pragma unroll
  for (int r = 0; r < 7; ++r) {
    const int ll = r - 3;
    rows[r] = (l0 + ll >= 0) ? *(const uint4*)(base + (ptrdiff_t)ll * DIN) : z4;
  }
  unsigned short* outb = xc_b + ((size_t)b * LHW + l0) * DIN + e0;
#pragma unroll
  for (int j = 0; j < 4; ++j) {
    float acc[8];
#pragma unroll
    for (int q = 0; q < 8; ++q) acc[q] = bias[q];
#pragma unroll
    for (int k = 0; k < 4; ++k) {
      const uint4 raw = rows[j + k];
      acc[0] = fmaf(b2f(raw.x),       wv[0][k], acc[0]);
      acc[1] = fmaf(b2f(raw.x >> 16), wv[1][k], acc[1]);
      acc[2] = fmaf(b2f(raw.y),       wv[2][k], acc[2]);
      acc[3] = fmaf(b2f(raw.y >> 16), wv[3][k], acc[3]);
      acc[4] = fmaf(b2f(raw.z),       wv[4][k], acc[4]);
      acc[5] = fmaf(b2f(raw.z >> 16), wv[5][k], acc[5]);
      acc[6] = fmaf(b2f(raw.w),       wv[6][k], acc[6]);
      acc[7] = fmaf(b2f(raw.w >> 16), wv[7][k], acc[7]);
    }
    uint4 o;
    o.x = (unsigned)f2b(siluf(acc[0])) | ((unsigned)f2b(siluf(acc[1])) << 16);
    o.y = (unsigned)f2b(siluf(acc[2])) | ((unsigned)f2b(siluf(acc[3])) << 16);
    o.z = (unsigned)f2b(siluf(acc[4])) | ((unsigned)f2b(siluf(acc[5])) << 16);
    o.w = (unsigned)f2b(siluf(acc[6])) | ((unsigned)f2b(siluf(acc[7])) << 16);
    *(uint4*)(outb + (size_t)j * DIN) = o;
  }
}

// ---------------------------------------------------------------------------
// G3: fused xproj+dt GEMM — cols 0..511 -> dt (softplus, bf16); 512..559 -> proj f32
// ---------------------------------------------------------------------------
__global__ __launch_bounds__(256)
void k_xdt_mfma(const unsigned short* __restrict__ xc_b, const unsigned short* __restrict__ wfb,
                const float* __restrict__ dtpb,
                unsigned short* __restrict__ dtb, float* __restrict__ proj) {
  __shared__ __align__(16) unsigned short As[4096], Bs[4096];
  const int t = threadIdx.x, lane = t & 63, w = t >> 6;
  const int wm = w >> 1, wn = w & 1;
  const int b = blockIdx.z, m0 = blockIdx.x * 128, n0 = blockIdx.y * 128;
  f32x4 acc[4][4] = {};
  gemm_loop_128<512, 512, 512>(xc_b + ((size_t)b * LHW + m0) * 512,
                               wfb + (size_t)n0 * 512, As, Bs, t, acc);
  const int fr = lane & 15, q4 = (lane >> 4) * 4;
#pragma unroll
  for (int i = 0; i < 4; ++i) {
    const int l = m0 + wm*64 + i*16 + q4;
#pragma unroll
    for (int j = 0; j < 4; ++j) {
      const int c = n0 + wn*64 + j*16 + fr;
      if (c < 512) {
        const float bias = dtpb[c];
        unsigned short* dst = dtb + ((size_t)b * LHW + l) * 512 + c;
#pragma unroll
        for (int q = 0; q < 4; ++q)
          dst[(size_t)q * 512] = f2b(splusf(acc[i][j][q] + bias));
      } else if (c < 560) {
        float* dst = proj + ((size_t)b * LHW + l) * 48 + (c - 512);
#pragma unroll
        for (int q = 0; q < 4; ++q)
          dst[(size_t)q * 48] = acc[i][j][q];
      }
    }
  }
}

// ---------------------------------------------------------------------------
// K5: scan phase A — per (b,chunk): P = exp(An·Σdt), S = local end state.
// ---------------------------------------------------------------------------
__global__ __launch_bounds__(512, 4)
void k_scanA(const float* __restrict__ proj, const unsigned short* __restrict__ dtb,
             const unsigned short* __restrict__ xc_b,
             const float* __restrict__ A_log, float* __restrict__ PS) {
  __shared__ float prs[CHL * 16];
  const int bx = blockIdx.x;
  const int b = bx >> 7, c = bx & 127;
  const int d = threadIdx.x;
  const size_t rbase = (size_t)b * LHW + c * CHL;
  for (int i = d; i < CHL * 4; i += 512) {
    const int row = i >> 2, c4 = i & 3;
    *(float4*)&prs[row * 16 + c4 * 4] = *(const float4*)(proj + (rbase + row) * 48 + 16 + c4 * 4);
  }
  float An[16], h[16];
#pragma unroll
  for (int q = 0; q < 4; ++q) {
    float4 a4 = *(const float4*)(A_log + d*16 + q*4);
    An[q*4+0] = -__expf(a4.x); An[q*4+1] = -__expf(a4.y);
    An[q*4+2] = -__expf(a4.z); An[q*4+3] = -__expf(a4.w);
  }
#pragma unroll
  for (int n = 0; n < 16; ++n) h[n] = 0.f;
  const float An0 = An[0];
  bool lin = true;
#pragma unroll
  for (int n = 1; n < 16; ++n)
    lin = lin && (fabsf(An[n] - (n + 1) * An0) <= 1e-4f * fabsf(An[n]));
  float sdt = 0.f;
  const unsigned short* dt0 = dtb + rbase * 512 + d;
  const unsigned short* xc0 = xc_b + rbase * DIN + d;
  __syncthreads();
  for (int i = 0; i < CHL; ++i) {
    const float dt = b2f(dt0[(size_t)i * 512]);
    sdt += dt;
    const float dtx = dt * b2f(xc0[(size_t)i * DIN]);
    float dA[16];
    if (lin) {
      const float e1 = __expf(dt * An0);
      const float e2 = e1 * e1, e3 = e2 * e1, e4 = e2 * e2;
      dA[0] = e1; dA[1] = e2; dA[2] = e3; dA[3] = e4;
#pragma unroll
      for (int n = 4; n < 16; ++n) dA[n] = dA[n-4] * e4;
    } else {
#pragma unroll
      for (int n = 0; n < 16; ++n) dA[n] = __expf(dt * An[n]);
    }
    const float* pr = &prs[i * 16];
#pragma unroll
    for (int q = 0; q < 4; ++q) {
      float4 B4 = *(const float4*)(pr + q*4);
      h[q*4+0] = fmaf(dA[q*4+0], h[q*4+0], dtx * B4.x);
      h[q*4+1] = fmaf(dA[q*4+1], h[q*4+1], dtx * B4.y);
      h[q*4+2] = fmaf(dA[q*4+2], h[q*4+2], dtx * B4.z);
      h[q*4+3] = fmaf(dA[q*4+3], h[q*4+3], dtx * B4.w);
    }
  }
  float* o = PS + ((size_t)bx * 512 + d) * 32;
#pragma unroll
  for (int q = 0; q < 4; ++q)
    *(float4*)(o + q*4) = make_float4(__expf(sdt*An[q*4+0]), __expf(sdt*An[q*4+1]),
                                      __expf(sdt*An[q*4+2]), __expf(sdt*An[q*4+3]));
#pragma unroll
  for (int q = 0; q < 4; ++q)
    *(float4*)(o + 16 + q*4) = make_float4(h[q*4], h[q*4+1], h[q*4+2], h[q*4+3]);
}

// ---------------------------------------------------------------------------
// K6: scan phase B — combine chunk summaries, store chunk-entry states
// ---------------------------------------------------------------------------
__global__ __launch_bounds__(256)
void k_scanB(const float* __restrict__ PS, float* __restrict__ hst) {
  const int tid = blockIdx.x * 256 + threadIdx.x;
  const int n = tid & 15;
  const int d = (tid >> 4) & 511;
  const int b = tid >> 13;
  float h = 0.f;
  for (int c = 0; c < NCHK; ++c) {
    const size_t idx = (size_t)((b*NCHK + c)*512 + d);
    hst[idx*16 + n] = h;
    h = PS[idx*32 + n] * h + PS[idx*32 + 16 + n];
  }
}

// ---------------------------------------------------------------------------
// K7: scan phase C — rescan from entry state; B,C staged in LDS; dt from dtb
// ---------------------------------------------------------------------------
__global__ __launch_bounds__(512, 4)
void k_scanC(const float* __restrict__ proj, const unsigned short* __restrict__ dtb,
             const unsigned short* __restrict__ xc_b,
             const unsigned short* __restrict__ zsb, const float* __restrict__ hst,
             const float* __restrict__ A_log, const float* __restrict__ Dpar,
             unsigned short* __restrict__ ydata) {
  __shared__ float prs[CHL * 32];
  const int bx = blockIdx.x;
  const int b = bx >> 7, c = bx & 127;
  const int d = threadIdx.x;
  const size_t rbase = (size_t)b * LHW + c * CHL;
  for (int i = d; i < CHL * 8; i += 512) {
    const int row = i >> 3, c4 = i & 7;
    *(float4*)&prs[row * 32 + c4 * 4] = *(const float4*)(proj + (rbase + row) * 48 + 16 + c4 * 4);
  }
  float An[16], h[16];
#pragma unroll
  for (int q = 0; q < 4; ++q) {
    float4 a4 = *(const float4*)(A_log + d*16 + q*4);
    An[q*4+0] = -__expf(a4.x); An[q*4+1] = -__expf(a4.y);
    An[q*4+2] = -__expf(a4.z); An[q*4+3] = -__expf(a4.w);
  }
#pragma unroll
  for (int q = 0; q < 4; ++q) {
    float4 h4 = *(const float4*)(hst + ((size_t)bx * 512 + d) * 16 + q*4);
    h[q*4+0] = h4.x; h[q*4+1] = h4.y; h[q*4+2] = h4.z; h[q*4+3] = h4.w;
  }
  const float An0 = An[0];
  bool lin = true;
#pragma unroll
  for (int n = 1; n < 16; ++n)
    lin = lin && (fabsf(An[n] - (n + 1) * An0) <= 1e-4f * fabsf(An[n]));
  const float dp = Dpar[d];
  const unsigned short* dt0 = dtb + rbase * 512 + d;
  const unsigned short* xc0 = xc_b + rbase * DIN + d;
  const unsigned short* zs0 = zsb + rbase * DIN + d;
  unsigned short* y0 = ydata + rbase * DIN + d;
  __syncthreads();
  for (int i = 0; i < CHL; ++i) {
    const float dt = b2f(dt0[(size_t)i * 512]);
    const float xt = b2f(xc0[(size_t)i * DIN]);
    const float zv = b2f(zs0[(size_t)i * DIN]);
    const float dtx = dt * xt;
    float dA[16];
    if (lin) {
      const float e1 = __expf(dt * An0);
      const float e2 = e1 * e1, e3 = e2 * e1, e4 = e2 * e2;
      dA[0] = e1; dA[1] = e2; dA[2] = e3; dA[3] = e4;
#pragma unroll
      for (int n = 4; n < 16; ++n) dA[n] = dA[n-4] * e4;
    } else {
#pragma unroll
      for (int n = 0; n < 16; ++n) dA[n] = __expf(dt * An[n]);
    }
    const float* pr = &prs[i * 32];
    float y0a = 0.f, y1a = 0.f, y2a = 0.f, y3a = 0.f;
#pragma unroll
    for (int q = 0; q < 4; ++q) {
      float4 B4 = *(const float4*)(pr + q*4);
      float4 C4 = *(const float4*)(pr + 16 + q*4);
      h[q*4+0] = fmaf(dA[q*4+0], h[q*4+0], dtx * B4.x);
      h[q*4+1] = fmaf(dA[q*4+1], h[q*4+1], dtx * B4.y);
      h[q*4+2] = fmaf(dA[q*4+2], h[q*4+2], dtx * B4.z);
      h[q*4+3] = fmaf(dA[q*4+3], h[q*4+3], dtx * B4.w);
      y0a = fmaf(h[q*4+0], C4.x, y0a);
      y1a = fmaf(h[q*4+1], C4.y, y1a);
      y2a = fmaf(h[q*4+2], C4.z, y2a);
      y3a = fmaf(h[q*4+3], C4.w, y3a);
    }
    const float y = (y0a + y1a) + (y2a + y3a);
    y0[(size_t)i * DIN] = f2b((y + xt * dp) * zv);
  }
}

// ---------------------------------------------------------------------------
// G4: outproj + residual(ub) -> padded channel-last bf16 xrp
// ---------------------------------------------------------------------------
__global__ __launch_bounds__(256)
void k_outproj_mfma(const unsigned short* __restrict__ ydata, const unsigned short* __restrict__ opwb,
                    const unsigned short* __restrict__ ub, unsigned short* __restrict__ xrp) {
  __shared__ __align__(16) unsigned short As[4096], Bs[4096];
  const int t = threadIdx.x, lane = t & 63, w = t >> 6;
  const int wm = w >> 1, wn = w & 1;
  const int b = blockIdx.z, m0 = blockIdx.y * 128, n0 = blockIdx.x * 128;
  f32x4 acc[4][4] = {};
  gemm_loop_128<512, 512, 512>(ydata + ((size_t)b * LHW + m0) * 512,
                               opwb + (size_t)n0 * 512, As, Bs, t, acc);
  const int fr = lane & 15, q4 = (lane >> 4) * 4;
#pragma unroll
  for (int i = 0; i < 4; ++i) {
    const int lbase = m0 + wm*64 + i*16 + q4;
#pragma unroll
    for (int q = 0; q < 4; ++q) {
      const int l = lbase + q;
      const int pos = ((l >> 6) + 1) * PW + (l & 63) + 1;
#pragma unroll
      for (int j = 0; j < 4; ++j) {
        const int o = n0 + wn*64 + j*16 + fr;
        const float r = b2f(ub[((size_t)b * LHW + l) * COUT + o]);
        xrp[((size_t)b * PPOS + pos) * COUT + o] = f2b(acc[i][j][q] + r);
      }
    }
  }
}

// ---------------------------------------------------------------------------
// G5: refine 3x3 conv as MFMA implicit GEMM + BN + ReLU
// ---------------------------------------------------------------------------
__global__ __launch_bounds__(256)
void k_refine_mfma(const unsigned short* __restrict__ Aw,
                   const unsigned short* __restrict__ xrp,
                   const float* __restrict__ rb, const float* __restrict__ bng,
                   const float* __restrict__ bnb, const float* __restrict__ bnm,
                   const float* __restrict__ bnv, float* __restrict__ out) {
  __shared__ __align__(16) unsigned short As[4096], Bs[4096];
  const int t = threadIdx.x;
  const int lane = t & 63;
  const int w = t >> 6;
  const int wm = w >> 1, wn = w & 1;
  const int b  = blockIdx.z;
  const int m0 = blockIdx.y * 128;
  const int n0 = blockIdx.x * 128;
  const int y0 = n0 >> 6;
  const unsigned short* xb = xrp + (size_t)b * PPOS * COUT;
  const int arow = t >> 2;
  const int acol = (t & 3) * 8;
  f32x4 acc[4][4] = {};
  for (int ks = 0; ks < 72; ++ks) {
    const int tap = ks >> 3;
    const int i0  = (ks & 7) * 32;
    const int ky  = tap / 3, kx = tap - ky * 3;
    const int k0  = tap * 256 + i0;
    const unsigned short* ga0 = Aw + (size_t)(m0 + arow) * 2304 + k0 + acol;
    const unsigned short* gb0 = xb + ((size_t)((y0 + ky) * PW + kx + arow)) * COUT + i0 + acol;
    __syncthreads();
    gload16(ga0,              &As[w * 512]);
    gload16(ga0 + 64 * 2304,  &As[2048 + w * 512]);
    gload16(gb0,              &Bs[w * 512]);
    gload16(gb0 + PW * COUT,  &Bs[2048 + w * 512]);
    __syncthreads();
    const int fr = lane & 15, g8 = (lane >> 4) * 8;
    bf16x8 af[4], bfr[4];
#pragma unroll
    for (int f = 0; f < 4; ++f) {
      af[f]  = *(const bf16x8*)&As[(wm*64 + f*16 + fr) * 32 + g8];
      bfr[f] = *(const bf16x8*)&Bs[(wn*64 + f*16 + fr) * 32 + g8];
    }
#pragma unroll
    for (int i = 0; i < 4; ++i)
#pragma unroll
      for (int j = 0; j < 4; ++j)
        acc[i][j] = __builtin_amdgcn_mfma_f32_16x16x32_bf16(af[i], bfr[j], acc[i][j], 0, 0, 0);
  }
  const int fr = lane & 15, q4 = (lane >> 4) * 4;
#pragma unroll
  for (int i = 0; i < 4; ++i) {
    const int obase = m0 + wm*64 + i*16 + q4;
#pragma unroll
    for (int q = 0; q < 4; ++q) {
      const int o = obase + q;
      const float inv = bng[o] * rsqrtf(bnv[o] + 1e-5f);
      const float sh  = (rb[o] - bnm[o]) * inv + bnb[o];
      float* orow = out + ((size_t)b * COUT + o) * LHW + n0 + wn*64 + fr;
#pragma unroll
      for (int j = 0; j < 4; ++j)
        orow[j*16] = fmaxf(fmaf(acc[i][j][q], inv, sh), 0.f);
    }
  }
}

// ---------------------------------------------------------------------------
extern "C" void kernel_launch(void* const* d_in, const int* in_sizes, int n_in,
                              void* d_out, int out_size, void* d_ws, size_t ws_size,
                              hipStream_t stream) {
  const float* x    = (const float*)d_in[0];
  const float* lw   = (const float*)d_in[1];
  const float* lb   = (const float*)d_in[2];
  const float* ipw  = (const float*)d_in[3];
  const float* cw   = (const float*)d_in[4];
  const float* cb   = (const float*)d_in[5];
  const float* xpw  = (const float*)d_in[6];
  const float* dtpw = (const float*)d_in[7];
  const float* dtpb = (const float*)d_in[8];
  const float* Alog = (const float*)d_in[9];
  const float* Dpar = (const float*)d_in[10];
  const float* opw  = (const float*)d_in[11];
  const float* rw   = (const float*)d_in[12];
  const float* rb   = (const float*)d_in[13];
  const float* bng  = (const float*)d_in[14];
  const float* bnb  = (const float*)d_in[15];
  const float* bnm  = (const float*)d_in[16];
  const float* bnv  = (const float*)d_in[17];
  float* out = (float*)d_out;

  float* ws = (float*)d_ws;
  unsigned short* ub   = (unsigned short*)ws;                      // 8.4M us
  unsigned short* xt   = (unsigned short*)(ws + 4194304);          // 16.8M us (reused: dtb, xrp)
  unsigned short* xm_b = (unsigned short*)(ws + 12582912);         // 16.8M us (reused as ydata)
  unsigned short* xc_b = (unsigned short*)(ws + 20971520);         // 16.8M us
  unsigned short* zsb  = (unsigned short*)(ws + 29360128);         // 16.8M us
  float* proj = ws + 37748736;                                     //  1.57M f
  float* PS   = ws + 39321600;                                     // 16.8M f (NB*NCHK*512*32)
  float* hst  = ws + 56098816;                                     //  8.4M f (NB*NCHK*512*16)
  unsigned short* wb  = (unsigned short*)(ws + 64487424);          //  1.15M us
  unsigned short* wfb = (unsigned short*)(ws + 65060864);          //  0.33M us (640x512)
  unsigned short* lwb  = wb;
  unsigned short* ipwb = wb + WO1;
  unsigned short* opwb = wb + WO3;
  unsigned short* Aw   = wb + WO4;
  unsigned short* ydata = xm_b;
  unsigned short* dtb   = xt;   // xt dead after k_lat_mfma
  unsigned short* xrp   = xt;   // dtb dead after scanC; memset is after scanC

  k_wprep<<<dim3(4480), 256, 0, stream>>>(lw, ipw, xpw, opw, rw, wb);
  k_wfuse<<<dim3(1280), 256, 0, stream>>>(dtpw, xpw, wfb);
  k_xpose<<<dim3(64, 8, 8), 256, 0, stream>>>(x, xt);
  k_lat_mfma<<<dim3(2, 32, 8), 256, 0, stream>>>(xt, lwb, lb, ub);
  k_inproj_mfma<<<dim3(8, 32, 8), 256, 0, stream>>>(ub, ipwb, xm_b, zsb);
  k_conv1d<<<dim3(2048), 256, 0, stream>>>(xm_b, cw, cb, xc_b);
  k_xdt_mfma<<<dim3(32, 5, 8), 256, 0, stream>>>(xc_b, wfb, dtpb, dtb, proj);
  k_scanA<<<dim3(NB * NCHK), 512, 0, stream>>>(proj, dtb, xc_b, Alog, PS);
  k_scanB<<<dim3(256), 256, 0, stream>>>(PS, hst);
  k_scanC<<<dim3(NB * NCHK), 512, 0, stream>>>(proj, dtb, xc_b, zsb, hst, Alog, Dpar, ydata);
  hipMemsetAsync(xrp, 0, (size_t)NB * PPOS * COUT * sizeof(unsigned short), stream);
  k_outproj_mfma<<<dim3(2, 32, 8), 256, 0, stream>>>(ydata, opwb, ub, xrp);
  k_refine_mfma<<<dim3(32, 2, 8), 256, 0, stream>>>(Aw, xrp, rb, bng, bnb, bnm, bnv, out);
}